// Round 11
// baseline (5950.983 us; speedup 1.0000x reference)
//
#include <hip/hip_runtime.h>

// Problem constants (reference: T=512, N=256, H=256, HR=64, WC=128, V=64)
#define TSTEPS 512
#define NBATCH 256
#define HID    256
#define TCHUNK 64
#define NCHUNK 8

typedef __attribute__((ext_vector_type(8))) short bf16x8;
typedef __attribute__((ext_vector_type(4))) float f32x4;

__device__ __forceinline__ unsigned short f2b(float x) {
    union { float f; unsigned int u; } c; c.f = x;
    unsigned int u = c.u;
    return (unsigned short)((u + 0x7fffu + ((u >> 16) & 1u)) >> 16);
}
__device__ __forceinline__ float b2f(unsigned short u) {
    union { float f; unsigned int u; } c; c.u = ((unsigned int)u) << 16;
    return c.f;
}

__device__ __forceinline__ void gload_lds16(const float* g, float* l) {
    __builtin_amdgcn_global_load_lds(
        (const __attribute__((address_space(1))) unsigned int*)g,
        (__attribute__((address_space(3))) unsigned int*)l,
        16, 0, 0);
}
// ushort variants, PROVEN widths only (16B / 4B). LDS bases kept 16B-aligned.
__device__ __forceinline__ void gload_lds16u(const unsigned short* g, unsigned short* l) {
    __builtin_amdgcn_global_load_lds(
        (const __attribute__((address_space(1))) unsigned int*)g,
        (__attribute__((address_space(3))) unsigned int*)l,
        16, 0, 0);
}
__device__ __forceinline__ void gload_lds4u(const unsigned short* g, unsigned short* l) {
    __builtin_amdgcn_global_load_lds(
        (const __attribute__((address_space(1))) unsigned int*)g,
        (__attribute__((address_space(3))) unsigned int*)l,
        4, 0, 0);
}

// LDS bank-conflict mitigation for [row][32]-short GEMM tiles (v7, kept).
__device__ __forceinline__ int swzi(int row, int g) {
    return ((g ^ ((row >> 3) & 3)) << 3);
}

// ---------------------------------------------------------------------------
// Generic GEMM (256 thr): C = act(A@B + bias). Prologue use. Swizzled LDS.
// OBF=1: write bf16 (ushort) output, ldc in ushort units.
// ---------------------------------------------------------------------------
template<bool TRANS_B, int ACT, int OBF>
__global__ __launch_bounds__(256) void gemm_f32(
    const float* __restrict__ A, long lda, long sA,
    const float* __restrict__ B, long ldb, long sB,
    const float* __restrict__ bias,
    float* __restrict__ C, long ldc, long sC,
    int M, int N, int K)
{
    __shared__ __align__(16) unsigned short As[64][32];
    __shared__ __align__(16) unsigned short Bs[64][32];
    const int z = blockIdx.z;
    A += (long)z * sA; B += (long)z * sB; C += (long)z * sC;
    const int n0 = blockIdx.x * 64, m0 = blockIdx.y * 64;
    const int tid  = threadIdx.x;
    const int lane = tid & 63, w = tid >> 6;
    const int wr = (w >> 1) * 32, wc = (w & 1) * 32;

    f32x4 acc[2][2];
#pragma unroll
    for (int i = 0; i < 2; i++)
#pragma unroll
        for (int j = 0; j < 2; j++) acc[i][j] = (f32x4){0.f, 0.f, 0.f, 0.f};

    for (int k0 = 0; k0 < K; k0 += 32) {
        {
            const int r = tid >> 2, ck = (tid & 3) << 3;
            const float* s = A + (long)(m0 + r) * lda + k0 + ck;
            float4 v0 = *(const float4*)s, v1 = *(const float4*)(s + 4);
            unsigned short* d = &As[r][swzi(r, ck >> 3)];
            d[0] = f2b(v0.x); d[1] = f2b(v0.y); d[2] = f2b(v0.z); d[3] = f2b(v0.w);
            d[4] = f2b(v1.x); d[5] = f2b(v1.y); d[6] = f2b(v1.z); d[7] = f2b(v1.w);
        }
        if (TRANS_B) {
            const int r = tid >> 2, ck = (tid & 3) << 3;
            const float* s = B + (long)(n0 + r) * ldb + k0 + ck;
            float4 v0 = *(const float4*)s, v1 = *(const float4*)(s + 4);
            unsigned short* d = &Bs[r][swzi(r, ck >> 3)];
            d[0] = f2b(v0.x); d[1] = f2b(v0.y); d[2] = f2b(v0.z); d[3] = f2b(v0.w);
            d[4] = f2b(v1.x); d[5] = f2b(v1.y); d[6] = f2b(v1.z); d[7] = f2b(v1.w);
        } else {
            const int kk = tid >> 3, cn = (tid & 7) << 3;
            const float* s = B + (long)(k0 + kk) * ldb + n0 + cn;
            float4 v0 = *(const float4*)s, v1 = *(const float4*)(s + 4);
            const int sc = swzi(cn, kk >> 3) + (kk & 7);
            Bs[cn + 0][sc] = f2b(v0.x); Bs[cn + 1][sc] = f2b(v0.y);
            Bs[cn + 2][sc] = f2b(v0.z); Bs[cn + 3][sc] = f2b(v0.w);
            Bs[cn + 4][sc] = f2b(v1.x); Bs[cn + 5][sc] = f2b(v1.y);
            Bs[cn + 6][sc] = f2b(v1.z); Bs[cn + 7][sc] = f2b(v1.w);
        }
        __syncthreads();
        const int l15 = lane & 15, q = lane >> 4;
        bf16x8 a0 = *(const bf16x8*)&As[wr +      l15][swzi(wr +      l15, q)];
        bf16x8 a1 = *(const bf16x8*)&As[wr + 16 + l15][swzi(wr + 16 + l15, q)];
        bf16x8 b0 = *(const bf16x8*)&Bs[wc +      l15][swzi(wc +      l15, q)];
        bf16x8 b1 = *(const bf16x8*)&Bs[wc + 16 + l15][swzi(wc + 16 + l15, q)];
        acc[0][0] = __builtin_amdgcn_mfma_f32_16x16x32_bf16(a0, b0, acc[0][0], 0, 0, 0);
        acc[0][1] = __builtin_amdgcn_mfma_f32_16x16x32_bf16(a0, b1, acc[0][1], 0, 0, 0);
        acc[1][0] = __builtin_amdgcn_mfma_f32_16x16x32_bf16(a1, b0, acc[1][0], 0, 0, 0);
        acc[1][1] = __builtin_amdgcn_mfma_f32_16x16x32_bf16(a1, b1, acc[1][1], 0, 0, 0);
        __syncthreads();
    }
    const int cq = lane >> 4, cc = lane & 15;
#pragma unroll
    for (int i = 0; i < 2; i++)
#pragma unroll
        for (int j = 0; j < 2; j++) {
#pragma unroll
            for (int rg = 0; rg < 4; rg++) {
                int row = m0 + wr + i * 16 + cq * 4 + rg;
                int col = n0 + wc + j * 16 + cc;
                float v = acc[i][j][rg];
                if (bias) v += bias[col];
                if (ACT == 1) v = v > 0.f ? v : 0.f;
                if (OBF) ((unsigned short*)C)[(long)row * ldc + col] = f2b(v);
                else     C[(long)row * ldc + col] = v;
            }
        }
}

// ---------------------------------------------------------------------------
// Helpers
// ---------------------------------------------------------------------------
__global__ void combine_bias(const float* a0, const float* b0,
                             const float* a1, const float* b1,
                             const float* a2, const float* b2,
                             float* o0, float* o1, float* o2)
{
    int i = blockIdx.x * 256 + threadIdx.x;
    o0[i] = a0[i] + b0[i];
    o1[i] = a1[i] + b1[i];
    o2[i] = a2[i] + b2[i];
}

__global__ void seq_major(const float* __restrict__ M, float* __restrict__ Mseq)
{
    int b = blockIdx.x;
    int s = b >> 8, n = b & 255;
    int t = threadIdx.x;
    Mseq[(long)b * 256 + t] = M[((long)n * 64 + s) * 256 + t];
}

// ---------------------------------------------------------------------------
// pack_w: 8-wave scan fragment layout (v3/v7, proven).
// ---------------------------------------------------------------------------
__global__ __launch_bounds__(256) void pack_w(
    const float* __restrict__ Wf, const float* __restrict__ Wb, const float* __restrict__ Wc,
    unsigned short* __restrict__ Pf, unsigned short* __restrict__ Pb, unsigned short* __restrict__ Pc)
{
    int chunk = blockIdx.x * 256 + threadIdx.x;      // 0..24575
    const float* W = (blockIdx.y == 0) ? Wf : ((blockIdx.y == 1) ? Wb : Wc);
    unsigned short* P = (blockIdx.y == 0) ? Pf : ((blockIdx.y == 1) ? Pb : Pc);
    int lane = chunk & 63;
    int kt   = (chunk >> 6) & 7;
    int f    = (chunk >> 9) % 6;
    int w    = chunk / 3072;
    int g = f >> 1, hh = f & 1;
    int c = lane & 15, q = lane >> 4;
    int col = g * 256 + w * 32 + hh * 16 + c;
    int k0  = kt * 32 + q * 8;
    unsigned int v[8];
#pragma unroll
    for (int j = 0; j < 8; j++) v[j] = f2b(W[(long)(k0 + j) * 768 + col]);
    uint4 o;
    o.x = v[0] | (v[1] << 16); o.y = v[2] | (v[3] << 16);
    o.z = v[4] | (v[5] << 16); o.w = v[6] | (v[7] << 16);
    *(uint4*)&P[(long)chunk * 8] = o;
}

__global__ void build_x(const float* __restrict__ values, const float* __restrict__ Mbuf,
                        const int* __restrict__ actions, const int* __restrict__ a0,
                        float* __restrict__ Xc, int t0)
{
    int m = blockIdx.x;
    int tl = m >> 8, n = m & 255;
    int t = t0 + tl;
    int c = threadIdx.x;
    float v;
    if (c < 64) {
        v = values[((long)t * 256 + n) * 64 + c];
    } else {
        int ap = (t == 0) ? a0[n] : actions[(long)(t - 1) * 256 + n];
        v = Mbuf[((long)n * 64 + ap) * 256 + (c - 64)];
    }
    Xc[(long)m * 320 + c] = v;
}

// ---------------------------------------------------------------------------
// Fused kernel v11: bf16 gate inputs (stride 776 = 1552B rows, 16B-aligned
// chunk bases) -> LDS union ~66.6KB -> 2 blocks/CU, launch_bounds(512,4).
// Staging uses only proven widths: 16B chunk (first 512 ushorts) + 2x 4B
// chunks (remaining 256). 6 loads + 8 stores per wave-step -> vmcnt(8).
// ---------------------------------------------------------------------------
struct GemmRole {
    const float* A; const float* B; const float* bias; float* C;
    int K; long lda; long ldb; long ldc; int act; int nblocks; int ntn; int obf;
};

union FusedLds {
    struct { unsigned short hbuf[2][16][264]; unsigned short gibuf[2][16 * 776]; } s;
    struct { unsigned short As[64][32]; unsigned short Bs[128][32]; } g;
    struct { unsigned short As2[2][64][32]; unsigned short Bs2[2][64][32]; } l;
};

// ---- scan role: v3/v7 structure (8 waves, split-hh, fences, counted vmcnt);
// gi bf16: per-row {16B x64, 4B x64, 4B x64} chunks, 6 per wave per step. ----
__device__ __forceinline__ void scan_role(FusedLds* L,
    const unsigned short* gi, const unsigned short* PK, const float* h_init,
    float* outp, float* h_state, int n0, int steps, int kgru, int d)
{
    auto& hbuf  = L->s.hbuf;
    auto& gibuf = L->s.gibuf;
    const int tid = threadIdx.x;
    const int w = tid >> 6, lane = tid & 63;
    const int q = lane >> 4, c = lane & 15, q8 = q << 3;
    const int wcol = w * 32;

    bf16x8 Bf[6][8];
#pragma unroll
    for (int f = 0; f < 6; f++)
#pragma unroll
        for (int kt = 0; kt < 8; kt++)
            Bf[f][kt] = *(const bf16x8*)&PK[(((long)(w * 6 + f) * 8 + kt) * 64 + lane) * 8];

    f32x4 hreg[2];
#pragma unroll
    for (int hh = 0; hh < 2; hh++)
#pragma unroll
        for (int rg = 0; rg < 4; rg++) {
            float v = 0.f;
            if (!kgru) v = h_init[(long)(n0 + q * 4 + rg) * 256 + wcol + hh * 16 + c];
            hreg[hh][rg] = v;
            hbuf[1][q * 4 + rg][wcol + hh * 16 + c] = f2b(v);
        }

    const int row0 = kgru ? (d ? 63 : 0) : 0;
    const long gstride = (kgru && d) ? -196608L : 196608L;   // ushort units
    const unsigned short* gsrc = gi + ((long)row0 * 256 + n0) * 768;
    float* optr[4];
    long ostride;
    if (kgru) {
        ostride = d ? -512L : 512L;
#pragma unroll
        for (int rg = 0; rg < 4; rg++)
            optr[rg] = outp + ((long)(n0 + q * 4 + rg) * 64 + row0) * 512 + d * 256 + wcol + c;
    } else {
        ostride = 65536L;
#pragma unroll
        for (int rg = 0; rg < 4; rg++)
            optr[rg] = outp + (long)(n0 + q * 4 + rg) * 256 + wcol + c;
    }

    // prologue: gi[0] -> gibuf[0]; 48 chunks (16 rows x {1024B,256B,256B})
#pragma unroll
    for (int i = 0; i < 6; i++) {
        int idx = w * 6 + i;              // 0..47
        int r = idx / 3, kd = idx % 3;
        if (kd == 0)
            gload_lds16u(gsrc + (long)r * 768 + lane * 8, &gibuf[0][r * 776]);
        else if (kd == 1)
            gload_lds4u(gsrc + (long)r * 768 + 512 + lane * 2, &gibuf[0][r * 776 + 512]);
        else
            gload_lds4u(gsrc + (long)r * 768 + 640 + lane * 2, &gibuf[0][r * 776 + 640]);
    }
    __syncthreads();

    for (int s = 0; s < steps; s++) {
        const int cur = s & 1;
        if (s + 1 < steps) {
            const unsigned short* src = gsrc + gstride;
#pragma unroll
            for (int i = 0; i < 6; i++) {
                int idx = w * 6 + i;
                int r = idx / 3, kd = idx % 3;
                if (kd == 0)
                    gload_lds16u(src + (long)r * 768 + lane * 8, &gibuf[cur ^ 1][r * 776]);
                else if (kd == 1)
                    gload_lds4u(src + (long)r * 768 + 512 + lane * 2, &gibuf[cur ^ 1][r * 776 + 512]);
                else
                    gload_lds4u(src + (long)r * 768 + 640 + lane * 2, &gibuf[cur ^ 1][r * 776 + 640]);
            }
        }
        gsrc += gstride;
        asm volatile("" ::: "memory");

        const unsigned short* hrd = &hbuf[cur ^ 1][0][0];
        const unsigned short* gp = &gibuf[cur][(q * 4) * 776 + wcol + c];
        unsigned short* hwr = &hbuf[cur][q * 4][wcol + c];

#pragma unroll
        for (int hh = 0; hh < 2; hh++) {
            f32x4 ar = (f32x4){0.f, 0.f, 0.f, 0.f};
            f32x4 az = (f32x4){0.f, 0.f, 0.f, 0.f};
            f32x4 an = (f32x4){0.f, 0.f, 0.f, 0.f};
#pragma unroll
            for (int kt = 0; kt < 8; kt++) {
                bf16x8 a = *(const bf16x8*)&hrd[c * 264 + kt * 32 + q8];
                ar = __builtin_amdgcn_mfma_f32_16x16x32_bf16(a, Bf[0 + hh][kt], ar, 0, 0, 0);
                az = __builtin_amdgcn_mfma_f32_16x16x32_bf16(a, Bf[2 + hh][kt], az, 0, 0, 0);
                an = __builtin_amdgcn_mfma_f32_16x16x32_bf16(a, Bf[4 + hh][kt], an, 0, 0, 0);
            }
#pragma unroll
            for (int rg = 0; rg < 4; rg++) {
                float gr = b2f(gp[rg * 776 +       hh * 16]);
                float gz = b2f(gp[rg * 776 + 256 + hh * 16]);
                float gn = b2f(gp[rg * 776 + 512 + hh * 16]);
                float r  = __builtin_amdgcn_rcpf(1.f + __expf(-(gr + ar[rg])));
                float zg = __builtin_amdgcn_rcpf(1.f + __expf(-(gz + az[rg])));
                float nn = 1.f - 2.f * __builtin_amdgcn_rcpf(1.f + __expf(2.f * (gn + r * an[rg])));
                float hv = (1.f - zg) * nn + zg * hreg[hh][rg];
                hreg[hh][rg] = hv;
                hwr[rg * 264 + hh * 16] = f2b(hv);
                optr[rg][hh * 16] = hv;
            }
            asm volatile("" ::: "memory");
        }

#pragma unroll
        for (int rg = 0; rg < 4; rg++) optr[rg] += ostride;

        // 6 gi loads + 8 stores issued; vmcnt(8) retires the loads only.
        asm volatile("s_waitcnt vmcnt(8) lgkmcnt(0)" ::: "memory");
        __builtin_amdgcn_sched_barrier(0);
        __builtin_amdgcn_s_barrier();
        __builtin_amdgcn_sched_barrier(0);
    }

    if (!kgru) {
#pragma unroll
        for (int hh = 0; hh < 2; hh++)
#pragma unroll
            for (int rg = 0; rg < 4; rg++)
                h_state[(long)(n0 + q * 4 + rg) * 256 + wcol + hh * 16 + c] = hreg[hh][rg];
    }
}

// ---- gemm role: 512-thread 64x128 tile, B stored (K,N), swizzled LDS ----
__device__ __forceinline__ void gemm_role(FusedLds* L, const GemmRole& R, int rb)
{
    auto& As = L->g.As;
    auto& Bs = L->g.Bs;
    const int tid = threadIdx.x;
    const int lane = tid & 63, w = tid >> 6;
    const int mt = rb / R.ntn, nt = rb % R.ntn;
    const long m0 = (long)mt * 64, n0 = (long)nt * 128;
    const int wr = (w >> 2) * 32, wc = (w & 3) * 32;

    f32x4 acc[2][2];
#pragma unroll
    for (int i = 0; i < 2; i++)
#pragma unroll
        for (int j = 0; j < 2; j++) acc[i][j] = (f32x4){0.f, 0.f, 0.f, 0.f};

    for (int k0 = 0; k0 < R.K; k0 += 32) {
        {
            const int r = tid >> 3, ck = (tid & 7) << 2;
            const float* s = R.A + (m0 + r) * R.lda + k0 + ck;
            float4 v = *(const float4*)s;
            unsigned short* dp = &As[r][swzi(r, ck >> 3) + (ck & 7)];
            dp[0] = f2b(v.x); dp[1] = f2b(v.y); dp[2] = f2b(v.z); dp[3] = f2b(v.w);
        }
        {
            const int kk = tid >> 4, cn = (tid & 15) << 3;
            const float* s = R.B + (long)(k0 + kk) * R.ldb + n0 + cn;
            float4 v0 = *(const float4*)s, v1 = *(const float4*)(s + 4);
            const int sc = swzi(cn, kk >> 3) + (kk & 7);
            Bs[cn + 0][sc] = f2b(v0.x); Bs[cn + 1][sc] = f2b(v0.y);
            Bs[cn + 2][sc] = f2b(v0.z); Bs[cn + 3][sc] = f2b(v0.w);
            Bs[cn + 4][sc] = f2b(v1.x); Bs[cn + 5][sc] = f2b(v1.y);
            Bs[cn + 6][sc] = f2b(v1.z); Bs[cn + 7][sc] = f2b(v1.w);
        }
        __syncthreads();
        const int l15 = lane & 15, q = lane >> 4;
        bf16x8 a0 = *(const bf16x8*)&As[wr +      l15][swzi(wr +      l15, q)];
        bf16x8 a1 = *(const bf16x8*)&As[wr + 16 + l15][swzi(wr + 16 + l15, q)];
        bf16x8 b0 = *(const bf16x8*)&Bs[wc +      l15][swzi(wc +      l15, q)];
        bf16x8 b1 = *(const bf16x8*)&Bs[wc + 16 + l15][swzi(wc + 16 + l15, q)];
        acc[0][0] = __builtin_amdgcn_mfma_f32_16x16x32_bf16(a0, b0, acc[0][0], 0, 0, 0);
        acc[0][1] = __builtin_amdgcn_mfma_f32_16x16x32_bf16(a0, b1, acc[0][1], 0, 0, 0);
        acc[1][0] = __builtin_amdgcn_mfma_f32_16x16x32_bf16(a1, b0, acc[1][0], 0, 0, 0);
        acc[1][1] = __builtin_amdgcn_mfma_f32_16x16x32_bf16(a1, b1, acc[1][1], 0, 0, 0);
        __syncthreads();
    }
    const int cq = lane >> 4, cc = lane & 15;
#pragma unroll
    for (int i = 0; i < 2; i++)
#pragma unroll
        for (int j = 0; j < 2; j++) {
#pragma unroll
            for (int rg = 0; rg < 4; rg++) {
                long row = m0 + wr + i * 16 + cq * 4 + rg;
                long col = n0 + wc + j * 16 + cc;
                float v = acc[i][j][rg];
                if (R.bias) v += R.bias[col];
                if (R.act == 1) v = v > 0.f ? v : 0.f;
                if (R.obf) ((unsigned short*)R.C)[row * R.ldc + col] = f2b(v);
                else       R.C[row * R.ldc + col] = v;
            }
        }
}

// ---- logits role: dual-z 64x64x512 GEMM (both halves barrier-identical) ----
__device__ __forceinline__ void logits_role(FusedLds* L, int rb,
    const float* Qs, const float* Kb, float* Lout)
{
    auto& As = L->l.As2;
    auto& Bs = L->l.Bs2;
    const int tid = threadIdx.x;
    const int half = tid >> 8, htid = tid & 255;
    const int z = rb * 2 + half;
    const float* A = Qs + (long)z * 512;
    const float* B = Kb + (long)z * 32768;
    float* C = Lout + (long)z * 64;
    const int lane = htid & 63, w4 = htid >> 6;
    const int wr = (w4 >> 1) * 32, wc = (w4 & 1) * 32;

    f32x4 acc[2][2];
#pragma unroll
    for (int i = 0; i < 2; i++)
#pragma unroll
        for (int j = 0; j < 2; j++) acc[i][j] = (f32x4){0.f, 0.f, 0.f, 0.f};

    for (int k0 = 0; k0 < 512; k0 += 32) {
        const int r = htid >> 2, ck = (htid & 3) << 3;
        {
            const float* s = A + (long)r * 131072 + k0 + ck;
            float4 v0 = *(const float4*)s, v1 = *(const float4*)(s + 4);
            unsigned short* d = &As[half][r][swzi(r, ck >> 3)];
            d[0] = f2b(v0.x); d[1] = f2b(v0.y); d[2] = f2b(v0.z); d[3] = f2b(v0.w);
            d[4] = f2b(v1.x); d[5] = f2b(v1.y); d[6] = f2b(v1.z); d[7] = f2b(v1.w);
        }
        {
            const float* s = B + (long)r * 512 + k0 + ck;
            float4 v0 = *(const float4*)s, v1 = *(const float4*)(s + 4);
            unsigned short* d = &Bs[half][r][swzi(r, ck >> 3)];
            d[0] = f2b(v0.x); d[1] = f2b(v0.y); d[2] = f2b(v0.z); d[3] = f2b(v0.w);
            d[4] = f2b(v1.x); d[5] = f2b(v1.y); d[6] = f2b(v1.z); d[7] = f2b(v1.w);
        }
        __syncthreads();
        const int l15 = lane & 15, q = lane >> 4;
        bf16x8 a0 = *(const bf16x8*)&As[half][wr +      l15][swzi(wr +      l15, q)];
        bf16x8 a1 = *(const bf16x8*)&As[half][wr + 16 + l15][swzi(wr + 16 + l15, q)];
        bf16x8 b0 = *(const bf16x8*)&Bs[half][wc +      l15][swzi(wc +      l15, q)];
        bf16x8 b1 = *(const bf16x8*)&Bs[half][wc + 16 + l15][swzi(wc + 16 + l15, q)];
        acc[0][0] = __builtin_amdgcn_mfma_f32_16x16x32_bf16(a0, b0, acc[0][0], 0, 0, 0);
        acc[0][1] = __builtin_amdgcn_mfma_f32_16x16x32_bf16(a0, b1, acc[0][1], 0, 0, 0);
        acc[1][0] = __builtin_amdgcn_mfma_f32_16x16x32_bf16(a1, b0, acc[1][0], 0, 0, 0);
        acc[1][1] = __builtin_amdgcn_mfma_f32_16x16x32_bf16(a1, b1, acc[1][1], 0, 0, 0);
        __syncthreads();
    }
    const int cq = lane >> 4, cc = lane & 15;
#pragma unroll
    for (int i = 0; i < 2; i++)
#pragma unroll
        for (int j = 0; j < 2; j++) {
#pragma unroll
            for (int rg = 0; rg < 4; rg++)
                C[(long)(wr + i * 16 + cq * 4 + rg) * 16384 + wc + j * 16 + cc] = acc[i][j][rg];
        }
}

// ---- epilogue role: per warp, one (t,n); no barriers ----
__device__ __forceinline__ void epi_role(int rb,
    const float* Hall, const float* Lc, const int* actions,
    const float* critic_W, const float* critic_b, float* out, int t0)
{
    const int w = threadIdx.x >> 6, j = threadIdx.x & 63;
    const int m = rb * 8 + w;
    const int tl = m >> 8, n = m & 255;
    const int t = t0 + tl;
    long o = ((long)t * 256 + n) * 322;
    const float* h = Hall + (long)m * 256;
    float part = 0.f;
#pragma unroll
    for (int i = 0; i < 4; i++) {
        float hv = h[j + 64 * i];
        out[o + 2 + j + 64 * i] = hv;
        part += hv * critic_W[j + 64 * i];
    }
    for (int off = 32; off > 0; off >>= 1) part += __shfl_down(part, off);
    if (j == 0) {
        out[o]     = (float)actions[(long)t * 256 + n];
        out[o + 1] = part + critic_b[0];
    }
    float x = Lc[(long)m * 64 + j];
    float mx = x;
    for (int off = 32; off > 0; off >>= 1) mx = fmaxf(mx, __shfl_down(mx, off));
    mx = __shfl(mx, 0);
    float e = __expf(x - mx);
    float ssum = e;
    for (int off = 32; off > 0; off >>= 1) ssum += __shfl_down(ssum, off);
    ssum = __shfl(ssum, 0);
    out[o + 258 + j] = e / ssum;
}

// ---- build_x role ----
__device__ __forceinline__ void bx_role(int rb,
    const float* values, const float* Mbuf, const int* actions, const int* a0,
    float* Xd, int t0)
{
    const int tid = threadIdx.x;
    if (tid >= 320) return;
    for (int rr = 0; rr < 128; rr++) {
        int m = rb * 128 + rr;
        int tl = m >> 8, n = m & 255;
        int t = t0 + tl;
        float v;
        if (tid < 64) {
            v = values[((long)t * 256 + n) * 64 + tid];
        } else {
            int ap = (t == 0) ? a0[n] : actions[(long)(t - 1) * 256 + n];
            v = Mbuf[((long)n * 64 + ap) * 256 + (tid - 64)];
        }
        Xd[(long)m * 320 + tid] = v;
    }
}

__global__ __launch_bounds__(512, 4) void fused_k(
    int sc_nblk, const unsigned short* sc_gi, const unsigned short* sc_PK,
    const float* sc_hinit, float* sc_out, float* sc_hstate,
    int kgru_nblk, const unsigned short* kg_gi0, const unsigned short* kg_gi1,
    const unsigned short* kg_PK0, const unsigned short* kg_PK1, float* kg_out,
    GemmRole g0, GemmRole g1, GemmRole g2, GemmRole g3, GemmRole g4, GemmRole g5,
    int lg_nblk, const float* lg_Q, const float* lg_K, float* lg_L,
    int ep_nblk, const float* ep_Hall, const float* ep_L, int ep_t0,
    int bx_nblk, const float* values, const float* Mbuf,
    const int* actions, const int* a0, float* bx_dst, int bx_t0,
    const float* critic_W, const float* critic_b, float* out)
{
    __shared__ __align__(16) FusedLds L;
    int b = blockIdx.x;
    if (b < sc_nblk) {
        scan_role(&L, sc_gi, sc_PK, sc_hinit, sc_out, sc_hstate, b * 16, TCHUNK, 0, 0);
        return;
    }
    b -= sc_nblk;
    if (b < kgru_nblk) {
        int d = b >> 4, n0 = (b & 15) * 16;
        scan_role(&L, d ? kg_gi1 : kg_gi0, d ? kg_PK1 : kg_PK0, nullptr,
                  kg_out, nullptr, n0, 64, 1, d);
        return;
    }
    b -= kgru_nblk;
    if (b < g0.nblocks) { gemm_role(&L, g0, b); return; }
    b -= g0.nblocks;
    if (b < g1.nblocks) { gemm_role(&L, g1, b); return; }
    b -= g1.nblocks;
    if (b < g2.nblocks) { gemm_role(&L, g2, b); return; }
    b -= g2.nblocks;
    if (b < g3.nblocks) { gemm_role(&L, g3, b); return; }
    b -= g3.nblocks;
    if (b < g4.nblocks) { gemm_role(&L, g4, b); return; }
    b -= g4.nblocks;
    if (b < g5.nblocks) { gemm_role(&L, g5, b); return; }
    b -= g5.nblocks;
    if (b < lg_nblk) { logits_role(&L, b, lg_Q, lg_K, lg_L); return; }
    b -= lg_nblk;
    if (b < ep_nblk) { epi_role(b, ep_Hall, ep_L, actions, critic_W, critic_b, out, ep_t0); return; }
    b -= ep_nblk;
    if (b < bx_nblk) bx_role(b, values, Mbuf, actions, a0, bx_dst, bx_t0);
}

// ---------------------------------------------------------------------------
// Epilogue kernel (final tail use)
// ---------------------------------------------------------------------------
__global__ __launch_bounds__(64) void epilogue_k(
    const float* __restrict__ Hallc, const float* __restrict__ Lc,
    const int* __restrict__ actions,
    const float* __restrict__ critic_W, const float* __restrict__ critic_b,
    float* __restrict__ out, int t0)
{
    int m = blockIdx.x;
    int tl = m >> 8, n = m & 255;
    int t = t0 + tl;
    int j = threadIdx.x;
    long o = ((long)t * 256 + n) * 322;
    const float* h = Hallc + (long)m * 256;
    float part = 0.f;
#pragma unroll
    for (int i = 0; i < 4; i++) {
        float hv = h[j + 64 * i];
        out[o + 2 + j + 64 * i] = hv;
        part += hv * critic_W[j + 64 * i];
    }
    for (int off = 32; off > 0; off >>= 1) part += __shfl_down(part, off);
    if (j == 0) {
        out[o]     = (float)actions[(long)t * 256 + n];
        out[o + 1] = part + critic_b[0];
    }
    float x = Lc[(long)m * 64 + j];
    float mx = x;
    for (int off = 32; off > 0; off >>= 1) mx = fmaxf(mx, __shfl_down(mx, off));
    mx = __shfl(mx, 0);
    float e = __expf(x - mx);
    float ssum = e;
    for (int off = 32; off > 0; off >>= 1) ssum += __shfl_down(ssum, off);
    ssum = __shfl(ssum, 0);
    out[o + 258 + j] = e / ssum;
}

// ---------------------------------------------------------------------------
extern "C" void kernel_launch(void* const* d_in, const int* in_sizes, int n_in,
                              void* d_out, int out_size, void* d_ws, size_t ws_size,
                              hipStream_t stream)
{
    const float* values   = (const float*)d_in[0];
    const float* mdp      = (const float*)d_in[1];
    const int*   actions  = (const int*)  d_in[2];
    const int*   a0       = (const int*)  d_in[3];
    const float* h0       = (const float*)d_in[4];
    const float* emb_W    = (const float*)d_in[5];
    const float* emb_b    = (const float*)d_in[6];
    const float* gfw_Wih  = (const float*)d_in[7];
    const float* gfw_Whh  = (const float*)d_in[8];
    const float* gfw_bih  = (const float*)d_in[9];
    const float* gfw_bhh  = (const float*)d_in[10];
    const float* gbw_Wih  = (const float*)d_in[11];
    const float* gbw_Whh  = (const float*)d_in[12];
    const float* gbw_bih  = (const float*)d_in[13];
    const float* gbw_bhh  = (const float*)d_in[14];
    const float* f0_W     = (const float*)d_in[15];
    const float* f0_b     = (const float*)d_in[16];
    const float* f1_W     = (const float*)d_in[17];
    const float* f1_b     = (const float*)d_in[18];
    const float* cell_Wih = (const float*)d_in[19];
    const float* cell_Whh = (const float*)d_in[20];
    const float* cell_bih = (const float*)d_in[21];
    const float* cell_bhh = (const float*)d_in[22];
    const float* critic_W = (const float*)d_in[23];
    const float* critic_b = (const float*)d_in[24];
    const float* qg_W     = (const float*)d_in[25];
    const float* qg_b     = (const float*)d_in[26];
    float* out = (float*)d_out;

    char* base = (char*)d_ws;
    size_t off = 0;
    auto alloc = [&](size_t nf) -> float* {
        float* p = (float*)(base + off);
        off += nf * sizeof(float);
        off = (off + 255) & ~(size_t)255;
        return p;
    };
    float* Mbuf   = alloc(16384ull * 256);
    float* Mseq   = alloc(16384ull * 256);   // aliased as Hallr[2] (dead after fused(0))
    unsigned short* gfA = (unsigned short*)alloc(16384ull * 384);  // bf16 16384x768
    unsigned short* gbA = (unsigned short*)alloc(16384ull * 384);
    float* Kbuf   = alloc(256ull * 64 * 512);
    float* PKf    = alloc(98304);
    float* PKb    = alloc(98304);
    float* PKc    = alloc(98304);
    float* hstate = alloc(256ull * 256);
    float* Xr[2]    = { alloc(16384ull * 320), alloc(16384ull * 320) };
    float* X0r[2]   = { alloc(16384ull * 256), alloc(16384ull * 256) };
    float* X1r[2]   = { alloc(16384ull * 256), alloc(16384ull * 256) };
    unsigned short* GIr[2] = { (unsigned short*)alloc(16384ull * 384),
                               (unsigned short*)alloc(16384ull * 384) };  // bf16
    float* Hallr[4] = { alloc(16384ull * 256), alloc(16384ull * 256),
                        Mseq, alloc(16384ull * 256) };
    float* Qr[2]  = { alloc(16384ull * 512), alloc(16384ull * 512) };
    float* Lr[2]  = { alloc(16384ull * 64), alloc(16384ull * 64) };
    float* bias_f = alloc(768);
    float* bias_b = alloc(768);
    float* bias_c = alloc(768);
    (void)ws_size; (void)in_sizes; (void)n_in; (void)out_size;

    dim3 blk(256);

    // ---- Phase 1: embeddings + weight prep (gate GEMMs run in fused(0)) ----
    gemm_f32<false, 0, 0><<<dim3(4, 256, 1), blk, 0, stream>>>(
        mdp, 128, 0, emb_W, 256, 0, emb_b, Mbuf, 256, 0, 16384, 256, 128);
    seq_major<<<dim3(16384), blk, 0, stream>>>(Mbuf, Mseq);
    pack_w<<<dim3(96, 3, 1), blk, 0, stream>>>(
        gfw_Whh, gbw_Whh, cell_Whh,
        (unsigned short*)PKf, (unsigned short*)PKb, (unsigned short*)PKc);
    combine_bias<<<dim3(3), blk, 0, stream>>>(gfw_bih, gfw_bhh, gbw_bih, gbw_bhh,
                                              cell_bih, cell_bhh, bias_f, bias_b, bias_c);

    // ---- Pipeline priming (x-path for chunks 0..3 partial) ----
    build_x<<<dim3(16384), dim3(320), 0, stream>>>(values, Mbuf, actions, a0, Xr[0], 0);
    gemm_f32<false, 1, 0><<<dim3(4, 256, 1), blk, 0, stream>>>(
        Xr[0], 320, 0, f0_W, 256, 0, f0_b, X0r[0], 256, 0, 16384, 256, 320);
    build_x<<<dim3(16384), dim3(320), 0, stream>>>(values, Mbuf, actions, a0, Xr[1], 64);
    gemm_f32<false, 1, 0><<<dim3(4, 256, 1), blk, 0, stream>>>(
        Xr[1], 320, 0, f0_W, 256, 0, f0_b, X0r[1], 256, 0, 16384, 256, 320);
    gemm_f32<false, 1, 0><<<dim3(4, 256, 1), blk, 0, stream>>>(
        X0r[0], 256, 0, f1_W, 256, 0, f1_b, X1r[0], 256, 0, 16384, 256, 256);
    build_x<<<dim3(16384), dim3(320), 0, stream>>>(values, Mbuf, actions, a0, Xr[0], 128);
    gemm_f32<false, 1, 0><<<dim3(4, 256, 1), blk, 0, stream>>>(
        Xr[0], 320, 0, f0_W, 256, 0, f0_b, X0r[0], 256, 0, 16384, 256, 320);
    gemm_f32<false, 1, 0><<<dim3(4, 256, 1), blk, 0, stream>>>(
        X0r[1], 256, 0, f1_W, 256, 0, f1_b, X1r[1], 256, 0, 16384, 256, 256);
    build_x<<<dim3(16384), dim3(320), 0, stream>>>(values, Mbuf, actions, a0, Xr[1], 192);
    gemm_f32<false, 0, 1><<<dim3(12, 256, 1), blk, 0, stream>>>(
        X1r[0], 256, 0, cell_Wih, 768, 0, bias_c, (float*)GIr[0], 768, 0, 16384, 768, 256);

    // ---- Fused pipeline (staggered roles):
    //   fused(c) = scan(c) | gateGEMMs(c==0) | kgru(c==1) | f0(c+3) | f1(c+2)
    //            | GI(c+1) | qg(c-1) | logits(c-2) | epi(c-3) | bx(c+4)
    for (int c = 0; c < NCHUNK; c++) {
        GemmRole g0{}, g1{}, g2{}, g3{}, g4{}, g5{};
        if (c <= 4) g0 = GemmRole{ Xr[(c + 1) & 1], f0_W, f0_b, X0r[(c + 1) & 1],
                                   320, 320, 256, 256, 1, 512, 2, 0 };
        if (c <= 5) g1 = GemmRole{ X0r[c & 1], f1_W, f1_b, X1r[c & 1],
                                   256, 256, 256, 256, 1, 512, 2, 0 };
        if (c <= 6) g2 = GemmRole{ X1r[(c + 1) & 1], cell_Wih, bias_c, (float*)GIr[(c + 1) & 1],
                                   256, 256, 768, 768, 0, 1536, 6, 1 };
        if (c >= 1) g3 = GemmRole{ Hallr[(c - 1) & 3], qg_W, qg_b, Qr[(c - 1) & 1],
                                   256, 256, 512, 512, 0, 1024, 4, 0 };
        if (c == 0) {
            g4 = GemmRole{ Mseq, gfw_Wih, bias_f, (float*)gfA, 256, 256, 768, 768, 0, 1536, 6, 1 };
            g5 = GemmRole{ Mseq, gbw_Wih, bias_b, (float*)gbA, 256, 256, 768, 768, 0, 1536, 6, 1 };
        }
        int kgn = (c == 1) ? 32 : 0;
        int lgn = (c >= 2) ? 128 : 0;
        int epn = (c >= 3) ? 2048 : 0;
        int bxn = (c <= 3) ? 128 : 0;
        int total = 16 + kgn + g0.nblocks + g1.nblocks + g2.nblocks + g3.nblocks
                    + g4.nblocks + g5.nblocks + lgn + epn + bxn;

        fused_k<<<dim3(total), dim3(512), 0, stream>>>(
            16, GIr[c & 1], (const unsigned short*)PKc, (c == 0) ? h0 : (const float*)hstate,
            Hallr[c & 3], hstate,
            kgn, gfA, gbA, (const unsigned short*)PKf, (const unsigned short*)PKb, Kbuf,
            g0, g1, g2, g3, g4, g5,
            lgn, Qr[(c - 2) & 1], Kbuf, Lr[(c - 2) & 1],
            epn, Hallr[(c - 3) & 3], Lr[(c - 3) & 1], (c - 3) * 64,
            bxn, values, Mbuf, actions, a0, Xr[c & 1], (c + 4) * 64,
            critic_W, critic_b, out);
    }

    // ---- Tail drain: T1 = qg(7) | logits(6) | epi(5) ----
    {
        GemmRole gz{}, g3t = GemmRole{ Hallr[3], qg_W, qg_b, Qr[1],
                                       256, 256, 512, 512, 0, 1024, 4, 0 };
        fused_k<<<dim3(1024 + 128 + 2048), dim3(512), 0, stream>>>(
            0, GIr[0], (const unsigned short*)PKc, hstate, Hallr[0], hstate,
            0, gfA, gbA, (const unsigned short*)PKf, (const unsigned short*)PKb, Kbuf,
            gz, gz, gz, g3t, gz, gz,
            128, Qr[0], Kbuf, Lr[0],
            2048, Hallr[1], Lr[1], 5 * 64,
            0, values, Mbuf, actions, a0, Xr[0], 0,
            critic_W, critic_b, out);
    }
    // ---- T2 = logits(7) | epi(6) ----
    {
        GemmRole gz{};
        fused_k<<<dim3(128 + 2048), dim3(512), 0, stream>>>(
            0, GIr[0], (const unsigned short*)PKc, hstate, Hallr[0], hstate,
            0, gfA, gbA, (const unsigned short*)PKf, (const unsigned short*)PKb, Kbuf,
            gz, gz, gz, gz, gz, gz,
            128, Qr[1], Kbuf, Lr[1],
            2048, Hallr[2], Lr[0], 6 * 64,
            0, values, Mbuf, actions, a0, Xr[0], 0,
            critic_W, critic_b, out);
    }
    // ---- T3 = epi(7) ----
    epilogue_k<<<dim3(16384), dim3(64), 0, stream>>>(
        Hallr[3], Lr[1], actions, critic_W, critic_b, out, 7 * 64);
}

// Round 12
// 2237.968 us; speedup vs baseline: 2.6591x; 2.6591x over previous
//
#include <hip/hip_runtime.h>

// Problem constants (reference: T=512, N=256, H=256, HR=64, WC=128, V=64)
#define TSTEPS 512
#define NBATCH 256
#define HID    256
#define TCHUNK 64
#define NCHUNK 8

typedef __attribute__((ext_vector_type(8))) short bf16x8;
typedef __attribute__((ext_vector_type(4))) float f32x4;

__device__ __forceinline__ unsigned short f2b(float x) {
    union { float f; unsigned int u; } c; c.f = x;
    unsigned int u = c.u;
    return (unsigned short)((u + 0x7fffu + ((u >> 16) & 1u)) >> 16);
}
__device__ __forceinline__ float b2f(unsigned short u) {
    union { float f; unsigned int u; } c; c.u = ((unsigned int)u) << 16;
    return c.f;
}

__device__ __forceinline__ void gload_lds16(const float* g, float* l) {
    __builtin_amdgcn_global_load_lds(
        (const __attribute__((address_space(1))) unsigned int*)g,
        (__attribute__((address_space(3))) unsigned int*)l,
        16, 0, 0);
}
// ushort variants, PROVEN widths only (16B / 4B). LDS bases kept 16B-aligned.
__device__ __forceinline__ void gload_lds16u(const unsigned short* g, unsigned short* l) {
    __builtin_amdgcn_global_load_lds(
        (const __attribute__((address_space(1))) unsigned int*)g,
        (__attribute__((address_space(3))) unsigned int*)l,
        16, 0, 0);
}
__device__ __forceinline__ void gload_lds4u(const unsigned short* g, unsigned short* l) {
    __builtin_amdgcn_global_load_lds(
        (const __attribute__((address_space(1))) unsigned int*)g,
        (__attribute__((address_space(3))) unsigned int*)l,
        4, 0, 0);
}

// LDS bank-conflict mitigation for [row][32]-short GEMM tiles (v7, kept).
__device__ __forceinline__ int swzi(int row, int g) {
    return ((g ^ ((row >> 3) & 3)) << 3);
}

// ---------------------------------------------------------------------------
// Generic GEMM (256 thr): C = act(A@B + bias). Prologue use. Swizzled LDS.
// OBF=1: write bf16 (ushort) output, ldc in ushort units.
// ---------------------------------------------------------------------------
template<bool TRANS_B, int ACT, int OBF>
__global__ __launch_bounds__(256) void gemm_f32(
    const float* __restrict__ A, long lda, long sA,
    const float* __restrict__ B, long ldb, long sB,
    const float* __restrict__ bias,
    float* __restrict__ C, long ldc, long sC,
    int M, int N, int K)
{
    __shared__ __align__(16) unsigned short As[64][32];
    __shared__ __align__(16) unsigned short Bs[64][32];
    const int z = blockIdx.z;
    A += (long)z * sA; B += (long)z * sB; C += (long)z * sC;
    const int n0 = blockIdx.x * 64, m0 = blockIdx.y * 64;
    const int tid  = threadIdx.x;
    const int lane = tid & 63, w = tid >> 6;
    const int wr = (w >> 1) * 32, wc = (w & 1) * 32;

    f32x4 acc[2][2];
#pragma unroll
    for (int i = 0; i < 2; i++)
#pragma unroll
        for (int j = 0; j < 2; j++) acc[i][j] = (f32x4){0.f, 0.f, 0.f, 0.f};

    for (int k0 = 0; k0 < K; k0 += 32) {
        {
            const int r = tid >> 2, ck = (tid & 3) << 3;
            const float* s = A + (long)(m0 + r) * lda + k0 + ck;
            float4 v0 = *(const float4*)s, v1 = *(const float4*)(s + 4);
            unsigned short* d = &As[r][swzi(r, ck >> 3)];
            d[0] = f2b(v0.x); d[1] = f2b(v0.y); d[2] = f2b(v0.z); d[3] = f2b(v0.w);
            d[4] = f2b(v1.x); d[5] = f2b(v1.y); d[6] = f2b(v1.z); d[7] = f2b(v1.w);
        }
        if (TRANS_B) {
            const int r = tid >> 2, ck = (tid & 3) << 3;
            const float* s = B + (long)(n0 + r) * ldb + k0 + ck;
            float4 v0 = *(const float4*)s, v1 = *(const float4*)(s + 4);
            unsigned short* d = &Bs[r][swzi(r, ck >> 3)];
            d[0] = f2b(v0.x); d[1] = f2b(v0.y); d[2] = f2b(v0.z); d[3] = f2b(v0.w);
            d[4] = f2b(v1.x); d[5] = f2b(v1.y); d[6] = f2b(v1.z); d[7] = f2b(v1.w);
        } else {
            const int kk = tid >> 3, cn = (tid & 7) << 3;
            const float* s = B + (long)(k0 + kk) * ldb + n0 + cn;
            float4 v0 = *(const float4*)s, v1 = *(const float4*)(s + 4);
            const int sc = swzi(cn, kk >> 3) + (kk & 7);
            Bs[cn + 0][sc] = f2b(v0.x); Bs[cn + 1][sc] = f2b(v0.y);
            Bs[cn + 2][sc] = f2b(v0.z); Bs[cn + 3][sc] = f2b(v0.w);
            Bs[cn + 4][sc] = f2b(v1.x); Bs[cn + 5][sc] = f2b(v1.y);
            Bs[cn + 6][sc] = f2b(v1.z); Bs[cn + 7][sc] = f2b(v1.w);
        }
        __syncthreads();
        const int l15 = lane & 15, q = lane >> 4;
        bf16x8 a0 = *(const bf16x8*)&As[wr +      l15][swzi(wr +      l15, q)];
        bf16x8 a1 = *(const bf16x8*)&As[wr + 16 + l15][swzi(wr + 16 + l15, q)];
        bf16x8 b0 = *(const bf16x8*)&Bs[wc +      l15][swzi(wc +      l15, q)];
        bf16x8 b1 = *(const bf16x8*)&Bs[wc + 16 + l15][swzi(wc + 16 + l15, q)];
        acc[0][0] = __builtin_amdgcn_mfma_f32_16x16x32_bf16(a0, b0, acc[0][0], 0, 0, 0);
        acc[0][1] = __builtin_amdgcn_mfma_f32_16x16x32_bf16(a0, b1, acc[0][1], 0, 0, 0);
        acc[1][0] = __builtin_amdgcn_mfma_f32_16x16x32_bf16(a1, b0, acc[1][0], 0, 0, 0);
        acc[1][1] = __builtin_amdgcn_mfma_f32_16x16x32_bf16(a1, b1, acc[1][1], 0, 0, 0);
        __syncthreads();
    }
    const int cq = lane >> 4, cc = lane & 15;
#pragma unroll
    for (int i = 0; i < 2; i++)
#pragma unroll
        for (int j = 0; j < 2; j++) {
#pragma unroll
            for (int rg = 0; rg < 4; rg++) {
                int row = m0 + wr + i * 16 + cq * 4 + rg;
                int col = n0 + wc + j * 16 + cc;
                float v = acc[i][j][rg];
                if (bias) v += bias[col];
                if (ACT == 1) v = v > 0.f ? v : 0.f;
                if (OBF) ((unsigned short*)C)[(long)row * ldc + col] = f2b(v);
                else     C[(long)row * ldc + col] = v;
            }
        }
}

// ---------------------------------------------------------------------------
// Helpers
// ---------------------------------------------------------------------------
__global__ void combine_bias(const float* a0, const float* b0,
                             const float* a1, const float* b1,
                             const float* a2, const float* b2,
                             float* o0, float* o1, float* o2)
{
    int i = blockIdx.x * 256 + threadIdx.x;
    o0[i] = a0[i] + b0[i];
    o1[i] = a1[i] + b1[i];
    o2[i] = a2[i] + b2[i];
}

__global__ void seq_major(const float* __restrict__ M, float* __restrict__ Mseq)
{
    int b = blockIdx.x;
    int s = b >> 8, n = b & 255;
    int t = threadIdx.x;
    Mseq[(long)b * 256 + t] = M[((long)n * 64 + s) * 256 + t];
}

// ---------------------------------------------------------------------------
// pack_w: 8-wave scan fragment layout (v3/v7, proven).
// ---------------------------------------------------------------------------
__global__ __launch_bounds__(256) void pack_w(
    const float* __restrict__ Wf, const float* __restrict__ Wb, const float* __restrict__ Wc,
    unsigned short* __restrict__ Pf, unsigned short* __restrict__ Pb, unsigned short* __restrict__ Pc)
{
    int chunk = blockIdx.x * 256 + threadIdx.x;      // 0..24575
    const float* W = (blockIdx.y == 0) ? Wf : ((blockIdx.y == 1) ? Wb : Wc);
    unsigned short* P = (blockIdx.y == 0) ? Pf : ((blockIdx.y == 1) ? Pb : Pc);
    int lane = chunk & 63;
    int kt   = (chunk >> 6) & 7;
    int f    = (chunk >> 9) % 6;
    int w    = chunk / 3072;
    int g = f >> 1, hh = f & 1;
    int c = lane & 15, q = lane >> 4;
    int col = g * 256 + w * 32 + hh * 16 + c;
    int k0  = kt * 32 + q * 8;
    unsigned int v[8];
#pragma unroll
    for (int j = 0; j < 8; j++) v[j] = f2b(W[(long)(k0 + j) * 768 + col]);
    uint4 o;
    o.x = v[0] | (v[1] << 16); o.y = v[2] | (v[3] << 16);
    o.z = v[4] | (v[5] << 16); o.w = v[6] | (v[7] << 16);
    *(uint4*)&P[(long)chunk * 8] = o;
}

__global__ void build_x(const float* __restrict__ values, const float* __restrict__ Mbuf,
                        const int* __restrict__ actions, const int* __restrict__ a0,
                        float* __restrict__ Xc, int t0)
{
    int m = blockIdx.x;
    int tl = m >> 8, n = m & 255;
    int t = t0 + tl;
    int c = threadIdx.x;
    float v;
    if (c < 64) {
        v = values[((long)t * 256 + n) * 64 + c];
    } else {
        int ap = (t == 0) ? a0[n] : actions[(long)(t - 1) * 256 + n];
        v = Mbuf[((long)n * 64 + ap) * 256 + (c - 64)];
    }
    Xc[(long)m * 320 + c] = v;
}

// ---------------------------------------------------------------------------
// Fused kernel v12: identical to v11 except launch_bounds (512,2) — the
// register budget the scan codegen needs (VGPR 128 + AGPRs). Occupancy 2
// blocks/CU comes from LDS 66.6KB + VGPR 128 naturally, not from the bound.
// ---------------------------------------------------------------------------
struct GemmRole {
    const float* A; const float* B; const float* bias; float* C;
    int K; long lda; long ldb; long ldc; int act; int nblocks; int ntn; int obf;
};

union FusedLds {
    struct { unsigned short hbuf[2][16][264]; unsigned short gibuf[2][16 * 776]; } s;
    struct { unsigned short As[64][32]; unsigned short Bs[128][32]; } g;
    struct { unsigned short As2[2][64][32]; unsigned short Bs2[2][64][32]; } l;
};

// ---- scan role: v3/v7 structure (8 waves, split-hh, fences, counted vmcnt);
// gi bf16: per-row {16B x64, 4B x64, 4B x64} chunks, 6 per wave per step. ----
__device__ __forceinline__ void scan_role(FusedLds* L,
    const unsigned short* gi, const unsigned short* PK, const float* h_init,
    float* outp, float* h_state, int n0, int steps, int kgru, int d)
{
    auto& hbuf  = L->s.hbuf;
    auto& gibuf = L->s.gibuf;
    const int tid = threadIdx.x;
    const int w = tid >> 6, lane = tid & 63;
    const int q = lane >> 4, c = lane & 15, q8 = q << 3;
    const int wcol = w * 32;

    bf16x8 Bf[6][8];
#pragma unroll
    for (int f = 0; f < 6; f++)
#pragma unroll
        for (int kt = 0; kt < 8; kt++)
            Bf[f][kt] = *(const bf16x8*)&PK[(((long)(w * 6 + f) * 8 + kt) * 64 + lane) * 8];

    f32x4 hreg[2];
#pragma unroll
    for (int hh = 0; hh < 2; hh++)
#pragma unroll
        for (int rg = 0; rg < 4; rg++) {
            float v = 0.f;
            if (!kgru) v = h_init[(long)(n0 + q * 4 + rg) * 256 + wcol + hh * 16 + c];
            hreg[hh][rg] = v;
            hbuf[1][q * 4 + rg][wcol + hh * 16 + c] = f2b(v);
        }

    const int row0 = kgru ? (d ? 63 : 0) : 0;
    const long gstride = (kgru && d) ? -196608L : 196608L;   // ushort units
    const unsigned short* gsrc = gi + ((long)row0 * 256 + n0) * 768;
    float* optr[4];
    long ostride;
    if (kgru) {
        ostride = d ? -512L : 512L;
#pragma unroll
        for (int rg = 0; rg < 4; rg++)
            optr[rg] = outp + ((long)(n0 + q * 4 + rg) * 64 + row0) * 512 + d * 256 + wcol + c;
    } else {
        ostride = 65536L;
#pragma unroll
        for (int rg = 0; rg < 4; rg++)
            optr[rg] = outp + (long)(n0 + q * 4 + rg) * 256 + wcol + c;
    }

    // prologue: gi[0] -> gibuf[0]; 48 chunks (16 rows x {1024B,256B,256B})
#pragma unroll
    for (int i = 0; i < 6; i++) {
        int idx = w * 6 + i;              // 0..47
        int r = idx / 3, kd = idx % 3;
        if (kd == 0)
            gload_lds16u(gsrc + (long)r * 768 + lane * 8, &gibuf[0][r * 776]);
        else if (kd == 1)
            gload_lds4u(gsrc + (long)r * 768 + 512 + lane * 2, &gibuf[0][r * 776 + 512]);
        else
            gload_lds4u(gsrc + (long)r * 768 + 640 + lane * 2, &gibuf[0][r * 776 + 640]);
    }
    __syncthreads();

    for (int s = 0; s < steps; s++) {
        const int cur = s & 1;
        if (s + 1 < steps) {
            const unsigned short* src = gsrc + gstride;
#pragma unroll
            for (int i = 0; i < 6; i++) {
                int idx = w * 6 + i;
                int r = idx / 3, kd = idx % 3;
                if (kd == 0)
                    gload_lds16u(src + (long)r * 768 + lane * 8, &gibuf[cur ^ 1][r * 776]);
                else if (kd == 1)
                    gload_lds4u(src + (long)r * 768 + 512 + lane * 2, &gibuf[cur ^ 1][r * 776 + 512]);
                else
                    gload_lds4u(src + (long)r * 768 + 640 + lane * 2, &gibuf[cur ^ 1][r * 776 + 640]);
            }
        }
        gsrc += gstride;
        asm volatile("" ::: "memory");

        const unsigned short* hrd = &hbuf[cur ^ 1][0][0];
        const unsigned short* gp = &gibuf[cur][(q * 4) * 776 + wcol + c];
        unsigned short* hwr = &hbuf[cur][q * 4][wcol + c];

#pragma unroll
        for (int hh = 0; hh < 2; hh++) {
            f32x4 ar = (f32x4){0.f, 0.f, 0.f, 0.f};
            f32x4 az = (f32x4){0.f, 0.f, 0.f, 0.f};
            f32x4 an = (f32x4){0.f, 0.f, 0.f, 0.f};
#pragma unroll
            for (int kt = 0; kt < 8; kt++) {
                bf16x8 a = *(const bf16x8*)&hrd[c * 264 + kt * 32 + q8];
                ar = __builtin_amdgcn_mfma_f32_16x16x32_bf16(a, Bf[0 + hh][kt], ar, 0, 0, 0);
                az = __builtin_amdgcn_mfma_f32_16x16x32_bf16(a, Bf[2 + hh][kt], az, 0, 0, 0);
                an = __builtin_amdgcn_mfma_f32_16x16x32_bf16(a, Bf[4 + hh][kt], an, 0, 0, 0);
            }
#pragma unroll
            for (int rg = 0; rg < 4; rg++) {
                float gr = b2f(gp[rg * 776 +       hh * 16]);
                float gz = b2f(gp[rg * 776 + 256 + hh * 16]);
                float gn = b2f(gp[rg * 776 + 512 + hh * 16]);
                float r  = __builtin_amdgcn_rcpf(1.f + __expf(-(gr + ar[rg])));
                float zg = __builtin_amdgcn_rcpf(1.f + __expf(-(gz + az[rg])));
                float nn = 1.f - 2.f * __builtin_amdgcn_rcpf(1.f + __expf(2.f * (gn + r * an[rg])));
                float hv = (1.f - zg) * nn + zg * hreg[hh][rg];
                hreg[hh][rg] = hv;
                hwr[rg * 264 + hh * 16] = f2b(hv);
                optr[rg][hh * 16] = hv;
            }
            asm volatile("" ::: "memory");
        }

#pragma unroll
        for (int rg = 0; rg < 4; rg++) optr[rg] += ostride;

        // 6 gi loads + 8 stores issued; vmcnt(8) retires the loads only.
        asm volatile("s_waitcnt vmcnt(8) lgkmcnt(0)" ::: "memory");
        __builtin_amdgcn_sched_barrier(0);
        __builtin_amdgcn_s_barrier();
        __builtin_amdgcn_sched_barrier(0);
    }

    if (!kgru) {
#pragma unroll
        for (int hh = 0; hh < 2; hh++)
#pragma unroll
            for (int rg = 0; rg < 4; rg++)
                h_state[(long)(n0 + q * 4 + rg) * 256 + wcol + hh * 16 + c] = hreg[hh][rg];
    }
}

// ---- gemm role: 512-thread 64x128 tile, B stored (K,N), swizzled LDS ----
__device__ __forceinline__ void gemm_role(FusedLds* L, const GemmRole& R, int rb)
{
    auto& As = L->g.As;
    auto& Bs = L->g.Bs;
    const int tid = threadIdx.x;
    const int lane = tid & 63, w = tid >> 6;
    const int mt = rb / R.ntn, nt = rb % R.ntn;
    const long m0 = (long)mt * 64, n0 = (long)nt * 128;
    const int wr = (w >> 2) * 32, wc = (w & 3) * 32;

    f32x4 acc[2][2];
#pragma unroll
    for (int i = 0; i < 2; i++)
#pragma unroll
        for (int j = 0; j < 2; j++) acc[i][j] = (f32x4){0.f, 0.f, 0.f, 0.f};

    for (int k0 = 0; k0 < R.K; k0 += 32) {
        {
            const int r = tid >> 3, ck = (tid & 7) << 2;
            const float* s = R.A + (m0 + r) * R.lda + k0 + ck;
            float4 v = *(const float4*)s;
            unsigned short* dp = &As[r][swzi(r, ck >> 3) + (ck & 7)];
            dp[0] = f2b(v.x); dp[1] = f2b(v.y); dp[2] = f2b(v.z); dp[3] = f2b(v.w);
        }
        {
            const int kk = tid >> 4, cn = (tid & 15) << 3;
            const float* s = R.B + (long)(k0 + kk) * R.ldb + n0 + cn;
            float4 v0 = *(const float4*)s, v1 = *(const float4*)(s + 4);
            const int sc = swzi(cn, kk >> 3) + (kk & 7);
            Bs[cn + 0][sc] = f2b(v0.x); Bs[cn + 1][sc] = f2b(v0.y);
            Bs[cn + 2][sc] = f2b(v0.z); Bs[cn + 3][sc] = f2b(v0.w);
            Bs[cn + 4][sc] = f2b(v1.x); Bs[cn + 5][sc] = f2b(v1.y);
            Bs[cn + 6][sc] = f2b(v1.z); Bs[cn + 7][sc] = f2b(v1.w);
        }
        __syncthreads();
        const int l15 = lane & 15, q = lane >> 4;
        bf16x8 a0 = *(const bf16x8*)&As[wr +      l15][swzi(wr +      l15, q)];
        bf16x8 a1 = *(const bf16x8*)&As[wr + 16 + l15][swzi(wr + 16 + l15, q)];
        bf16x8 b0 = *(const bf16x8*)&Bs[wc +      l15][swzi(wc +      l15, q)];
        bf16x8 b1 = *(const bf16x8*)&Bs[wc + 16 + l15][swzi(wc + 16 + l15, q)];
        acc[0][0] = __builtin_amdgcn_mfma_f32_16x16x32_bf16(a0, b0, acc[0][0], 0, 0, 0);
        acc[0][1] = __builtin_amdgcn_mfma_f32_16x16x32_bf16(a0, b1, acc[0][1], 0, 0, 0);
        acc[1][0] = __builtin_amdgcn_mfma_f32_16x16x32_bf16(a1, b0, acc[1][0], 0, 0, 0);
        acc[1][1] = __builtin_amdgcn_mfma_f32_16x16x32_bf16(a1, b1, acc[1][1], 0, 0, 0);
        __syncthreads();
    }
    const int cq = lane >> 4, cc = lane & 15;
#pragma unroll
    for (int i = 0; i < 2; i++)
#pragma unroll
        for (int j = 0; j < 2; j++) {
#pragma unroll
            for (int rg = 0; rg < 4; rg++) {
                long row = m0 + wr + i * 16 + cq * 4 + rg;
                long col = n0 + wc + j * 16 + cc;
                float v = acc[i][j][rg];
                if (R.bias) v += R.bias[col];
                if (R.act == 1) v = v > 0.f ? v : 0.f;
                if (R.obf) ((unsigned short*)R.C)[row * R.ldc + col] = f2b(v);
                else       R.C[row * R.ldc + col] = v;
            }
        }
}

// ---- logits role: dual-z 64x64x512 GEMM (both halves barrier-identical) ----
__device__ __forceinline__ void logits_role(FusedLds* L, int rb,
    const float* Qs, const float* Kb, float* Lout)
{
    auto& As = L->l.As2;
    auto& Bs = L->l.Bs2;
    const int tid = threadIdx.x;
    const int half = tid >> 8, htid = tid & 255;
    const int z = rb * 2 + half;
    const float* A = Qs + (long)z * 512;
    const float* B = Kb + (long)z * 32768;
    float* C = Lout + (long)z * 64;
    const int lane = htid & 63, w4 = htid >> 6;
    const int wr = (w4 >> 1) * 32, wc = (w4 & 1) * 32;

    f32x4 acc[2][2];
#pragma unroll
    for (int i = 0; i < 2; i++)
#pragma unroll
        for (int j = 0; j < 2; j++) acc[i][j] = (f32x4){0.f, 0.f, 0.f, 0.f};

    for (int k0 = 0; k0 < 512; k0 += 32) {
        const int r = htid >> 2, ck = (htid & 3) << 3;
        {
            const float* s = A + (long)r * 131072 + k0 + ck;
            float4 v0 = *(const float4*)s, v1 = *(const float4*)(s + 4);
            unsigned short* d = &As[half][r][swzi(r, ck >> 3)];
            d[0] = f2b(v0.x); d[1] = f2b(v0.y); d[2] = f2b(v0.z); d[3] = f2b(v0.w);
            d[4] = f2b(v1.x); d[5] = f2b(v1.y); d[6] = f2b(v1.z); d[7] = f2b(v1.w);
        }
        {
            const float* s = B + (long)r * 512 + k0 + ck;
            float4 v0 = *(const float4*)s, v1 = *(const float4*)(s + 4);
            unsigned short* d = &Bs[half][r][swzi(r, ck >> 3)];
            d[0] = f2b(v0.x); d[1] = f2b(v0.y); d[2] = f2b(v0.z); d[3] = f2b(v0.w);
            d[4] = f2b(v1.x); d[5] = f2b(v1.y); d[6] = f2b(v1.z); d[7] = f2b(v1.w);
        }
        __syncthreads();
        const int l15 = lane & 15, q = lane >> 4;
        bf16x8 a0 = *(const bf16x8*)&As[half][wr +      l15][swzi(wr +      l15, q)];
        bf16x8 a1 = *(const bf16x8*)&As[half][wr + 16 + l15][swzi(wr + 16 + l15, q)];
        bf16x8 b0 = *(const bf16x8*)&Bs[half][wc +      l15][swzi(wc +      l15, q)];
        bf16x8 b1 = *(const bf16x8*)&Bs[half][wc + 16 + l15][swzi(wc + 16 + l15, q)];
        acc[0][0] = __builtin_amdgcn_mfma_f32_16x16x32_bf16(a0, b0, acc[0][0], 0, 0, 0);
        acc[0][1] = __builtin_amdgcn_mfma_f32_16x16x32_bf16(a0, b1, acc[0][1], 0, 0, 0);
        acc[1][0] = __builtin_amdgcn_mfma_f32_16x16x32_bf16(a1, b0, acc[1][0], 0, 0, 0);
        acc[1][1] = __builtin_amdgcn_mfma_f32_16x16x32_bf16(a1, b1, acc[1][1], 0, 0, 0);
        __syncthreads();
    }
    const int cq = lane >> 4, cc = lane & 15;
#pragma unroll
    for (int i = 0; i < 2; i++)
#pragma unroll
        for (int j = 0; j < 2; j++) {
#pragma unroll
            for (int rg = 0; rg < 4; rg++)
                C[(long)(wr + i * 16 + cq * 4 + rg) * 16384 + wc + j * 16 + cc] = acc[i][j][rg];
        }
}

// ---- epilogue role: per warp, one (t,n); no barriers ----
__device__ __forceinline__ void epi_role(int rb,
    const float* Hall, const float* Lc, const int* actions,
    const float* critic_W, const float* critic_b, float* out, int t0)
{
    const int w = threadIdx.x >> 6, j = threadIdx.x & 63;
    const int m = rb * 8 + w;
    const int tl = m >> 8, n = m & 255;
    const int t = t0 + tl;
    long o = ((long)t * 256 + n) * 322;
    const float* h = Hall + (long)m * 256;
    float part = 0.f;
#pragma unroll
    for (int i = 0; i < 4; i++) {
        float hv = h[j + 64 * i];
        out[o + 2 + j + 64 * i] = hv;
        part += hv * critic_W[j + 64 * i];
    }
    for (int off = 32; off > 0; off >>= 1) part += __shfl_down(part, off);
    if (j == 0) {
        out[o]     = (float)actions[(long)t * 256 + n];
        out[o + 1] = part + critic_b[0];
    }
    float x = Lc[(long)m * 64 + j];
    float mx = x;
    for (int off = 32; off > 0; off >>= 1) mx = fmaxf(mx, __shfl_down(mx, off));
    mx = __shfl(mx, 0);
    float e = __expf(x - mx);
    float ssum = e;
    for (int off = 32; off > 0; off >>= 1) ssum += __shfl_down(ssum, off);
    ssum = __shfl(ssum, 0);
    out[o + 258 + j] = e / ssum;
}

// ---- build_x role ----
__device__ __forceinline__ void bx_role(int rb,
    const float* values, const float* Mbuf, const int* actions, const int* a0,
    float* Xd, int t0)
{
    const int tid = threadIdx.x;
    if (tid >= 320) return;
    for (int rr = 0; rr < 128; rr++) {
        int m = rb * 128 + rr;
        int tl = m >> 8, n = m & 255;
        int t = t0 + tl;
        float v;
        if (tid < 64) {
            v = values[((long)t * 256 + n) * 64 + tid];
        } else {
            int ap = (t == 0) ? a0[n] : actions[(long)(t - 1) * 256 + n];
            v = Mbuf[((long)n * 64 + ap) * 256 + (tid - 64)];
        }
        Xd[(long)m * 320 + tid] = v;
    }
}

__global__ __launch_bounds__(512, 2) void fused_k(
    int sc_nblk, const unsigned short* sc_gi, const unsigned short* sc_PK,
    const float* sc_hinit, float* sc_out, float* sc_hstate,
    int kgru_nblk, const unsigned short* kg_gi0, const unsigned short* kg_gi1,
    const unsigned short* kg_PK0, const unsigned short* kg_PK1, float* kg_out,
    GemmRole g0, GemmRole g1, GemmRole g2, GemmRole g3, GemmRole g4, GemmRole g5,
    int lg_nblk, const float* lg_Q, const float* lg_K, float* lg_L,
    int ep_nblk, const float* ep_Hall, const float* ep_L, int ep_t0,
    int bx_nblk, const float* values, const float* Mbuf,
    const int* actions, const int* a0, float* bx_dst, int bx_t0,
    const float* critic_W, const float* critic_b, float* out)
{
    __shared__ __align__(16) FusedLds L;
    int b = blockIdx.x;
    if (b < sc_nblk) {
        scan_role(&L, sc_gi, sc_PK, sc_hinit, sc_out, sc_hstate, b * 16, TCHUNK, 0, 0);
        return;
    }
    b -= sc_nblk;
    if (b < kgru_nblk) {
        int d = b >> 4, n0 = (b & 15) * 16;
        scan_role(&L, d ? kg_gi1 : kg_gi0, d ? kg_PK1 : kg_PK0, nullptr,
                  kg_out, nullptr, n0, 64, 1, d);
        return;
    }
    b -= kgru_nblk;
    if (b < g0.nblocks) { gemm_role(&L, g0, b); return; }
    b -= g0.nblocks;
    if (b < g1.nblocks) { gemm_role(&L, g1, b); return; }
    b -= g1.nblocks;
    if (b < g2.nblocks) { gemm_role(&L, g2, b); return; }
    b -= g2.nblocks;
    if (b < g3.nblocks) { gemm_role(&L, g3, b); return; }
    b -= g3.nblocks;
    if (b < g4.nblocks) { gemm_role(&L, g4, b); return; }
    b -= g4.nblocks;
    if (b < g5.nblocks) { gemm_role(&L, g5, b); return; }
    b -= g5.nblocks;
    if (b < lg_nblk) { logits_role(&L, b, lg_Q, lg_K, lg_L); return; }
    b -= lg_nblk;
    if (b < ep_nblk) { epi_role(b, ep_Hall, ep_L, actions, critic_W, critic_b, out, ep_t0); return; }
    b -= ep_nblk;
    if (b < bx_nblk) bx_role(b, values, Mbuf, actions, a0, bx_dst, bx_t0);
}

// ---------------------------------------------------------------------------
// Epilogue kernel (final tail use)
// ---------------------------------------------------------------------------
__global__ __launch_bounds__(64) void epilogue_k(
    const float* __restrict__ Hallc, const float* __restrict__ Lc,
    const int* __restrict__ actions,
    const float* __restrict__ critic_W, const float* __restrict__ critic_b,
    float* __restrict__ out, int t0)
{
    int m = blockIdx.x;
    int tl = m >> 8, n = m & 255;
    int t = t0 + tl;
    int j = threadIdx.x;
    long o = ((long)t * 256 + n) * 322;
    const float* h = Hallc + (long)m * 256;
    float part = 0.f;
#pragma unroll
    for (int i = 0; i < 4; i++) {
        float hv = h[j + 64 * i];
        out[o + 2 + j + 64 * i] = hv;
        part += hv * critic_W[j + 64 * i];
    }
    for (int off = 32; off > 0; off >>= 1) part += __shfl_down(part, off);
    if (j == 0) {
        out[o]     = (float)actions[(long)t * 256 + n];
        out[o + 1] = part + critic_b[0];
    }
    float x = Lc[(long)m * 64 + j];
    float mx = x;
    for (int off = 32; off > 0; off >>= 1) mx = fmaxf(mx, __shfl_down(mx, off));
    mx = __shfl(mx, 0);
    float e = __expf(x - mx);
    float ssum = e;
    for (int off = 32; off > 0; off >>= 1) ssum += __shfl_down(ssum, off);
    ssum = __shfl(ssum, 0);
    out[o + 258 + j] = e / ssum;
}

// ---------------------------------------------------------------------------
extern "C" void kernel_launch(void* const* d_in, const int* in_sizes, int n_in,
                              void* d_out, int out_size, void* d_ws, size_t ws_size,
                              hipStream_t stream)
{
    const float* values   = (const float*)d_in[0];
    const float* mdp      = (const float*)d_in[1];
    const int*   actions  = (const int*)  d_in[2];
    const int*   a0       = (const int*)  d_in[3];
    const float* h0       = (const float*)d_in[4];
    const float* emb_W    = (const float*)d_in[5];
    const float* emb_b    = (const float*)d_in[6];
    const float* gfw_Wih  = (const float*)d_in[7];
    const float* gfw_Whh  = (const float*)d_in[8];
    const float* gfw_bih  = (const float*)d_in[9];
    const float* gfw_bhh  = (const float*)d_in[10];
    const float* gbw_Wih  = (const float*)d_in[11];
    const float* gbw_Whh  = (const float*)d_in[12];
    const float* gbw_bih  = (const float*)d_in[13];
    const float* gbw_bhh  = (const float*)d_in[14];
    const float* f0_W     = (const float*)d_in[15];
    const float* f0_b     = (const float*)d_in[16];
    const float* f1_W     = (const float*)d_in[17];
    const float* f1_b     = (const float*)d_in[18];
    const float* cell_Wih = (const float*)d_in[19];
    const float* cell_Whh = (const float*)d_in[20];
    const float* cell_bih = (const float*)d_in[21];
    const float* cell_bhh = (const float*)d_in[22];
    const float* critic_W = (const float*)d_in[23];
    const float* critic_b = (const float*)d_in[24];
    const float* qg_W     = (const float*)d_in[25];
    const float* qg_b     = (const float*)d_in[26];
    float* out = (float*)d_out;

    char* base = (char*)d_ws;
    size_t off = 0;
    auto alloc = [&](size_t nf) -> float* {
        float* p = (float*)(base + off);
        off += nf * sizeof(float);
        off = (off + 255) & ~(size_t)255;
        return p;
    };
    float* Mbuf   = alloc(16384ull * 256);
    float* Mseq   = alloc(16384ull * 256);   // aliased as Hallr[2] (dead after fused(0))
    unsigned short* gfA = (unsigned short*)alloc(16384ull * 384);  // bf16 16384x768
    unsigned short* gbA = (unsigned short*)alloc(16384ull * 384);
    float* Kbuf   = alloc(256ull * 64 * 512);
    float* PKf    = alloc(98304);
    float* PKb    = alloc(98304);
    float* PKc    = alloc(98304);
    float* hstate = alloc(256ull * 256);
    float* Xr[2]    = { alloc(16384ull * 320), alloc(16384ull * 320) };
    float* X0r[2]   = { alloc(16384ull * 256), alloc(16384ull * 256) };
    float* X1r[2]   = { alloc(16384ull * 256), alloc(16384ull * 256) };
    unsigned short* GIr[2] = { (unsigned short*)alloc(16384ull * 384),
                               (unsigned short*)alloc(16384ull * 384) };  // bf16
    float* Hallr[4] = { alloc(16384ull * 256), alloc(16384ull * 256),
                        Mseq, alloc(16384ull * 256) };
    float* Qr[2]  = { alloc(16384ull * 512), alloc(16384ull * 512) };
    float* Lr[2]  = { alloc(16384ull * 64), alloc(16384ull * 64) };
    float* bias_f = alloc(768);
    float* bias_b = alloc(768);
    float* bias_c = alloc(768);
    (void)ws_size; (void)in_sizes; (void)n_in; (void)out_size;

    dim3 blk(256);

    // ---- Phase 1: embeddings + weight prep (gate GEMMs run in fused(0)) ----
    gemm_f32<false, 0, 0><<<dim3(4, 256, 1), blk, 0, stream>>>(
        mdp, 128, 0, emb_W, 256, 0, emb_b, Mbuf, 256, 0, 16384, 256, 128);
    seq_major<<<dim3(16384), blk, 0, stream>>>(Mbuf, Mseq);
    pack_w<<<dim3(96, 3, 1), blk, 0, stream>>>(
        gfw_Whh, gbw_Whh, cell_Whh,
        (unsigned short*)PKf, (unsigned short*)PKb, (unsigned short*)PKc);
    combine_bias<<<dim3(3), blk, 0, stream>>>(gfw_bih, gfw_bhh, gbw_bih, gbw_bhh,
                                              cell_bih, cell_bhh, bias_f, bias_b, bias_c);

    // ---- Pipeline priming (x-path for chunks 0..3 partial) ----
    build_x<<<dim3(16384), dim3(320), 0, stream>>>(values, Mbuf, actions, a0, Xr[0], 0);
    gemm_f32<false, 1, 0><<<dim3(4, 256, 1), blk, 0, stream>>>(
        Xr[0], 320, 0, f0_W, 256, 0, f0_b, X0r[0], 256, 0, 16384, 256, 320);
    build_x<<<dim3(16384), dim3(320), 0, stream>>>(values, Mbuf, actions, a0, Xr[1], 64);
    gemm_f32<false, 1, 0><<<dim3(4, 256, 1), blk, 0, stream>>>(
        Xr[1], 320, 0, f0_W, 256, 0, f0_b, X0r[1], 256, 0, 16384, 256, 320);
    gemm_f32<false, 1, 0><<<dim3(4, 256, 1), blk, 0, stream>>>(
        X0r[0], 256, 0, f1_W, 256, 0, f1_b, X1r[0], 256, 0, 16384, 256, 256);
    build_x<<<dim3(16384), dim3(320), 0, stream>>>(values, Mbuf, actions, a0, Xr[0], 128);
    gemm_f32<false, 1, 0><<<dim3(4, 256, 1), blk, 0, stream>>>(
        Xr[0], 320, 0, f0_W, 256, 0, f0_b, X0r[0], 256, 0, 16384, 256, 320);
    gemm_f32<false, 1, 0><<<dim3(4, 256, 1), blk, 0, stream>>>(
        X0r[1], 256, 0, f1_W, 256, 0, f1_b, X1r[1], 256, 0, 16384, 256, 256);
    build_x<<<dim3(16384), dim3(320), 0, stream>>>(values, Mbuf, actions, a0, Xr[1], 192);
    gemm_f32<false, 0, 1><<<dim3(12, 256, 1), blk, 0, stream>>>(
        X1r[0], 256, 0, cell_Wih, 768, 0, bias_c, (float*)GIr[0], 768, 0, 16384, 768, 256);

    // ---- Fused pipeline (staggered roles):
    //   fused(c) = scan(c) | gateGEMMs(c==0) | kgru(c==1) | f0(c+3) | f1(c+2)
    //            | GI(c+1) | qg(c-1) | logits(c-2) | epi(c-3) | bx(c+4)
    for (int c = 0; c < NCHUNK; c++) {
        GemmRole g0{}, g1{}, g2{}, g3{}, g4{}, g5{};
        if (c <= 4) g0 = GemmRole{ Xr[(c + 1) & 1], f0_W, f0_b, X0r[(c + 1) & 1],
                                   320, 320, 256, 256, 1, 512, 2, 0 };
        if (c <= 5) g1 = GemmRole{ X0r[c & 1], f1_W, f1_b, X1r[c & 1],
                                   256, 256, 256, 256, 1, 512, 2, 0 };
        if (c <= 6) g2 = GemmRole{ X1r[(c + 1) & 1], cell_Wih, bias_c, (float*)GIr[(c + 1) & 1],
                                   256, 256, 768, 768, 0, 1536, 6, 1 };
        if (c >= 1) g3 = GemmRole{ Hallr[(c - 1) & 3], qg_W, qg_b, Qr[(c - 1) & 1],
                                   256, 256, 512, 512, 0, 1024, 4, 0 };
        if (c == 0) {
            g4 = GemmRole{ Mseq, gfw_Wih, bias_f, (float*)gfA, 256, 256, 768, 768, 0, 1536, 6, 1 };
            g5 = GemmRole{ Mseq, gbw_Wih, bias_b, (float*)gbA, 256, 256, 768, 768, 0, 1536, 6, 1 };
        }
        int kgn = (c == 1) ? 32 : 0;
        int lgn = (c >= 2) ? 128 : 0;
        int epn = (c >= 3) ? 2048 : 0;
        int bxn = (c <= 3) ? 128 : 0;
        int total = 16 + kgn + g0.nblocks + g1.nblocks + g2.nblocks + g3.nblocks
                    + g4.nblocks + g5.nblocks + lgn + epn + bxn;

        fused_k<<<dim3(total), dim3(512), 0, stream>>>(
            16, GIr[c & 1], (const unsigned short*)PKc, (c == 0) ? h0 : (const float*)hstate,
            Hallr[c & 3], hstate,
            kgn, gfA, gbA, (const unsigned short*)PKf, (const unsigned short*)PKb, Kbuf,
            g0, g1, g2, g3, g4, g5,
            lgn, Qr[(c - 2) & 1], Kbuf, Lr[(c - 2) & 1],
            epn, Hallr[(c - 3) & 3], Lr[(c - 3) & 1], (c - 3) * 64,
            bxn, values, Mbuf, actions, a0, Xr[c & 1], (c + 4) * 64,
            critic_W, critic_b, out);
    }

    // ---- Tail drain: T1 = qg(7) | logits(6) | epi(5) ----
    {
        GemmRole gz{}, g3t = GemmRole{ Hallr[3], qg_W, qg_b, Qr[1],
                                       256, 256, 512, 512, 0, 1024, 4, 0 };
        fused_k<<<dim3(1024 + 128 + 2048), dim3(512), 0, stream>>>(
            0, GIr[0], (const unsigned short*)PKc, hstate, Hallr[0], hstate,
            0, gfA, gbA, (const unsigned short*)PKf, (const unsigned short*)PKb, Kbuf,
            gz, gz, gz, g3t, gz, gz,
            128, Qr[0], Kbuf, Lr[0],
            2048, Hallr[1], Lr[1], 5 * 64,
            0, values, Mbuf, actions, a0, Xr[0], 0,
            critic_W, critic_b, out);
    }
    // ---- T2 = logits(7) | epi(6) ----
    {
        GemmRole gz{};
        fused_k<<<dim3(128 + 2048), dim3(512), 0, stream>>>(
            0, GIr[0], (const unsigned short*)PKc, hstate, Hallr[0], hstate,
            0, gfA, gbA, (const unsigned short*)PKf, (const unsigned short*)PKb, Kbuf,
            gz, gz, gz, gz, gz, gz,
            128, Qr[1], Kbuf, Lr[1],
            2048, Hallr[2], Lr[0], 6 * 64,
            0, values, Mbuf, actions, a0, Xr[0], 0,
            critic_W, critic_b, out);
    }
    // ---- T3 = epi(7) ----
    epilogue_k<<<dim3(16384), dim3(64), 0, stream>>>(
        Hallr[3], Lr[1], actions, critic_W, critic_b, out, 7 * 64);
}

// Round 13
// 2150.508 us; speedup vs baseline: 2.7672x; 1.0407x over previous
//
#include <hip/hip_runtime.h>

// Problem constants (reference: T=512, N=256, H=256, HR=64, WC=128, V=64)
#define TSTEPS 512
#define NBATCH 256
#define HID    256
#define TCHUNK 64
#define NCHUNK 8

typedef __attribute__((ext_vector_type(8))) short bf16x8;
typedef __attribute__((ext_vector_type(4))) float f32x4;

__device__ __forceinline__ unsigned short f2b(float x) {
    union { float f; unsigned int u; } c; c.f = x;
    unsigned int u = c.u;
    return (unsigned short)((u + 0x7fffu + ((u >> 16) & 1u)) >> 16);
}

__device__ __forceinline__ void gload_lds16(const float* g, float* l) {
    __builtin_amdgcn_global_load_lds(
        (const __attribute__((address_space(1))) unsigned int*)g,
        (__attribute__((address_space(3))) unsigned int*)l,
        16, 0, 0);
}

// LDS bank-conflict mitigation for [row][32]-short GEMM tiles (v7, kept).
__device__ __forceinline__ int swzi(int row, int g) {
    return ((g ^ ((row >> 3) & 3)) << 3);
}

// ---------------------------------------------------------------------------
// Generic GEMM (256 thr): C = act(A@B + bias). Prologue use. Swizzled LDS.
// ---------------------------------------------------------------------------
template<bool TRANS_B, int ACT>
__global__ __launch_bounds__(256) void gemm_f32(
    const float* __restrict__ A, long lda, long sA,
    const float* __restrict__ B, long ldb, long sB,
    const float* __restrict__ bias,
    float* __restrict__ C, long ldc, long sC,
    int M, int N, int K)
{
    __shared__ __align__(16) unsigned short As[64][32];
    __shared__ __align__(16) unsigned short Bs[64][32];
    const int z = blockIdx.z;
    A += (long)z * sA; B += (long)z * sB; C += (long)z * sC;
    const int n0 = blockIdx.x * 64, m0 = blockIdx.y * 64;
    const int tid  = threadIdx.x;
    const int lane = tid & 63, w = tid >> 6;
    const int wr = (w >> 1) * 32, wc = (w & 1) * 32;

    f32x4 acc[2][2];
#pragma unroll
    for (int i = 0; i < 2; i++)
#pragma unroll
        for (int j = 0; j < 2; j++) acc[i][j] = (f32x4){0.f, 0.f, 0.f, 0.f};

    for (int k0 = 0; k0 < K; k0 += 32) {
        {
            const int r = tid >> 2, ck = (tid & 3) << 3;
            const float* s = A + (long)(m0 + r) * lda + k0 + ck;
            float4 v0 = *(const float4*)s, v1 = *(const float4*)(s + 4);
            unsigned short* d = &As[r][swzi(r, ck >> 3)];
            d[0] = f2b(v0.x); d[1] = f2b(v0.y); d[2] = f2b(v0.z); d[3] = f2b(v0.w);
            d[4] = f2b(v1.x); d[5] = f2b(v1.y); d[6] = f2b(v1.z); d[7] = f2b(v1.w);
        }
        if (TRANS_B) {
            const int r = tid >> 2, ck = (tid & 3) << 3;
            const float* s = B + (long)(n0 + r) * ldb + k0 + ck;
            float4 v0 = *(const float4*)s, v1 = *(const float4*)(s + 4);
            unsigned short* d = &Bs[r][swzi(r, ck >> 3)];
            d[0] = f2b(v0.x); d[1] = f2b(v0.y); d[2] = f2b(v0.z); d[3] = f2b(v0.w);
            d[4] = f2b(v1.x); d[5] = f2b(v1.y); d[6] = f2b(v1.z); d[7] = f2b(v1.w);
        } else {
            const int kk = tid >> 3, cn = (tid & 7) << 3;
            const float* s = B + (long)(k0 + kk) * ldb + n0 + cn;
            float4 v0 = *(const float4*)s, v1 = *(const float4*)(s + 4);
            const int sc = swzi(cn, kk >> 3) + (kk & 7);
            Bs[cn + 0][sc] = f2b(v0.x); Bs[cn + 1][sc] = f2b(v0.y);
            Bs[cn + 2][sc] = f2b(v0.z); Bs[cn + 3][sc] = f2b(v0.w);
            Bs[cn + 4][sc] = f2b(v1.x); Bs[cn + 5][sc] = f2b(v1.y);
            Bs[cn + 6][sc] = f2b(v1.z); Bs[cn + 7][sc] = f2b(v1.w);
        }
        __syncthreads();
        const int l15 = lane & 15, q = lane >> 4;
        bf16x8 a0 = *(const bf16x8*)&As[wr +      l15][swzi(wr +      l15, q)];
        bf16x8 a1 = *(const bf16x8*)&As[wr + 16 + l15][swzi(wr + 16 + l15, q)];
        bf16x8 b0 = *(const bf16x8*)&Bs[wc +      l15][swzi(wc +      l15, q)];
        bf16x8 b1 = *(const bf16x8*)&Bs[wc + 16 + l15][swzi(wc + 16 + l15, q)];
        acc[0][0] = __builtin_amdgcn_mfma_f32_16x16x32_bf16(a0, b0, acc[0][0], 0, 0, 0);
        acc[0][1] = __builtin_amdgcn_mfma_f32_16x16x32_bf16(a0, b1, acc[0][1], 0, 0, 0);
        acc[1][0] = __builtin_amdgcn_mfma_f32_16x16x32_bf16(a1, b0, acc[1][0], 0, 0, 0);
        acc[1][1] = __builtin_amdgcn_mfma_f32_16x16x32_bf16(a1, b1, acc[1][1], 0, 0, 0);
        __syncthreads();
    }
    const int cq = lane >> 4, cc = lane & 15;
#pragma unroll
    for (int i = 0; i < 2; i++)
#pragma unroll
        for (int j = 0; j < 2; j++) {
#pragma unroll
            for (int rg = 0; rg < 4; rg++) {
                int row = m0 + wr + i * 16 + cq * 4 + rg;
                int col = n0 + wc + j * 16 + cc;
                float v = acc[i][j][rg];
                if (bias) v += bias[col];
                if (ACT == 1) v = v > 0.f ? v : 0.f;
                C[(long)row * ldc + col] = v;
            }
        }
}

// ---------------------------------------------------------------------------
// Helpers
// ---------------------------------------------------------------------------
__global__ void combine_bias(const float* a0, const float* b0,
                             const float* a1, const float* b1,
                             const float* a2, const float* b2,
                             float* o0, float* o1, float* o2)
{
    int i = blockIdx.x * 256 + threadIdx.x;
    o0[i] = a0[i] + b0[i];
    o1[i] = a1[i] + b1[i];
    o2[i] = a2[i] + b2[i];
}

__global__ void seq_major(const float* __restrict__ M, float* __restrict__ Mseq)
{
    int b = blockIdx.x;
    int s = b >> 8, n = b & 255;
    int t = threadIdx.x;
    Mseq[(long)b * 256 + t] = M[((long)n * 64 + s) * 256 + t];
}

// ---------------------------------------------------------------------------
// pack_w: 8-wave scan fragment layout (v3/v7, proven).
// ---------------------------------------------------------------------------
__global__ __launch_bounds__(256) void pack_w(
    const float* __restrict__ Wf, const float* __restrict__ Wb, const float* __restrict__ Wc,
    unsigned short* __restrict__ Pf, unsigned short* __restrict__ Pb, unsigned short* __restrict__ Pc)
{
    int chunk = blockIdx.x * 256 + threadIdx.x;      // 0..24575
    const float* W = (blockIdx.y == 0) ? Wf : ((blockIdx.y == 1) ? Wb : Wc);
    unsigned short* P = (blockIdx.y == 0) ? Pf : ((blockIdx.y == 1) ? Pb : Pc);
    int lane = chunk & 63;
    int kt   = (chunk >> 6) & 7;
    int f    = (chunk >> 9) % 6;
    int w    = chunk / 3072;
    int g = f >> 1, hh = f & 1;
    int c = lane & 15, q = lane >> 4;
    int col = g * 256 + w * 32 + hh * 16 + c;
    int k0  = kt * 32 + q * 8;
    unsigned int v[8];
#pragma unroll
    for (int j = 0; j < 8; j++) v[j] = f2b(W[(long)(k0 + j) * 768 + col]);
    uint4 o;
    o.x = v[0] | (v[1] << 16); o.y = v[2] | (v[3] << 16);
    o.z = v[4] | (v[5] << 16); o.w = v[6] | (v[7] << 16);
    *(uint4*)&P[(long)chunk * 8] = o;
}

__global__ void build_x(const float* __restrict__ values, const float* __restrict__ Mbuf,
                        const int* __restrict__ actions, const int* __restrict__ a0,
                        float* __restrict__ Xc, int t0)
{
    int m = blockIdx.x;
    int tl = m >> 8, n = m & 255;
    int t = t0 + tl;
    int c = threadIdx.x;
    float v;
    if (c < 64) {
        v = values[((long)t * 256 + n) * 64 + c];
    } else {
        int ap = (t == 0) ? a0[n] : actions[(long)(t - 1) * 256 + n];
        v = Mbuf[((long)n * 64 + ap) * 256 + (c - 64)];
    }
    Xc[(long)m * 320 + c] = v;
}

// ---------------------------------------------------------------------------
// Fused kernel v13 = v7 schedule (fp32 gi, fat LDS, serial gate GEMMs, kgru
// in fused(0)) + v9's fused tail (sc_nblk param, role-only tail launches).
// ---------------------------------------------------------------------------
struct GemmRole {
    const float* A; const float* B; const float* bias; float* C;
    int K; long lda; long ldb; long ldc; int act; int nblocks; int ntn;
};

union FusedLds {
    struct { unsigned short hbuf[2][16][264]; float gibuf[2][16 * 772]; } s;
    struct { unsigned short As[64][32]; unsigned short Bs[128][32]; } g;
    struct { unsigned short As2[2][64][32]; unsigned short Bs2[2][64][32]; } l;
};

// ---- scan role: EXACT v3/v7 structure (8 waves, split-hh, fences, vmcnt(8)) ----
__device__ __forceinline__ void scan_role(FusedLds* L,
    const float* gi, const unsigned short* PK, const float* h_init,
    float* outp, float* h_state, int n0, int steps, int kgru, int d)
{
    auto& hbuf  = L->s.hbuf;
    auto& gibuf = L->s.gibuf;
    const int tid = threadIdx.x;
    const int w = tid >> 6, lane = tid & 63;
    const int q = lane >> 4, c = lane & 15, q8 = q << 3;
    const int wcol = w * 32;

    bf16x8 Bf[6][8];
#pragma unroll
    for (int f = 0; f < 6; f++)
#pragma unroll
        for (int kt = 0; kt < 8; kt++)
            Bf[f][kt] = *(const bf16x8*)&PK[(((long)(w * 6 + f) * 8 + kt) * 64 + lane) * 8];

    f32x4 hreg[2];
#pragma unroll
    for (int hh = 0; hh < 2; hh++)
#pragma unroll
        for (int rg = 0; rg < 4; rg++) {
            float v = 0.f;
            if (!kgru) v = h_init[(long)(n0 + q * 4 + rg) * 256 + wcol + hh * 16 + c];
            hreg[hh][rg] = v;
            hbuf[1][q * 4 + rg][wcol + hh * 16 + c] = f2b(v);
        }

    const int row0 = kgru ? (d ? 63 : 0) : 0;
    const long gstride = (kgru && d) ? -196608L : 196608L;
    const float* gsrc = gi + ((long)row0 * 256 + n0) * 768;
    float* optr[4];
    long ostride;
    if (kgru) {
        ostride = d ? -512L : 512L;
#pragma unroll
        for (int rg = 0; rg < 4; rg++)
            optr[rg] = outp + ((long)(n0 + q * 4 + rg) * 64 + row0) * 512 + d * 256 + wcol + c;
    } else {
        ostride = 65536L;
#pragma unroll
        for (int rg = 0; rg < 4; rg++)
            optr[rg] = outp + (long)(n0 + q * 4 + rg) * 256 + wcol + c;
    }

#pragma unroll
    for (int i = 0; i < 6; i++) {
        int idx = w * 6 + i;
        int r = idx / 3, ch = idx % 3;
        gload_lds16(gsrc + (long)r * 768 + ch * 256 + lane * 4,
                    &gibuf[0][r * 772 + ch * 256]);
    }
    __syncthreads();

    for (int s = 0; s < steps; s++) {
        const int cur = s & 1;
        if (s + 1 < steps) {
            const float* src = gsrc + gstride;
#pragma unroll
            for (int i = 0; i < 6; i++) {
                int idx = w * 6 + i;
                int r = idx / 3, ch = idx % 3;
                gload_lds16(src + (long)r * 768 + ch * 256 + lane * 4,
                            &gibuf[cur ^ 1][r * 772 + ch * 256]);
            }
        }
        gsrc += gstride;
        asm volatile("" ::: "memory");

        const unsigned short* hrd = &hbuf[cur ^ 1][0][0];
        const float* gp = &gibuf[cur][(q * 4) * 772 + wcol + c];
        unsigned short* hwr = &hbuf[cur][q * 4][wcol + c];

#pragma unroll
        for (int hh = 0; hh < 2; hh++) {
            f32x4 ar = (f32x4){0.f, 0.f, 0.f, 0.f};
            f32x4 az = (f32x4){0.f, 0.f, 0.f, 0.f};
            f32x4 an = (f32x4){0.f, 0.f, 0.f, 0.f};
#pragma unroll
            for (int kt = 0; kt < 8; kt++) {
                bf16x8 a = *(const bf16x8*)&hrd[c * 264 + kt * 32 + q8];
                ar = __builtin_amdgcn_mfma_f32_16x16x32_bf16(a, Bf[0 + hh][kt], ar, 0, 0, 0);
                az = __builtin_amdgcn_mfma_f32_16x16x32_bf16(a, Bf[2 + hh][kt], az, 0, 0, 0);
                an = __builtin_amdgcn_mfma_f32_16x16x32_bf16(a, Bf[4 + hh][kt], an, 0, 0, 0);
            }
#pragma unroll
            for (int rg = 0; rg < 4; rg++) {
                float gr = gp[rg * 772 +       hh * 16];
                float gz = gp[rg * 772 + 256 + hh * 16];
                float gn = gp[rg * 772 + 512 + hh * 16];
                float r  = __builtin_amdgcn_rcpf(1.f + __expf(-(gr + ar[rg])));
                float zg = __builtin_amdgcn_rcpf(1.f + __expf(-(gz + az[rg])));
                float nn = 1.f - 2.f * __builtin_amdgcn_rcpf(1.f + __expf(2.f * (gn + r * an[rg])));
                float hv = (1.f - zg) * nn + zg * hreg[hh][rg];
                hreg[hh][rg] = hv;
                hwr[rg * 264 + hh * 16] = f2b(hv);
                optr[rg][hh * 16] = hv;
            }
            asm volatile("" ::: "memory");
        }

#pragma unroll
        for (int rg = 0; rg < 4; rg++) optr[rg] += ostride;

        asm volatile("s_waitcnt vmcnt(8) lgkmcnt(0)" ::: "memory");
        __builtin_amdgcn_sched_barrier(0);
        __builtin_amdgcn_s_barrier();
        __builtin_amdgcn_sched_barrier(0);
    }

    if (!kgru) {
#pragma unroll
        for (int hh = 0; hh < 2; hh++)
#pragma unroll
            for (int rg = 0; rg < 4; rg++)
                h_state[(long)(n0 + q * 4 + rg) * 256 + wcol + hh * 16 + c] = hreg[hh][rg];
    }
}

// ---- gemm role: 512-thread 64x128 tile, B stored (K,N), swizzled LDS ----
__device__ __forceinline__ void gemm_role(FusedLds* L, const GemmRole& R, int rb)
{
    auto& As = L->g.As;
    auto& Bs = L->g.Bs;
    const int tid = threadIdx.x;
    const int lane = tid & 63, w = tid >> 6;
    const int mt = rb / R.ntn, nt = rb % R.ntn;
    const long m0 = (long)mt * 64, n0 = (long)nt * 128;
    const int wr = (w >> 2) * 32, wc = (w & 3) * 32;

    f32x4 acc[2][2];
#pragma unroll
    for (int i = 0; i < 2; i++)
#pragma unroll
        for (int j = 0; j < 2; j++) acc[i][j] = (f32x4){0.f, 0.f, 0.f, 0.f};

    for (int k0 = 0; k0 < R.K; k0 += 32) {
        {
            const int r = tid >> 3, ck = (tid & 7) << 2;
            const float* s = R.A + (m0 + r) * R.lda + k0 + ck;
            float4 v = *(const float4*)s;
            unsigned short* dp = &As[r][swzi(r, ck >> 3) + (ck & 7)];
            dp[0] = f2b(v.x); dp[1] = f2b(v.y); dp[2] = f2b(v.z); dp[3] = f2b(v.w);
        }
        {
            const int kk = tid >> 4, cn = (tid & 15) << 3;
            const float* s = R.B + (long)(k0 + kk) * R.ldb + n0 + cn;
            float4 v0 = *(const float4*)s, v1 = *(const float4*)(s + 4);
            const int sc = swzi(cn, kk >> 3) + (kk & 7);
            Bs[cn + 0][sc] = f2b(v0.x); Bs[cn + 1][sc] = f2b(v0.y);
            Bs[cn + 2][sc] = f2b(v0.z); Bs[cn + 3][sc] = f2b(v0.w);
            Bs[cn + 4][sc] = f2b(v1.x); Bs[cn + 5][sc] = f2b(v1.y);
            Bs[cn + 6][sc] = f2b(v1.z); Bs[cn + 7][sc] = f2b(v1.w);
        }
        __syncthreads();
        const int l15 = lane & 15, q = lane >> 4;
        bf16x8 a0 = *(const bf16x8*)&As[wr +      l15][swzi(wr +      l15, q)];
        bf16x8 a1 = *(const bf16x8*)&As[wr + 16 + l15][swzi(wr + 16 + l15, q)];
        bf16x8 b0 = *(const bf16x8*)&Bs[wc +      l15][swzi(wc +      l15, q)];
        bf16x8 b1 = *(const bf16x8*)&Bs[wc + 16 + l15][swzi(wc + 16 + l15, q)];
        acc[0][0] = __builtin_amdgcn_mfma_f32_16x16x32_bf16(a0, b0, acc[0][0], 0, 0, 0);
        acc[0][1] = __builtin_amdgcn_mfma_f32_16x16x32_bf16(a0, b1, acc[0][1], 0, 0, 0);
        acc[1][0] = __builtin_amdgcn_mfma_f32_16x16x32_bf16(a1, b0, acc[1][0], 0, 0, 0);
        acc[1][1] = __builtin_amdgcn_mfma_f32_16x16x32_bf16(a1, b1, acc[1][1], 0, 0, 0);
        __syncthreads();
    }
    const int cq = lane >> 4, cc = lane & 15;
#pragma unroll
    for (int i = 0; i < 2; i++)
#pragma unroll
        for (int j = 0; j < 2; j++) {
#pragma unroll
            for (int rg = 0; rg < 4; rg++) {
                long row = m0 + wr + i * 16 + cq * 4 + rg;
                long col = n0 + wc + j * 16 + cc;
                float v = acc[i][j][rg];
                if (R.bias) v += R.bias[col];
                if (R.act == 1) v = v > 0.f ? v : 0.f;
                R.C[row * R.ldc + col] = v;
            }
        }
}

// ---- logits role: dual-z 64x64x512 GEMM (both halves barrier-identical) ----
__device__ __forceinline__ void logits_role(FusedLds* L, int rb,
    const float* Qs, const float* Kb, float* Lout)
{
    auto& As = L->l.As2;
    auto& Bs = L->l.Bs2;
    const int tid = threadIdx.x;
    const int half = tid >> 8, htid = tid & 255;
    const int z = rb * 2 + half;
    const float* A = Qs + (long)z * 512;
    const float* B = Kb + (long)z * 32768;
    float* C = Lout + (long)z * 64;
    const int lane = htid & 63, w4 = htid >> 6;
    const int wr = (w4 >> 1) * 32, wc = (w4 & 1) * 32;

    f32x4 acc[2][2];
#pragma unroll
    for (int i = 0; i < 2; i++)
#pragma unroll
        for (int j = 0; j < 2; j++) acc[i][j] = (f32x4){0.f, 0.f, 0.f, 0.f};

    for (int k0 = 0; k0 < 512; k0 += 32) {
        const int r = htid >> 2, ck = (htid & 3) << 3;
        {
            const float* s = A + (long)r * 131072 + k0 + ck;
            float4 v0 = *(const float4*)s, v1 = *(const float4*)(s + 4);
            unsigned short* d = &As[half][r][swzi(r, ck >> 3)];
            d[0] = f2b(v0.x); d[1] = f2b(v0.y); d[2] = f2b(v0.z); d[3] = f2b(v0.w);
            d[4] = f2b(v1.x); d[5] = f2b(v1.y); d[6] = f2b(v1.z); d[7] = f2b(v1.w);
        }
        {
            const float* s = B + (long)r * 512 + k0 + ck;
            float4 v0 = *(const float4*)s, v1 = *(const float4*)(s + 4);
            unsigned short* d = &Bs[half][r][swzi(r, ck >> 3)];
            d[0] = f2b(v0.x); d[1] = f2b(v0.y); d[2] = f2b(v0.z); d[3] = f2b(v0.w);
            d[4] = f2b(v1.x); d[5] = f2b(v1.y); d[6] = f2b(v1.z); d[7] = f2b(v1.w);
        }
        __syncthreads();
        const int l15 = lane & 15, q = lane >> 4;
        bf16x8 a0 = *(const bf16x8*)&As[half][wr +      l15][swzi(wr +      l15, q)];
        bf16x8 a1 = *(const bf16x8*)&As[half][wr + 16 + l15][swzi(wr + 16 + l15, q)];
        bf16x8 b0 = *(const bf16x8*)&Bs[half][wc +      l15][swzi(wc +      l15, q)];
        bf16x8 b1 = *(const bf16x8*)&Bs[half][wc + 16 + l15][swzi(wc + 16 + l15, q)];
        acc[0][0] = __builtin_amdgcn_mfma_f32_16x16x32_bf16(a0, b0, acc[0][0], 0, 0, 0);
        acc[0][1] = __builtin_amdgcn_mfma_f32_16x16x32_bf16(a0, b1, acc[0][1], 0, 0, 0);
        acc[1][0] = __builtin_amdgcn_mfma_f32_16x16x32_bf16(a1, b0, acc[1][0], 0, 0, 0);
        acc[1][1] = __builtin_amdgcn_mfma_f32_16x16x32_bf16(a1, b1, acc[1][1], 0, 0, 0);
        __syncthreads();
    }
    const int cq = lane >> 4, cc = lane & 15;
#pragma unroll
    for (int i = 0; i < 2; i++)
#pragma unroll
        for (int j = 0; j < 2; j++) {
#pragma unroll
            for (int rg = 0; rg < 4; rg++)
                C[(long)(wr + i * 16 + cq * 4 + rg) * 16384 + wc + j * 16 + cc] = acc[i][j][rg];
        }
}

// ---- epilogue role: per warp, one (t,n); no barriers ----
__device__ __forceinline__ void epi_role(int rb,
    const float* Hall, const float* Lc, const int* actions,
    const float* critic_W, const float* critic_b, float* out, int t0)
{
    const int w = threadIdx.x >> 6, j = threadIdx.x & 63;
    const int m = rb * 8 + w;
    const int tl = m >> 8, n = m & 255;
    const int t = t0 + tl;
    long o = ((long)t * 256 + n) * 322;
    const float* h = Hall + (long)m * 256;
    float part = 0.f;
#pragma unroll
    for (int i = 0; i < 4; i++) {
        float hv = h[j + 64 * i];
        out[o + 2 + j + 64 * i] = hv;
        part += hv * critic_W[j + 64 * i];
    }
    for (int off = 32; off > 0; off >>= 1) part += __shfl_down(part, off);
    if (j == 0) {
        out[o]     = (float)actions[(long)t * 256 + n];
        out[o + 1] = part + critic_b[0];
    }
    float x = Lc[(long)m * 64 + j];
    float mx = x;
    for (int off = 32; off > 0; off >>= 1) mx = fmaxf(mx, __shfl_down(mx, off));
    mx = __shfl(mx, 0);
    float e = __expf(x - mx);
    float ssum = e;
    for (int off = 32; off > 0; off >>= 1) ssum += __shfl_down(ssum, off);
    ssum = __shfl(ssum, 0);
    out[o + 258 + j] = e / ssum;
}

// ---- build_x role ----
__device__ __forceinline__ void bx_role(int rb,
    const float* values, const float* Mbuf, const int* actions, const int* a0,
    float* Xd, int t0)
{
    const int tid = threadIdx.x;
    if (tid >= 320) return;
    for (int rr = 0; rr < 128; rr++) {
        int m = rb * 128 + rr;
        int tl = m >> 8, n = m & 255;
        int t = t0 + tl;
        float v;
        if (tid < 64) {
            v = values[((long)t * 256 + n) * 64 + tid];
        } else {
            int ap = (t == 0) ? a0[n] : actions[(long)(t - 1) * 256 + n];
            v = Mbuf[((long)n * 64 + ap) * 256 + (tid - 64)];
        }
        Xd[(long)m * 320 + tid] = v;
    }
}

__global__ __launch_bounds__(512, 2) void fused_k(
    int sc_nblk, const float* sc_gi, const unsigned short* sc_PK, const float* sc_hinit,
    float* sc_out, float* sc_hstate,
    int kgru_nblk, const float* kg_gi0, const float* kg_gi1,
    const unsigned short* kg_PK0, const unsigned short* kg_PK1, float* kg_out,
    GemmRole g0, GemmRole g1, GemmRole g2, GemmRole g3,
    int lg_nblk, const float* lg_Q, const float* lg_K, float* lg_L,
    int ep_nblk, const float* ep_Hall, const float* ep_L, int ep_t0,
    int bx_nblk, const float* values, const float* Mbuf,
    const int* actions, const int* a0, float* bx_dst, int bx_t0,
    const float* critic_W, const float* critic_b, float* out)
{
    __shared__ __align__(16) FusedLds L;
    int b = blockIdx.x;
    if (b < sc_nblk) {
        scan_role(&L, sc_gi, sc_PK, sc_hinit, sc_out, sc_hstate, b * 16, TCHUNK, 0, 0);
        return;
    }
    b -= sc_nblk;
    if (b < kgru_nblk) {
        int d = b >> 4, n0 = (b & 15) * 16;
        scan_role(&L, d ? kg_gi1 : kg_gi0, d ? kg_PK1 : kg_PK0, nullptr,
                  kg_out, nullptr, n0, 64, 1, d);
        return;
    }
    b -= kgru_nblk;
    if (b < g0.nblocks) { gemm_role(&L, g0, b); return; }
    b -= g0.nblocks;
    if (b < g1.nblocks) { gemm_role(&L, g1, b); return; }
    b -= g1.nblocks;
    if (b < g2.nblocks) { gemm_role(&L, g2, b); return; }
    b -= g2.nblocks;
    if (b < g3.nblocks) { gemm_role(&L, g3, b); return; }
    b -= g3.nblocks;
    if (b < lg_nblk) { logits_role(&L, b, lg_Q, lg_K, lg_L); return; }
    b -= lg_nblk;
    if (b < ep_nblk) { epi_role(b, ep_Hall, ep_L, actions, critic_W, critic_b, out, ep_t0); return; }
    b -= ep_nblk;
    if (b < bx_nblk) bx_role(b, values, Mbuf, actions, a0, bx_dst, bx_t0);
}

// ---------------------------------------------------------------------------
// Epilogue kernel (final tail use)
// ---------------------------------------------------------------------------
__global__ __launch_bounds__(64) void epilogue_k(
    const float* __restrict__ Hallc, const float* __restrict__ Lc,
    const int* __restrict__ actions,
    const float* __restrict__ critic_W, const float* __restrict__ critic_b,
    float* __restrict__ out, int t0)
{
    int m = blockIdx.x;
    int tl = m >> 8, n = m & 255;
    int t = t0 + tl;
    int j = threadIdx.x;
    long o = ((long)t * 256 + n) * 322;
    const float* h = Hallc + (long)m * 256;
    float part = 0.f;
#pragma unroll
    for (int i = 0; i < 4; i++) {
        float hv = h[j + 64 * i];
        out[o + 2 + j + 64 * i] = hv;
        part += hv * critic_W[j + 64 * i];
    }
    for (int off = 32; off > 0; off >>= 1) part += __shfl_down(part, off);
    if (j == 0) {
        out[o]     = (float)actions[(long)t * 256 + n];
        out[o + 1] = part + critic_b[0];
    }
    float x = Lc[(long)m * 64 + j];
    float mx = x;
    for (int off = 32; off > 0; off >>= 1) mx = fmaxf(mx, __shfl_down(mx, off));
    mx = __shfl(mx, 0);
    float e = __expf(x - mx);
    float ssum = e;
    for (int off = 32; off > 0; off >>= 1) ssum += __shfl_down(ssum, off);
    ssum = __shfl(ssum, 0);
    out[o + 258 + j] = e / ssum;
}

// ---------------------------------------------------------------------------
extern "C" void kernel_launch(void* const* d_in, const int* in_sizes, int n_in,
                              void* d_out, int out_size, void* d_ws, size_t ws_size,
                              hipStream_t stream)
{
    const float* values   = (const float*)d_in[0];
    const float* mdp      = (const float*)d_in[1];
    const int*   actions  = (const int*)  d_in[2];
    const int*   a0       = (const int*)  d_in[3];
    const float* h0       = (const float*)d_in[4];
    const float* emb_W    = (const float*)d_in[5];
    const float* emb_b    = (const float*)d_in[6];
    const float* gfw_Wih  = (const float*)d_in[7];
    const float* gfw_Whh  = (const float*)d_in[8];
    const float* gfw_bih  = (const float*)d_in[9];
    const float* gfw_bhh  = (const float*)d_in[10];
    const float* gbw_Wih  = (const float*)d_in[11];
    const float* gbw_Whh  = (const float*)d_in[12];
    const float* gbw_bih  = (const float*)d_in[13];
    const float* gbw_bhh  = (const float*)d_in[14];
    const float* f0_W     = (const float*)d_in[15];
    const float* f0_b     = (const float*)d_in[16];
    const float* f1_W     = (const float*)d_in[17];
    const float* f1_b     = (const float*)d_in[18];
    const float* cell_Wih = (const float*)d_in[19];
    const float* cell_Whh = (const float*)d_in[20];
    const float* cell_bih = (const float*)d_in[21];
    const float* cell_bhh = (const float*)d_in[22];
    const float* critic_W = (const float*)d_in[23];
    const float* critic_b = (const float*)d_in[24];
    const float* qg_W     = (const float*)d_in[25];
    const float* qg_b     = (const float*)d_in[26];
    float* out = (float*)d_out;

    char* base = (char*)d_ws;
    size_t off = 0;
    auto alloc = [&](size_t nf) -> float* {
        float* p = (float*)(base + off);
        off += nf * sizeof(float);
        off = (off + 255) & ~(size_t)255;
        return p;
    };
    float* Mbuf   = alloc(16384ull * 256);
    float* Mseq   = alloc(16384ull * 256);   // aliased as Hallr[2] (dead after prologue)
    float* gfA    = alloc(16384ull * 768);
    float* gbA    = alloc(16384ull * 768);   // aliased as Qr[1] from fused(2) on
    float* Kbuf   = alloc(256ull * 64 * 512);
    float* PKf    = alloc(98304);
    float* PKb    = alloc(98304);
    float* PKc    = alloc(98304);
    float* hstate = alloc(256ull * 256);
    float* Xr[2]    = { alloc(16384ull * 320), alloc(16384ull * 320) };
    float* X0r[2]   = { alloc(16384ull * 256), alloc(16384ull * 256) };
    float* X1r[2]   = { alloc(16384ull * 256), alloc(16384ull * 256) };
    float* GIr[2]   = { alloc(16384ull * 768), alloc(16384ull * 768) };
    float* Hallr[4] = { alloc(16384ull * 256), alloc(16384ull * 256),
                        Mseq, alloc(16384ull * 256) };
    float* Qr[2]  = { alloc(16384ull * 512), gbA };  // gbA dead after fused(0) kgru
    float* Lr[2]  = { alloc(16384ull * 64), alloc(16384ull * 64) };
    float* bias_f = alloc(768);
    float* bias_b = alloc(768);
    float* bias_c = alloc(768);
    (void)ws_size; (void)in_sizes; (void)n_in; (void)out_size;

    dim3 blk(256);

    // ---- Phase 1: embeddings, gate-input GEMMs (serial, v7 schedule), packing ----
    gemm_f32<false, 0><<<dim3(4, 256, 1), blk, 0, stream>>>(
        mdp, 128, 0, emb_W, 256, 0, emb_b, Mbuf, 256, 0, 16384, 256, 128);
    seq_major<<<dim3(16384), blk, 0, stream>>>(Mbuf, Mseq);
    pack_w<<<dim3(96, 3, 1), blk, 0, stream>>>(
        gfw_Whh, gbw_Whh, cell_Whh,
        (unsigned short*)PKf, (unsigned short*)PKb, (unsigned short*)PKc);
    combine_bias<<<dim3(3), blk, 0, stream>>>(gfw_bih, gfw_bhh, gbw_bih, gbw_bhh,
                                              cell_bih, cell_bhh, bias_f, bias_b, bias_c);
    gemm_f32<false, 0><<<dim3(12, 256, 1), blk, 0, stream>>>(
        Mseq, 256, 0, gfw_Wih, 768, 0, bias_f, gfA, 768, 0, 16384, 768, 256);
    gemm_f32<false, 0><<<dim3(12, 256, 1), blk, 0, stream>>>(
        Mseq, 256, 0, gbw_Wih, 768, 0, bias_b, gbA, 768, 0, 16384, 768, 256);

    // ---- Pipeline priming (x-path for chunks 0..3 partial) ----
    build_x<<<dim3(16384), dim3(320), 0, stream>>>(values, Mbuf, actions, a0, Xr[0], 0);
    gemm_f32<false, 1><<<dim3(4, 256, 1), blk, 0, stream>>>(
        Xr[0], 320, 0, f0_W, 256, 0, f0_b, X0r[0], 256, 0, 16384, 256, 320);
    build_x<<<dim3(16384), dim3(320), 0, stream>>>(values, Mbuf, actions, a0, Xr[1], 64);
    gemm_f32<false, 1><<<dim3(4, 256, 1), blk, 0, stream>>>(
        Xr[1], 320, 0, f0_W, 256, 0, f0_b, X0r[1], 256, 0, 16384, 256, 320);
    gemm_f32<false, 1><<<dim3(4, 256, 1), blk, 0, stream>>>(
        X0r[0], 256, 0, f1_W, 256, 0, f1_b, X1r[0], 256, 0, 16384, 256, 256);
    build_x<<<dim3(16384), dim3(320), 0, stream>>>(values, Mbuf, actions, a0, Xr[0], 128);
    gemm_f32<false, 1><<<dim3(4, 256, 1), blk, 0, stream>>>(
        Xr[0], 320, 0, f0_W, 256, 0, f0_b, X0r[0], 256, 0, 16384, 256, 320);
    gemm_f32<false, 1><<<dim3(4, 256, 1), blk, 0, stream>>>(
        X0r[1], 256, 0, f1_W, 256, 0, f1_b, X1r[1], 256, 0, 16384, 256, 256);
    build_x<<<dim3(16384), dim3(320), 0, stream>>>(values, Mbuf, actions, a0, Xr[1], 192);
    gemm_f32<false, 0><<<dim3(12, 256, 1), blk, 0, stream>>>(
        X1r[0], 256, 0, cell_Wih, 768, 0, bias_c, GIr[0], 768, 0, 16384, 768, 256);

    // ---- Fused pipeline (v7 schedule + fused tail):
    //   fused(c) = scan(c) | kgru(c==0) | f0(c+3) | f1(c+2) | GI(c+1)
    //            | qg(c-1) | logits(c-2) | epi(c-3) | bx(c+4)
    for (int c = 0; c < NCHUNK; c++) {
        GemmRole g0{}, g1{}, g2{}, g3{};
        if (c <= 4) g0 = GemmRole{ Xr[(c + 1) & 1], f0_W, f0_b, X0r[(c + 1) & 1],
                                   320, 320, 256, 256, 1, 512, 2 };
        if (c <= 5) g1 = GemmRole{ X0r[c & 1], f1_W, f1_b, X1r[c & 1],
                                   256, 256, 256, 256, 1, 512, 2 };
        if (c <= 6) g2 = GemmRole{ X1r[(c + 1) & 1], cell_Wih, bias_c, GIr[(c + 1) & 1],
                                   256, 256, 768, 768, 0, 1536, 6 };
        if (c >= 1) g3 = GemmRole{ Hallr[(c - 1) & 3], qg_W, qg_b, Qr[(c - 1) & 1],
                                   256, 256, 512, 512, 0, 1024, 4 };
        int kgn = (c == 0) ? 32 : 0;
        int lgn = (c >= 2) ? 128 : 0;
        int epn = (c >= 3) ? 2048 : 0;
        int bxn = (c <= 3) ? 128 : 0;
        int total = 16 + kgn + g0.nblocks + g1.nblocks + g2.nblocks + g3.nblocks
                    + lgn + epn + bxn;

        fused_k<<<dim3(total), dim3(512), 0, stream>>>(
            16, GIr[c & 1], (const unsigned short*)PKc, (c == 0) ? h0 : (const float*)hstate,
            Hallr[c & 3], hstate,
            kgn, gfA, gbA, (const unsigned short*)PKf, (const unsigned short*)PKb, Kbuf,
            g0, g1, g2, g3,
            lgn, Qr[(c - 2) & 1], Kbuf, Lr[(c - 2) & 1],
            epn, Hallr[(c - 3) & 3], Lr[(c - 3) & 1], (c - 3) * 64,
            bxn, values, Mbuf, actions, a0, Xr[c & 1], (c + 4) * 64,
            critic_W, critic_b, out);
    }

    // ---- Tail drain: T1 = qg(7) | logits(6) | epi(5) ----
    {
        GemmRole gz{}, g3t = GemmRole{ Hallr[3], qg_W, qg_b, Qr[1],
                                       256, 256, 512, 512, 0, 1024, 4 };
        fused_k<<<dim3(1024 + 128 + 2048), dim3(512), 0, stream>>>(
            0, GIr[0], (const unsigned short*)PKc, hstate, Hallr[0], hstate,
            0, gfA, gbA, (const unsigned short*)PKf, (const unsigned short*)PKb, Kbuf,
            gz, gz, gz, g3t,
            128, Qr[0], Kbuf, Lr[0],
            2048, Hallr[1], Lr[1], 5 * 64,
            0, values, Mbuf, actions, a0, Xr[0], 0,
            critic_W, critic_b, out);
    }
    // ---- T2 = logits(7) | epi(6) ----
    {
        GemmRole gz{};
        fused_k<<<dim3(128 + 2048), dim3(512), 0, stream>>>(
            0, GIr[0], (const unsigned short*)PKc, hstate, Hallr[0], hstate,
            0, gfA, gbA, (const unsigned short*)PKf, (const unsigned short*)PKb, Kbuf,
            gz, gz, gz, gz,
            128, Qr[1], Kbuf, Lr[1],
            2048, Hallr[2], Lr[0], 6 * 64,
            0, values, Mbuf, actions, a0, Xr[0], 0,
            critic_W, critic_b, out);
    }
    // ---- T3 = epi(7) ----
    epilogue_k<<<dim3(16384), dim3(64), 0, stream>>>(
        Hallr[3], Lr[1], actions, critic_W, critic_b, out, 7 * 64);
}

// Round 15
// 2096.171 us; speedup vs baseline: 2.8390x; 1.0259x over previous
//
#include <hip/hip_runtime.h>

// Problem constants (reference: T=512, N=256, H=256, HR=64, WC=128, V=64)
#define TSTEPS 512
#define NBATCH 256
#define HID    256
#define TCHUNK 64
#define NCHUNK 8

typedef __attribute__((ext_vector_type(8))) short bf16x8;
typedef __attribute__((ext_vector_type(4))) float f32x4;

__device__ __forceinline__ unsigned short f2b(float x) {
    union { float f; unsigned int u; } c; c.f = x;
    unsigned int u = c.u;
    return (unsigned short)((u + 0x7fffu + ((u >> 16) & 1u)) >> 16);
}

__device__ __forceinline__ void gload_lds16(const float* g, float* l) {
    __builtin_amdgcn_global_load_lds(
        (const __attribute__((address_space(1))) unsigned int*)g,
        (__attribute__((address_space(3))) unsigned int*)l,
        16, 0, 0);
}

// LDS bank-conflict mitigation for [row][32]-short GEMM tiles (v7, kept).
__device__ __forceinline__ int swzi(int row, int g) {
    return ((g ^ ((row >> 3) & 3)) << 3);
}

// ---------------------------------------------------------------------------
// Generic GEMM (256 thr): C = act(A@B + bias). Prologue use. Swizzled LDS.
// ---------------------------------------------------------------------------
template<bool TRANS_B, int ACT>
__global__ __launch_bounds__(256) void gemm_f32(
    const float* __restrict__ A, long lda, long sA,
    const float* __restrict__ B, long ldb, long sB,
    const float* __restrict__ bias,
    float* __restrict__ C, long ldc, long sC,
    int M, int N, int K)
{
    __shared__ __align__(16) unsigned short As[64][32];
    __shared__ __align__(16) unsigned short Bs[64][32];
    const int z = blockIdx.z;
    A += (long)z * sA; B += (long)z * sB; C += (long)z * sC;
    const int n0 = blockIdx.x * 64, m0 = blockIdx.y * 64;
    const int tid  = threadIdx.x;
    const int lane = tid & 63, w = tid >> 6;
    const int wr = (w >> 1) * 32, wc = (w & 1) * 32;

    f32x4 acc[2][2];
#pragma unroll
    for (int i = 0; i < 2; i++)
#pragma unroll
        for (int j = 0; j < 2; j++) acc[i][j] = (f32x4){0.f, 0.f, 0.f, 0.f};

    for (int k0 = 0; k0 < K; k0 += 32) {
        {
            const int r = tid >> 2, ck = (tid & 3) << 3;
            const float* s = A + (long)(m0 + r) * lda + k0 + ck;
            float4 v0 = *(const float4*)s, v1 = *(const float4*)(s + 4);
            unsigned short* d = &As[r][swzi(r, ck >> 3)];
            d[0] = f2b(v0.x); d[1] = f2b(v0.y); d[2] = f2b(v0.z); d[3] = f2b(v0.w);
            d[4] = f2b(v1.x); d[5] = f2b(v1.y); d[6] = f2b(v1.z); d[7] = f2b(v1.w);
        }
        if (TRANS_B) {
            const int r = tid >> 2, ck = (tid & 3) << 3;
            const float* s = B + (long)(n0 + r) * ldb + k0 + ck;
            float4 v0 = *(const float4*)s, v1 = *(const float4*)(s + 4);
            unsigned short* d = &Bs[r][swzi(r, ck >> 3)];
            d[0] = f2b(v0.x); d[1] = f2b(v0.y); d[2] = f2b(v0.z); d[3] = f2b(v0.w);
            d[4] = f2b(v1.x); d[5] = f2b(v1.y); d[6] = f2b(v1.z); d[7] = f2b(v1.w);
        } else {
            const int kk = tid >> 3, cn = (tid & 7) << 3;
            const float* s = B + (long)(k0 + kk) * ldb + n0 + cn;
            float4 v0 = *(const float4*)s, v1 = *(const float4*)(s + 4);
            const int sc = swzi(cn, kk >> 3) + (kk & 7);
            Bs[cn + 0][sc] = f2b(v0.x); Bs[cn + 1][sc] = f2b(v0.y);
            Bs[cn + 2][sc] = f2b(v0.z); Bs[cn + 3][sc] = f2b(v0.w);
            Bs[cn + 4][sc] = f2b(v1.x); Bs[cn + 5][sc] = f2b(v1.y);
            Bs[cn + 6][sc] = f2b(v1.z); Bs[cn + 7][sc] = f2b(v1.w);
        }
        __syncthreads();
        const int l15 = lane & 15, q = lane >> 4;
        bf16x8 a0 = *(const bf16x8*)&As[wr +      l15][swzi(wr +      l15, q)];
        bf16x8 a1 = *(const bf16x8*)&As[wr + 16 + l15][swzi(wr + 16 + l15, q)];
        bf16x8 b0 = *(const bf16x8*)&Bs[wc +      l15][swzi(wc +      l15, q)];
        bf16x8 b1 = *(const bf16x8*)&Bs[wc + 16 + l15][swzi(wc + 16 + l15, q)];
        acc[0][0] = __builtin_amdgcn_mfma_f32_16x16x32_bf16(a0, b0, acc[0][0], 0, 0, 0);
        acc[0][1] = __builtin_amdgcn_mfma_f32_16x16x32_bf16(a0, b1, acc[0][1], 0, 0, 0);
        acc[1][0] = __builtin_amdgcn_mfma_f32_16x16x32_bf16(a1, b0, acc[1][0], 0, 0, 0);
        acc[1][1] = __builtin_amdgcn_mfma_f32_16x16x32_bf16(a1, b1, acc[1][1], 0, 0, 0);
        __syncthreads();
    }
    const int cq = lane >> 4, cc = lane & 15;
#pragma unroll
    for (int i = 0; i < 2; i++)
#pragma unroll
        for (int j = 0; j < 2; j++) {
#pragma unroll
            for (int rg = 0; rg < 4; rg++) {
                int row = m0 + wr + i * 16 + cq * 4 + rg;
                int col = n0 + wc + j * 16 + cc;
                float v = acc[i][j][rg];
                if (bias) v += bias[col];
                if (ACT == 1) v = v > 0.f ? v : 0.f;
                C[(long)row * ldc + col] = v;
            }
        }
}

// ---------------------------------------------------------------------------
// Helpers
// ---------------------------------------------------------------------------
__global__ void combine_bias(const float* a0, const float* b0,
                             const float* a1, const float* b1,
                             const float* a2, const float* b2,
                             float* o0, float* o1, float* o2)
{
    int i = blockIdx.x * 256 + threadIdx.x;
    o0[i] = a0[i] + b0[i];
    o1[i] = a1[i] + b1[i];
    o2[i] = a2[i] + b2[i];
}

__global__ void seq_major(const float* __restrict__ M, float* __restrict__ Mseq)
{
    int b = blockIdx.x;
    int s = b >> 8, n = b & 255;
    int t = threadIdx.x;
    Mseq[(long)b * 256 + t] = M[((long)n * 64 + s) * 256 + t];
}

// ---------------------------------------------------------------------------
// pack_w: 8-wave scan fragment layout (v3/v7, proven).
// ---------------------------------------------------------------------------
__global__ __launch_bounds__(256) void pack_w(
    const float* __restrict__ Wf, const float* __restrict__ Wb, const float* __restrict__ Wc,
    unsigned short* __restrict__ Pf, unsigned short* __restrict__ Pb, unsigned short* __restrict__ Pc)
{
    int chunk = blockIdx.x * 256 + threadIdx.x;      // 0..24575
    const float* W = (blockIdx.y == 0) ? Wf : ((blockIdx.y == 1) ? Wb : Wc);
    unsigned short* P = (blockIdx.y == 0) ? Pf : ((blockIdx.y == 1) ? Pb : Pc);
    int lane = chunk & 63;
    int kt   = (chunk >> 6) & 7;
    int f    = (chunk >> 9) % 6;
    int w    = chunk / 3072;
    int g = f >> 1, hh = f & 1;
    int c = lane & 15, q = lane >> 4;
    int col = g * 256 + w * 32 + hh * 16 + c;
    int k0  = kt * 32 + q * 8;
    unsigned int v[8];
#pragma unroll
    for (int j = 0; j < 8; j++) v[j] = f2b(W[(long)(k0 + j) * 768 + col]);
    uint4 o;
    o.x = v[0] | (v[1] << 16); o.y = v[2] | (v[3] << 16);
    o.z = v[4] | (v[5] << 16); o.w = v[6] | (v[7] << 16);
    *(uint4*)&P[(long)chunk * 8] = o;
}

__global__ void build_x(const float* __restrict__ values, const float* __restrict__ Mbuf,
                        const int* __restrict__ actions, const int* __restrict__ a0,
                        float* __restrict__ Xc, int t0)
{
    int m = blockIdx.x;
    int tl = m >> 8, n = m & 255;
    int t = t0 + tl;
    int c = threadIdx.x;
    float v;
    if (c < 64) {
        v = values[((long)t * 256 + n) * 64 + c];
    } else {
        int ap = (t == 0) ? a0[n] : actions[(long)(t - 1) * 256 + n];
        v = Mbuf[((long)n * 64 + ap) * 256 + (c - 64)];
    }
    Xc[(long)m * 320 + c] = v;
}

// ---------------------------------------------------------------------------
// Fused kernel v14 = v13 (v7 schedule) + dedicated SMALL-LDS tail kernel.
// ---------------------------------------------------------------------------
struct GemmRole {
    const float* A; const float* B; const float* bias; float* C;
    int K; long lda; long ldb; long ldc; int act; int nblocks; int ntn;
};

union FusedLds {
    struct { unsigned short hbuf[2][16][264]; float gibuf[2][16 * 772]; } s;
    struct { unsigned short As[64][32]; unsigned short Bs[128][32]; } g;
    struct { unsigned short As2[2][64][32]; unsigned short Bs2[2][64][32]; } l;
};
// Tail union: roles only (gemm 12.3KB, logits 16.4KB) -> 16.4KB -> 4 blk/CU.
union TailLds {
    struct { unsigned short As[64][32]; unsigned short Bs[128][32]; } g;
    struct { unsigned short As2[2][64][32]; unsigned short Bs2[2][64][32]; } l;
};

// ---- scan role: EXACT v3/v7 structure (8 waves, split-hh, fences, vmcnt(8)) ----
__device__ __forceinline__ void scan_role(FusedLds* L,
    const float* gi, const unsigned short* PK, const float* h_init,
    float* outp, float* h_state, int n0, int steps, int kgru, int d)
{
    auto& hbuf  = L->s.hbuf;
    auto& gibuf = L->s.gibuf;
    const int tid = threadIdx.x;
    const int w = tid >> 6, lane = tid & 63;
    const int q = lane >> 4, c = lane & 15, q8 = q << 3;
    const int wcol = w * 32;

    bf16x8 Bf[6][8];
#pragma unroll
    for (int f = 0; f < 6; f++)
#pragma unroll
        for (int kt = 0; kt < 8; kt++)
            Bf[f][kt] = *(const bf16x8*)&PK[(((long)(w * 6 + f) * 8 + kt) * 64 + lane) * 8];

    f32x4 hreg[2];
#pragma unroll
    for (int hh = 0; hh < 2; hh++)
#pragma unroll
        for (int rg = 0; rg < 4; rg++) {
            float v = 0.f;
            if (!kgru) v = h_init[(long)(n0 + q * 4 + rg) * 256 + wcol + hh * 16 + c];
            hreg[hh][rg] = v;
            hbuf[1][q * 4 + rg][wcol + hh * 16 + c] = f2b(v);
        }

    const int row0 = kgru ? (d ? 63 : 0) : 0;
    const long gstride = (kgru && d) ? -196608L : 196608L;
    const float* gsrc = gi + ((long)row0 * 256 + n0) * 768;
    float* optr[4];
    long ostride;
    if (kgru) {
        ostride = d ? -512L : 512L;
#pragma unroll
        for (int rg = 0; rg < 4; rg++)
            optr[rg] = outp + ((long)(n0 + q * 4 + rg) * 64 + row0) * 512 + d * 256 + wcol + c;
    } else {
        ostride = 65536L;
#pragma unroll
        for (int rg = 0; rg < 4; rg++)
            optr[rg] = outp + (long)(n0 + q * 4 + rg) * 256 + wcol + c;
    }

#pragma unroll
    for (int i = 0; i < 6; i++) {
        int idx = w * 6 + i;
        int r = idx / 3, ch = idx % 3;
        gload_lds16(gsrc + (long)r * 768 + ch * 256 + lane * 4,
                    &gibuf[0][r * 772 + ch * 256]);
    }
    __syncthreads();

    for (int s = 0; s < steps; s++) {
        const int cur = s & 1;
        if (s + 1 < steps) {
            const float* src = gsrc + gstride;
#pragma unroll
            for (int i = 0; i < 6; i++) {
                int idx = w * 6 + i;
                int r = idx / 3, ch = idx % 3;
                gload_lds16(src + (long)r * 768 + ch * 256 + lane * 4,
                            &gibuf[cur ^ 1][r * 772 + ch * 256]);
            }
        }
        gsrc += gstride;
        asm volatile("" ::: "memory");

        const unsigned short* hrd = &hbuf[cur ^ 1][0][0];
        const float* gp = &gibuf[cur][(q * 4) * 772 + wcol + c];
        unsigned short* hwr = &hbuf[cur][q * 4][wcol + c];

#pragma unroll
        for (int hh = 0; hh < 2; hh++) {
            f32x4 ar = (f32x4){0.f, 0.f, 0.f, 0.f};
            f32x4 az = (f32x4){0.f, 0.f, 0.f, 0.f};
            f32x4 an = (f32x4){0.f, 0.f, 0.f, 0.f};
#pragma unroll
            for (int kt = 0; kt < 8; kt++) {
                bf16x8 a = *(const bf16x8*)&hrd[c * 264 + kt * 32 + q8];
                ar = __builtin_amdgcn_mfma_f32_16x16x32_bf16(a, Bf[0 + hh][kt], ar, 0, 0, 0);
                az = __builtin_amdgcn_mfma_f32_16x16x32_bf16(a, Bf[2 + hh][kt], az, 0, 0, 0);
                an = __builtin_amdgcn_mfma_f32_16x16x32_bf16(a, Bf[4 + hh][kt], an, 0, 0, 0);
            }
#pragma unroll
            for (int rg = 0; rg < 4; rg++) {
                float gr = gp[rg * 772 +       hh * 16];
                float gz = gp[rg * 772 + 256 + hh * 16];
                float gn = gp[rg * 772 + 512 + hh * 16];
                float r  = __builtin_amdgcn_rcpf(1.f + __expf(-(gr + ar[rg])));
                float zg = __builtin_amdgcn_rcpf(1.f + __expf(-(gz + az[rg])));
                float nn = 1.f - 2.f * __builtin_amdgcn_rcpf(1.f + __expf(2.f * (gn + r * an[rg])));
                float hv = (1.f - zg) * nn + zg * hreg[hh][rg];
                hreg[hh][rg] = hv;
                hwr[rg * 264 + hh * 16] = f2b(hv);
                optr[rg][hh * 16] = hv;
            }
            asm volatile("" ::: "memory");
        }

#pragma unroll
        for (int rg = 0; rg < 4; rg++) optr[rg] += ostride;

        asm volatile("s_waitcnt vmcnt(8) lgkmcnt(0)" ::: "memory");
        __builtin_amdgcn_sched_barrier(0);
        __builtin_amdgcn_s_barrier();
        __builtin_amdgcn_sched_barrier(0);
    }

    if (!kgru) {
#pragma unroll
        for (int hh = 0; hh < 2; hh++)
#pragma unroll
            for (int rg = 0; rg < 4; rg++)
                h_state[(long)(n0 + q * 4 + rg) * 256 + wcol + hh * 16 + c] = hreg[hh][rg];
    }
}

// ---- gemm role: 512-thread 64x128 tile, B stored (K,N), swizzled LDS.
// Takes the tile pointers directly so fused_k and tail_k can share it. ----
__device__ __forceinline__ void gemm_role_impl(
    unsigned short (*As)[32], unsigned short (*Bs)[32], const GemmRole& R, int rb)
{
    const int tid = threadIdx.x;
    const int lane = tid & 63, w = tid >> 6;
    const int mt = rb / R.ntn, nt = rb % R.ntn;
    const long m0 = (long)mt * 64, n0 = (long)nt * 128;
    const int wr = (w >> 2) * 32, wc = (w & 3) * 32;

    f32x4 acc[2][2];
#pragma unroll
    for (int i = 0; i < 2; i++)
#pragma unroll
        for (int j = 0; j < 2; j++) acc[i][j] = (f32x4){0.f, 0.f, 0.f, 0.f};

    for (int k0 = 0; k0 < R.K; k0 += 32) {
        {
            const int r = tid >> 3, ck = (tid & 7) << 2;
            const float* s = R.A + (m0 + r) * R.lda + k0 + ck;
            float4 v = *(const float4*)s;
            unsigned short* dp = &As[r][swzi(r, ck >> 3) + (ck & 7)];
            dp[0] = f2b(v.x); dp[1] = f2b(v.y); dp[2] = f2b(v.z); dp[3] = f2b(v.w);
        }
        {
            const int kk = tid >> 4, cn = (tid & 15) << 3;
            const float* s = R.B + (long)(k0 + kk) * R.ldb + n0 + cn;
            float4 v0 = *(const float4*)s, v1 = *(const float4*)(s + 4);
            const int sc = swzi(cn, kk >> 3) + (kk & 7);
            Bs[cn + 0][sc] = f2b(v0.x); Bs[cn + 1][sc] = f2b(v0.y);
            Bs[cn + 2][sc] = f2b(v0.z); Bs[cn + 3][sc] = f2b(v0.w);
            Bs[cn + 4][sc] = f2b(v1.x); Bs[cn + 5][sc] = f2b(v1.y);
            Bs[cn + 6][sc] = f2b(v1.z); Bs[cn + 7][sc] = f2b(v1.w);
        }
        __syncthreads();
        const int l15 = lane & 15, q = lane >> 4;
        bf16x8 a0 = *(const bf16x8*)&As[wr +      l15][swzi(wr +      l15, q)];
        bf16x8 a1 = *(const bf16x8*)&As[wr + 16 + l15][swzi(wr + 16 + l15, q)];
        bf16x8 b0 = *(const bf16x8*)&Bs[wc +      l15][swzi(wc +      l15, q)];
        bf16x8 b1 = *(const bf16x8*)&Bs[wc + 16 + l15][swzi(wc + 16 + l15, q)];
        acc[0][0] = __builtin_amdgcn_mfma_f32_16x16x32_bf16(a0, b0, acc[0][0], 0, 0, 0);
        acc[0][1] = __builtin_amdgcn_mfma_f32_16x16x32_bf16(a0, b1, acc[0][1], 0, 0, 0);
        acc[1][0] = __builtin_amdgcn_mfma_f32_16x16x32_bf16(a1, b0, acc[1][0], 0, 0, 0);
        acc[1][1] = __builtin_amdgcn_mfma_f32_16x16x32_bf16(a1, b1, acc[1][1], 0, 0, 0);
        __syncthreads();
    }
    const int cq = lane >> 4, cc = lane & 15;
#pragma unroll
    for (int i = 0; i < 2; i++)
#pragma unroll
        for (int j = 0; j < 2; j++) {
#pragma unroll
            for (int rg = 0; rg < 4; rg++) {
                long row = m0 + wr + i * 16 + cq * 4 + rg;
                long col = n0 + wc + j * 16 + cc;
                float v = acc[i][j][rg];
                if (R.bias) v += R.bias[col];
                if (R.act == 1) v = v > 0.f ? v : 0.f;
                R.C[row * R.ldc + col] = v;
            }
        }
}

// ---- logits role: dual-z 64x64x512 GEMM (both halves barrier-identical) ----
__device__ __forceinline__ void logits_role_impl(
    unsigned short (*As)[64][32], unsigned short (*Bs)[64][32], int rb,
    const float* Qs, const float* Kb, float* Lout)
{
    const int tid = threadIdx.x;
    const int half = tid >> 8, htid = tid & 255;
    const int z = rb * 2 + half;
    const float* A = Qs + (long)z * 512;
    const float* B = Kb + (long)z * 32768;
    float* C = Lout + (long)z * 64;
    const int lane = htid & 63, w4 = htid >> 6;
    const int wr = (w4 >> 1) * 32, wc = (w4 & 1) * 32;

    f32x4 acc[2][2];
#pragma unroll
    for (int i = 0; i < 2; i++)
#pragma unroll
        for (int j = 0; j < 2; j++) acc[i][j] = (f32x4){0.f, 0.f, 0.f, 0.f};

    for (int k0 = 0; k0 < 512; k0 += 32) {
        const int r = htid >> 2, ck = (htid & 3) << 3;
        {
            const float* s = A + (long)r * 131072 + k0 + ck;
            float4 v0 = *(const float4*)s, v1 = *(const float4*)(s + 4);
            unsigned short* d = &As[half][r][swzi(r, ck >> 3)];
            d[0] = f2b(v0.x); d[1] = f2b(v0.y); d[2] = f2b(v0.z); d[3] = f2b(v0.w);
            d[4] = f2b(v1.x); d[5] = f2b(v1.y); d[6] = f2b(v1.z); d[7] = f2b(v1.w);
        }
        {
            const float* s = B + (long)r * 512 + k0 + ck;
            float4 v0 = *(const float4*)s, v1 = *(const float4*)(s + 4);
            unsigned short* d = &Bs[half][r][swzi(r, ck >> 3)];
            d[0] = f2b(v0.x); d[1] = f2b(v0.y); d[2] = f2b(v0.z); d[3] = f2b(v0.w);
            d[4] = f2b(v1.x); d[5] = f2b(v1.y); d[6] = f2b(v1.z); d[7] = f2b(v1.w);
        }
        __syncthreads();
        const int l15 = lane & 15, q = lane >> 4;
        bf16x8 a0 = *(const bf16x8*)&As[half][wr +      l15][swzi(wr +      l15, q)];
        bf16x8 a1 = *(const bf16x8*)&As[half][wr + 16 + l15][swzi(wr + 16 + l15, q)];
        bf16x8 b0 = *(const bf16x8*)&Bs[half][wc +      l15][swzi(wc +      l15, q)];
        bf16x8 b1 = *(const bf16x8*)&Bs[half][wc + 16 + l15][swzi(wc + 16 + l15, q)];
        acc[0][0] = __builtin_amdgcn_mfma_f32_16x16x32_bf16(a0, b0, acc[0][0], 0, 0, 0);
        acc[0][1] = __builtin_amdgcn_mfma_f32_16x16x32_bf16(a0, b1, acc[0][1], 0, 0, 0);
        acc[1][0] = __builtin_amdgcn_mfma_f32_16x16x32_bf16(a1, b0, acc[1][0], 0, 0, 0);
        acc[1][1] = __builtin_amdgcn_mfma_f32_16x16x32_bf16(a1, b1, acc[1][1], 0, 0, 0);
        __syncthreads();
    }
    const int cq = lane >> 4, cc = lane & 15;
#pragma unroll
    for (int i = 0; i < 2; i++)
#pragma unroll
        for (int j = 0; j < 2; j++) {
#pragma unroll
            for (int rg = 0; rg < 4; rg++)
                C[(long)(wr + i * 16 + cq * 4 + rg) * 16384 + wc + j * 16 + cc] = acc[i][j][rg];
        }
}

// ---- epilogue role: per warp, one (t,n); no barriers ----
__device__ __forceinline__ void epi_role(int rb,
    const float* Hall, const float* Lc, const int* actions,
    const float* critic_W, const float* critic_b, float* out, int t0)
{
    const int w = threadIdx.x >> 6, j = threadIdx.x & 63;
    const int m = rb * 8 + w;
    const int tl = m >> 8, n = m & 255;
    const int t = t0 + tl;
    long o = ((long)t * 256 + n) * 322;
    const float* h = Hall + (long)m * 256;
    float part = 0.f;
#pragma unroll
    for (int i = 0; i < 4; i++) {
        float hv = h[j + 64 * i];
        out[o + 2 + j + 64 * i] = hv;
        part += hv * critic_W[j + 64 * i];
    }
    for (int off = 32; off > 0; off >>= 1) part += __shfl_down(part, off);
    if (j == 0) {
        out[o]     = (float)actions[(long)t * 256 + n];
        out[o + 1] = part + critic_b[0];
    }
    float x = Lc[(long)m * 64 + j];
    float mx = x;
    for (int off = 32; off > 0; off >>= 1) mx = fmaxf(mx, __shfl_down(mx, off));
    mx = __shfl(mx, 0);
    float e = __expf(x - mx);
    float ssum = e;
    for (int off = 32; off > 0; off >>= 1) ssum += __shfl_down(ssum, off);
    ssum = __shfl(ssum, 0);
    out[o + 258 + j] = e / ssum;
}

// ---- build_x role ----
__device__ __forceinline__ void bx_role(int rb,
    const float* values, const float* Mbuf, const int* actions, const int* a0,
    float* Xd, int t0)
{
    const int tid = threadIdx.x;
    if (tid >= 320) return;
    for (int rr = 0; rr < 128; rr++) {
        int m = rb * 128 + rr;
        int tl = m >> 8, n = m & 255;
        int t = t0 + tl;
        float v;
        if (tid < 64) {
            v = values[((long)t * 256 + n) * 64 + tid];
        } else {
            int ap = (t == 0) ? a0[n] : actions[(long)(t - 1) * 256 + n];
            v = Mbuf[((long)n * 64 + ap) * 256 + (tid - 64)];
        }
        Xd[(long)m * 320 + tid] = v;
    }
}

__global__ __launch_bounds__(512, 2) void fused_k(
    const float* sc_gi, const unsigned short* sc_PK, const float* sc_hinit,
    float* sc_out, float* sc_hstate,
    int kgru_nblk, const float* kg_gi0, const float* kg_gi1,
    const unsigned short* kg_PK0, const unsigned short* kg_PK1, float* kg_out,
    GemmRole g0, GemmRole g1, GemmRole g2, GemmRole g3,
    int lg_nblk, const float* lg_Q, const float* lg_K, float* lg_L,
    int ep_nblk, const float* ep_Hall, const float* ep_L, int ep_t0,
    int bx_nblk, const float* values, const float* Mbuf,
    const int* actions, const int* a0, float* bx_dst, int bx_t0,
    const float* critic_W, const float* critic_b, float* out)
{
    __shared__ __align__(16) FusedLds L;
    int b = blockIdx.x;
    if (b < 16) {
        scan_role(&L, sc_gi, sc_PK, sc_hinit, sc_out, sc_hstate, b * 16, TCHUNK, 0, 0);
        return;
    }
    b -= 16;
    if (b < kgru_nblk) {
        int d = b >> 4, n0 = (b & 15) * 16;
        scan_role(&L, d ? kg_gi1 : kg_gi0, d ? kg_PK1 : kg_PK0, nullptr,
                  kg_out, nullptr, n0, 64, 1, d);
        return;
    }
    b -= kgru_nblk;
    if (b < g0.nblocks) { gemm_role_impl(L.g.As, L.g.Bs, g0, b); return; }
    b -= g0.nblocks;
    if (b < g1.nblocks) { gemm_role_impl(L.g.As, L.g.Bs, g1, b); return; }
    b -= g1.nblocks;
    if (b < g2.nblocks) { gemm_role_impl(L.g.As, L.g.Bs, g2, b); return; }
    b -= g2.nblocks;
    if (b < g3.nblocks) { gemm_role_impl(L.g.As, L.g.Bs, g3, b); return; }
    b -= g3.nblocks;
    if (b < lg_nblk) { logits_role_impl(L.l.As2, L.l.Bs2, b, lg_Q, lg_K, lg_L); return; }
    b -= lg_nblk;
    if (b < ep_nblk) { epi_role(b, ep_Hall, ep_L, actions, critic_W, critic_b, out, ep_t0); return; }
    b -= ep_nblk;
    if (b < bx_nblk) bx_role(b, values, Mbuf, actions, a0, bx_dst, bx_t0);
}

// ---- Tail kernel: roles only, SMALL LDS union (16.4KB -> 4 blocks/CU). ----
__global__ __launch_bounds__(512, 2) void tail_k(
    GemmRole g3,
    int lg_nblk, const float* lg_Q, const float* lg_K, float* lg_L,
    int ep_nblk, const float* ep_Hall, const float* ep_L, int ep_t0,
    const int* actions, const float* critic_W, const float* critic_b, float* out)
{
    __shared__ __align__(16) TailLds L;
    int b = blockIdx.x;
    if (b < g3.nblocks) { gemm_role_impl(L.g.As, L.g.Bs, g3, b); return; }
    b -= g3.nblocks;
    if (b < lg_nblk) { logits_role_impl(L.l.As2, L.l.Bs2, b, lg_Q, lg_K, lg_L); return; }
    b -= lg_nblk;
    if (b < ep_nblk) epi_role(b, ep_Hall, ep_L, actions, critic_W, critic_b, out, ep_t0);
}

// ---------------------------------------------------------------------------
// Epilogue kernel (final tail use)
// ---------------------------------------------------------------------------
__global__ __launch_bounds__(64) void epilogue_k(
    const float* __restrict__ Hallc, const float* __restrict__ Lc,
    const int* __restrict__ actions,
    const float* __restrict__ critic_W, const float* __restrict__ critic_b,
    float* __restrict__ out, int t0)
{
    int m = blockIdx.x;
    int tl = m >> 8, n = m & 255;
    int t = t0 + tl;
    int j = threadIdx.x;
    long o = ((long)t * 256 + n) * 322;
    const float* h = Hallc + (long)m * 256;
    float part = 0.f;
#pragma unroll
    for (int i = 0; i < 4; i++) {
        float hv = h[j + 64 * i];
        out[o + 2 + j + 64 * i] = hv;
        part += hv * critic_W[j + 64 * i];
    }
    for (int off = 32; off > 0; off >>= 1) part += __shfl_down(part, off);
    if (j == 0) {
        out[o]     = (float)actions[(long)t * 256 + n];
        out[o + 1] = part + critic_b[0];
    }
    float x = Lc[(long)m * 64 + j];
    float mx = x;
    for (int off = 32; off > 0; off >>= 1) mx = fmaxf(mx, __shfl_down(mx, off));
    mx = __shfl(mx, 0);
    float e = __expf(x - mx);
    float ssum = e;
    for (int off = 32; off > 0; off >>= 1) ssum += __shfl_down(ssum, off);
    ssum = __shfl(ssum, 0);
    out[o + 258 + j] = e / ssum;
}

// ---------------------------------------------------------------------------
extern "C" void kernel_launch(void* const* d_in, const int* in_sizes, int n_in,
                              void* d_out, int out_size, void* d_ws, size_t ws_size,
                              hipStream_t stream)
{
    const float* values   = (const float*)d_in[0];
    const float* mdp      = (const float*)d_in[1];
    const int*   actions  = (const int*)  d_in[2];
    const int*   a0       = (const int*)  d_in[3];
    const float* h0       = (const float*)d_in[4];
    const float* emb_W    = (const float*)d_in[5];
    const float* emb_b    = (const float*)d_in[6];
    const float* gfw_Wih  = (const float*)d_in[7];
    const float* gfw_Whh  = (const float*)d_in[8];
    const float* gfw_bih  = (const float*)d_in[9];
    const float* gfw_bhh  = (const float*)d_in[10];
    const float* gbw_Wih  = (const float*)d_in[11];
    const float* gbw_Whh  = (const float*)d_in[12];
    const float* gbw_bih  = (const float*)d_in[13];
    const float* gbw_bhh  = (const float*)d_in[14];
    const float* f0_W     = (const float*)d_in[15];
    const float* f0_b     = (const float*)d_in[16];
    const float* f1_W     = (const float*)d_in[17];
    const float* f1_b     = (const float*)d_in[18];
    const float* cell_Wih = (const float*)d_in[19];
    const float* cell_Whh = (const float*)d_in[20];
    const float* cell_bih = (const float*)d_in[21];
    const float* cell_bhh = (const float*)d_in[22];
    const float* critic_W = (const float*)d_in[23];
    const float* critic_b = (const float*)d_in[24];
    const float* qg_W     = (const float*)d_in[25];
    const float* qg_b     = (const float*)d_in[26];
    float* out = (float*)d_out;

    char* base = (char*)d_ws;
    size_t off = 0;
    auto alloc = [&](size_t nf) -> float* {
        float* p = (float*)(base + off);
        off += nf * sizeof(float);
        off = (off + 255) & ~(size_t)255;
        return p;
    };
    float* Mbuf   = alloc(16384ull * 256);
    float* Mseq   = alloc(16384ull * 256);   // aliased as Hallr[2] (dead after prologue)
    float* gfA    = alloc(16384ull * 768);
    float* gbA    = alloc(16384ull * 768);   // aliased as Qr[1] from fused(2) on
    float* Kbuf   = alloc(256ull * 64 * 512);
    float* PKf    = alloc(98304);
    float* PKb    = alloc(98304);
    float* PKc    = alloc(98304);
    float* hstate = alloc(256ull * 256);
    float* Xr[2]    = { alloc(16384ull * 320), alloc(16384ull * 320) };
    float* X0r[2]   = { alloc(16384ull * 256), alloc(16384ull * 256) };
    float* X1r[2]   = { alloc(16384ull * 256), alloc(16384ull * 256) };
    float* GIr[2]   = { alloc(16384ull * 768), alloc(16384ull * 768) };
    float* Hallr[4] = { alloc(16384ull * 256), alloc(16384ull * 256),
                        Mseq, alloc(16384ull * 256) };
    float* Qr[2]  = { alloc(16384ull * 512), gbA };  // gbA dead after fused(0) kgru
    float* Lr[2]  = { alloc(16384ull * 64), alloc(16384ull * 64) };
    float* bias_f = alloc(768);
    float* bias_b = alloc(768);
    float* bias_c = alloc(768);
    (void)ws_size; (void)in_sizes; (void)n_in; (void)out_size;

    dim3 blk(256);

    // ---- Phase 1: embeddings, gate-input GEMMs (serial, v7 schedule), packing ----
    gemm_f32<false, 0><<<dim3(4, 256, 1), blk, 0, stream>>>(
        mdp, 128, 0, emb_W, 256, 0, emb_b, Mbuf, 256, 0, 16384, 256, 128);
    seq_major<<<dim3(16384), blk, 0, stream>>>(Mbuf, Mseq);
    pack_w<<<dim3(96, 3, 1), blk, 0, stream>>>(
        gfw_Whh, gbw_Whh, cell_Whh,
        (unsigned short*)PKf, (unsigned short*)PKb, (unsigned short*)PKc);
    combine_bias<<<dim3(3), blk, 0, stream>>>(gfw_bih, gfw_bhh, gbw_bih, gbw_bhh,
                                              cell_bih, cell_bhh, bias_f, bias_b, bias_c);
    gemm_f32<false, 0><<<dim3(12, 256, 1), blk, 0, stream>>>(
        Mseq, 256, 0, gfw_Wih, 768, 0, bias_f, gfA, 768, 0, 16384, 768, 256);
    gemm_f32<false, 0><<<dim3(12, 256, 1), blk, 0, stream>>>(
        Mseq, 256, 0, gbw_Wih, 768, 0, bias_b, gbA, 768, 0, 16384, 768, 256);

    // ---- Pipeline priming (x-path for chunks 0..3 partial) ----
    build_x<<<dim3(16384), dim3(320), 0, stream>>>(values, Mbuf, actions, a0, Xr[0], 0);
    gemm_f32<false, 1><<<dim3(4, 256, 1), blk, 0, stream>>>(
        Xr[0], 320, 0, f0_W, 256, 0, f0_b, X0r[0], 256, 0, 16384, 256, 320);
    build_x<<<dim3(16384), dim3(320), 0, stream>>>(values, Mbuf, actions, a0, Xr[1], 64);
    gemm_f32<false, 1><<<dim3(4, 256, 1), blk, 0, stream>>>(
        Xr[1], 320, 0, f0_W, 256, 0, f0_b, X0r[1], 256, 0, 16384, 256, 320);
    gemm_f32<false, 1><<<dim3(4, 256, 1), blk, 0, stream>>>(
        X0r[0], 256, 0, f1_W, 256, 0, f1_b, X1r[0], 256, 0, 16384, 256, 256);
    build_x<<<dim3(16384), dim3(320), 0, stream>>>(values, Mbuf, actions, a0, Xr[0], 128);
    gemm_f32<false, 1><<<dim3(4, 256, 1), blk, 0, stream>>>(
        Xr[0], 320, 0, f0_W, 256, 0, f0_b, X0r[0], 256, 0, 16384, 256, 320);
    gemm_f32<false, 1><<<dim3(4, 256, 1), blk, 0, stream>>>(
        X0r[1], 256, 0, f1_W, 256, 0, f1_b, X1r[1], 256, 0, 16384, 256, 256);
    build_x<<<dim3(16384), dim3(320), 0, stream>>>(values, Mbuf, actions, a0, Xr[1], 192);
    gemm_f32<false, 0><<<dim3(12, 256, 1), blk, 0, stream>>>(
        X1r[0], 256, 0, cell_Wih, 768, 0, bias_c, GIr[0], 768, 0, 16384, 768, 256);

    // ---- Fused pipeline (v7 schedule):
    //   fused(c) = scan(c) | kgru(c==0) | f0(c+3) | f1(c+2) | GI(c+1)
    //            | qg(c-1) | logits(c-2) | epi(c-3) | bx(c+4)
    for (int c = 0; c < NCHUNK; c++) {
        GemmRole g0{}, g1{}, g2{}, g3{};
        if (c <= 4) g0 = GemmRole{ Xr[(c + 1) & 1], f0_W, f0_b, X0r[(c + 1) & 1],
                                   320, 320, 256, 256, 1, 512, 2 };
        if (c <= 5) g1 = GemmRole{ X0r[c & 1], f1_W, f1_b, X1r[c & 1],
                                   256, 256, 256, 256, 1, 512, 2 };
        if (c <= 6) g2 = GemmRole{ X1r[(c + 1) & 1], cell_Wih, bias_c, GIr[(c + 1) & 1],
                                   256, 256, 768, 768, 0, 1536, 6 };
        if (c >= 1) g3 = GemmRole{ Hallr[(c - 1) & 3], qg_W, qg_b, Qr[(c - 1) & 1],
                                   256, 256, 512, 512, 0, 1024, 4 };
        int kgn = (c == 0) ? 32 : 0;
        int lgn = (c >= 2) ? 128 : 0;
        int epn = (c >= 3) ? 2048 : 0;
        int bxn = (c <= 3) ? 128 : 0;
        int total = 16 + kgn + g0.nblocks + g1.nblocks + g2.nblocks + g3.nblocks
                    + lgn + epn + bxn;

        fused_k<<<dim3(total), dim3(512), 0, stream>>>(
            GIr[c & 1], (const unsigned short*)PKc, (c == 0) ? h0 : (const float*)hstate,
            Hallr[c & 3], hstate,
            kgn, gfA, gbA, (const unsigned short*)PKf, (const unsigned short*)PKb, Kbuf,
            g0, g1, g2, g3,
            lgn, Qr[(c - 2) & 1], Kbuf, Lr[(c - 2) & 1],
            epn, Hallr[(c - 3) & 3], Lr[(c - 3) & 1], (c - 3) * 64,
            bxn, values, Mbuf, actions, a0, Xr[c & 1], (c + 4) * 64,
            critic_W, critic_b, out);
    }

    // ---- Tail drain (small-LDS tail_k): T1 = qg(7) | logits(6) | epi(5) ----
    {
        GemmRole g3t = GemmRole{ Hallr[3], qg_W, qg_b, Qr[1],
                                 256, 256, 512, 512, 0, 1024, 4 };
        tail_k<<<dim3(1024 + 128 + 2048), dim3(512), 0, stream>>>(
            g3t, 128, Qr[0], Kbuf, Lr[0],
            2048, Hallr[1], Lr[1], 5 * 64,
            actions, critic_W, critic_b, out);
    }
    // ---- T2 = logits(7) | epi(6) ----
    {
        GemmRole gz{};
        tail_k<<<dim3(128 + 2048), dim3(512), 0, stream>>>(
            gz, 128, Qr[1], Kbuf, Lr[1],
            2048, Hallr[2], Lr[0], 6 * 64,
            actions, critic_W, critic_b, out);
    }
    // ---- T3 = epi(7) ----
    epilogue_k<<<dim3(16384), dim3(64), 0, stream>>>(
        Hallr[3], Lr[1], actions, critic_W, critic_b, out, 7 * 64);
}

// Round 17
// 1916.306 us; speedup vs baseline: 3.1054x; 1.0939x over previous
//
#include <hip/hip_runtime.h>

// Problem constants (reference: T=512, N=256, H=256, HR=64, WC=128, V=64)
#define TSTEPS 512
#define NBATCH 256
#define HID    256
#define TCHUNK 64
#define NCHUNK 8

typedef __attribute__((ext_vector_type(8))) short bf16x8;
typedef __attribute__((ext_vector_type(4))) float f32x4;

__device__ __forceinline__ unsigned short f2b(float x) {
    union { float f; unsigned int u; } c; c.f = x;
    unsigned int u = c.u;
    return (unsigned short)((u + 0x7fffu + ((u >> 16) & 1u)) >> 16);
}

__device__ __forceinline__ void gload_lds16(const float* g, float* l) {
    __builtin_amdgcn_global_load_lds(
        (const __attribute__((address_space(1))) unsigned int*)g,
        (__attribute__((address_space(3))) unsigned int*)l,
        16, 0, 0);
}

// LDS bank-conflict mitigation for [row][32]-short GEMM tiles (v7, kept).
__device__ __forceinline__ int swzi(int row, int g) {
    return ((g ^ ((row >> 3) & 3)) << 3);
}

// ---------------------------------------------------------------------------
// Generic GEMM (256 thr): C = act(A@B + bias). Prologue use. Swizzled LDS.
// ---------------------------------------------------------------------------
template<bool TRANS_B, int ACT>
__global__ __launch_bounds__(256) void gemm_f32(
    const float* __restrict__ A, long lda, long sA,
    const float* __restrict__ B, long ldb, long sB,
    const float* __restrict__ bias,
    float* __restrict__ C, long ldc, long sC,
    int M, int N, int K)
{
    __shared__ __align__(16) unsigned short As[64][32];
    __shared__ __align__(16) unsigned short Bs[64][32];
    const int z = blockIdx.z;
    A += (long)z * sA; B += (long)z * sB; C += (long)z * sC;
    const int n0 = blockIdx.x * 64, m0 = blockIdx.y * 64;
    const int tid  = threadIdx.x;
    const int lane = tid & 63, w = tid >> 6;
    const int wr = (w >> 1) * 32, wc = (w & 1) * 32;

    f32x4 acc[2][2];
#pragma unroll
    for (int i = 0; i < 2; i++)
#pragma unroll
        for (int j = 0; j < 2; j++) acc[i][j] = (f32x4){0.f, 0.f, 0.f, 0.f};

    for (int k0 = 0; k0 < K; k0 += 32) {
        {
            const int r = tid >> 2, ck = (tid & 3) << 3;
            const float* s = A + (long)(m0 + r) * lda + k0 + ck;
            float4 v0 = *(const float4*)s, v1 = *(const float4*)(s + 4);
            unsigned short* d = &As[r][swzi(r, ck >> 3)];
            d[0] = f2b(v0.x); d[1] = f2b(v0.y); d[2] = f2b(v0.z); d[3] = f2b(v0.w);
            d[4] = f2b(v1.x); d[5] = f2b(v1.y); d[6] = f2b(v1.z); d[7] = f2b(v1.w);
        }
        if (TRANS_B) {
            const int r = tid >> 2, ck = (tid & 3) << 3;
            const float* s = B + (long)(n0 + r) * ldb + k0 + ck;
            float4 v0 = *(const float4*)s, v1 = *(const float4*)(s + 4);
            unsigned short* d = &Bs[r][swzi(r, ck >> 3)];
            d[0] = f2b(v0.x); d[1] = f2b(v0.y); d[2] = f2b(v0.z); d[3] = f2b(v0.w);
            d[4] = f2b(v1.x); d[5] = f2b(v1.y); d[6] = f2b(v1.z); d[7] = f2b(v1.w);
        } else {
            const int kk = tid >> 3, cn = (tid & 7) << 3;
            const float* s = B + (long)(k0 + kk) * ldb + n0 + cn;
            float4 v0 = *(const float4*)s, v1 = *(const float4*)(s + 4);
            const int sc = swzi(cn, kk >> 3) + (kk & 7);
            Bs[cn + 0][sc] = f2b(v0.x); Bs[cn + 1][sc] = f2b(v0.y);
            Bs[cn + 2][sc] = f2b(v0.z); Bs[cn + 3][sc] = f2b(v0.w);
            Bs[cn + 4][sc] = f2b(v1.x); Bs[cn + 5][sc] = f2b(v1.y);
            Bs[cn + 6][sc] = f2b(v1.z); Bs[cn + 7][sc] = f2b(v1.w);
        }
        __syncthreads();
        const int l15 = lane & 15, q = lane >> 4;
        bf16x8 a0 = *(const bf16x8*)&As[wr +      l15][swzi(wr +      l15, q)];
        bf16x8 a1 = *(const bf16x8*)&As[wr + 16 + l15][swzi(wr + 16 + l15, q)];
        bf16x8 b0 = *(const bf16x8*)&Bs[wc +      l15][swzi(wc +      l15, q)];
        bf16x8 b1 = *(const bf16x8*)&Bs[wc + 16 + l15][swzi(wc + 16 + l15, q)];
        acc[0][0] = __builtin_amdgcn_mfma_f32_16x16x32_bf16(a0, b0, acc[0][0], 0, 0, 0);
        acc[0][1] = __builtin_amdgcn_mfma_f32_16x16x32_bf16(a0, b1, acc[0][1], 0, 0, 0);
        acc[1][0] = __builtin_amdgcn_mfma_f32_16x16x32_bf16(a1, b0, acc[1][0], 0, 0, 0);
        acc[1][1] = __builtin_amdgcn_mfma_f32_16x16x32_bf16(a1, b1, acc[1][1], 0, 0, 0);
        __syncthreads();
    }
    const int cq = lane >> 4, cc = lane & 15;
#pragma unroll
    for (int i = 0; i < 2; i++)
#pragma unroll
        for (int j = 0; j < 2; j++) {
#pragma unroll
            for (int rg = 0; rg < 4; rg++) {
                int row = m0 + wr + i * 16 + cq * 4 + rg;
                int col = n0 + wc + j * 16 + cc;
                float v = acc[i][j][rg];
                if (bias) v += bias[col];
                if (ACT == 1) v = v > 0.f ? v : 0.f;
                C[(long)row * ldc + col] = v;
            }
        }
}

// ---------------------------------------------------------------------------
// Helpers
// ---------------------------------------------------------------------------
__global__ void combine_bias(const float* a0, const float* b0,
                             const float* a1, const float* b1,
                             const float* a2, const float* b2,
                             float* o0, float* o1, float* o2)
{
    int i = blockIdx.x * 256 + threadIdx.x;
    o0[i] = a0[i] + b0[i];
    o1[i] = a1[i] + b1[i];
    o2[i] = a2[i] + b2[i];
}

__global__ void seq_major(const float* __restrict__ M, float* __restrict__ Mseq)
{
    int b = blockIdx.x;
    int s = b >> 8, n = b & 255;
    int t = threadIdx.x;
    Mseq[(long)b * 256 + t] = M[((long)n * 64 + s) * 256 + t];
}

// ---------------------------------------------------------------------------
// pack_w: 8-wave scan fragment layout (v3/v7, proven).
// ---------------------------------------------------------------------------
__global__ __launch_bounds__(256) void pack_w(
    const float* __restrict__ Wf, const float* __restrict__ Wb, const float* __restrict__ Wc,
    unsigned short* __restrict__ Pf, unsigned short* __restrict__ Pb, unsigned short* __restrict__ Pc)
{
    int chunk = blockIdx.x * 256 + threadIdx.x;      // 0..24575
    const float* W = (blockIdx.y == 0) ? Wf : ((blockIdx.y == 1) ? Wb : Wc);
    unsigned short* P = (blockIdx.y == 0) ? Pf : ((blockIdx.y == 1) ? Pb : Pc);
    int lane = chunk & 63;
    int kt   = (chunk >> 6) & 7;
    int f    = (chunk >> 9) % 6;
    int w    = chunk / 3072;
    int g = f >> 1, hh = f & 1;
    int c = lane & 15, q = lane >> 4;
    int col = g * 256 + w * 32 + hh * 16 + c;
    int k0  = kt * 32 + q * 8;
    unsigned int v[8];
#pragma unroll
    for (int j = 0; j < 8; j++) v[j] = f2b(W[(long)(k0 + j) * 768 + col]);
    uint4 o;
    o.x = v[0] | (v[1] << 16); o.y = v[2] | (v[3] << 16);
    o.z = v[4] | (v[5] << 16); o.w = v[6] | (v[7] << 16);
    *(uint4*)&P[(long)chunk * 8] = o;
}

__global__ void build_x(const float* __restrict__ values, const float* __restrict__ Mbuf,
                        const int* __restrict__ actions, const int* __restrict__ a0,
                        float* __restrict__ Xc, int t0)
{
    int m = blockIdx.x;
    int tl = m >> 8, n = m & 255;
    int t = t0 + tl;
    int c = threadIdx.x;
    float v;
    if (c < 64) {
        v = values[((long)t * 256 + n) * 64 + c];
    } else {
        int ap = (t == 0) ? a0[n] : actions[(long)(t - 1) * 256 + n];
        v = Mbuf[((long)n * 64 + ap) * 256 + (c - 64)];
    }
    Xc[(long)m * 320 + c] = v;
}

// ---------------------------------------------------------------------------
// Fused kernel v15 = v14 + 128x128 gemm-role tiles (half the role blocks,
// double MFMA per barrier at 1 blk/CU).
// ---------------------------------------------------------------------------
struct GemmRole {
    const float* A; const float* B; const float* bias; float* C;
    int K; long lda; long ldb; long ldc; int act; int nblocks; int ntn;
};

union FusedLds {
    struct { unsigned short hbuf[2][16][264]; float gibuf[2][16 * 772]; } s;
    struct { unsigned short As[128][32]; unsigned short Bs[128][32]; } g;
    struct { unsigned short As2[2][64][32]; unsigned short Bs2[2][64][32]; } l;
};
// Tail union: roles only (gemm 16.4KB, logits 16.4KB) -> ~16.4KB.
union TailLds {
    struct { unsigned short As[128][32]; unsigned short Bs[128][32]; } g;
    struct { unsigned short As2[2][64][32]; unsigned short Bs2[2][64][32]; } l;
};

// ---- scan role: EXACT v3/v7 structure (8 waves, split-hh, fences, vmcnt(8)) ----
__device__ __forceinline__ void scan_role(FusedLds* L,
    const float* gi, const unsigned short* PK, const float* h_init,
    float* outp, float* h_state, int n0, int steps, int kgru, int d)
{
    auto& hbuf  = L->s.hbuf;
    auto& gibuf = L->s.gibuf;
    const int tid = threadIdx.x;
    const int w = tid >> 6, lane = tid & 63;
    const int q = lane >> 4, c = lane & 15, q8 = q << 3;
    const int wcol = w * 32;

    bf16x8 Bf[6][8];
#pragma unroll
    for (int f = 0; f < 6; f++)
#pragma unroll
        for (int kt = 0; kt < 8; kt++)
            Bf[f][kt] = *(const bf16x8*)&PK[(((long)(w * 6 + f) * 8 + kt) * 64 + lane) * 8];

    f32x4 hreg[2];
#pragma unroll
    for (int hh = 0; hh < 2; hh++)
#pragma unroll
        for (int rg = 0; rg < 4; rg++) {
            float v = 0.f;
            if (!kgru) v = h_init[(long)(n0 + q * 4 + rg) * 256 + wcol + hh * 16 + c];
            hreg[hh][rg] = v;
            hbuf[1][q * 4 + rg][wcol + hh * 16 + c] = f2b(v);
        }

    const int row0 = kgru ? (d ? 63 : 0) : 0;
    const long gstride = (kgru && d) ? -196608L : 196608L;
    const float* gsrc = gi + ((long)row0 * 256 + n0) * 768;
    float* optr[4];
    long ostride;
    if (kgru) {
        ostride = d ? -512L : 512L;
#pragma unroll
        for (int rg = 0; rg < 4; rg++)
            optr[rg] = outp + ((long)(n0 + q * 4 + rg) * 64 + row0) * 512 + d * 256 + wcol + c;
    } else {
        ostride = 65536L;
#pragma unroll
        for (int rg = 0; rg < 4; rg++)
            optr[rg] = outp + (long)(n0 + q * 4 + rg) * 256 + wcol + c;
    }

#pragma unroll
    for (int i = 0; i < 6; i++) {
        int idx = w * 6 + i;
        int r = idx / 3, ch = idx % 3;
        gload_lds16(gsrc + (long)r * 768 + ch * 256 + lane * 4,
                    &gibuf[0][r * 772 + ch * 256]);
    }
    __syncthreads();

    for (int s = 0; s < steps; s++) {
        const int cur = s & 1;
        if (s + 1 < steps) {
            const float* src = gsrc + gstride;
#pragma unroll
            for (int i = 0; i < 6; i++) {
                int idx = w * 6 + i;
                int r = idx / 3, ch = idx % 3;
                gload_lds16(src + (long)r * 768 + ch * 256 + lane * 4,
                            &gibuf[cur ^ 1][r * 772 + ch * 256]);
            }
        }
        gsrc += gstride;
        asm volatile("" ::: "memory");

        const unsigned short* hrd = &hbuf[cur ^ 1][0][0];
        const float* gp = &gibuf[cur][(q * 4) * 772 + wcol + c];
        unsigned short* hwr = &hbuf[cur][q * 4][wcol + c];

#pragma unroll
        for (int hh = 0; hh < 2; hh++) {
            f32x4 ar = (f32x4){0.f, 0.f, 0.f, 0.f};
            f32x4 az = (f32x4){0.f, 0.f, 0.f, 0.f};
            f32x4 an = (f32x4){0.f, 0.f, 0.f, 0.f};
#pragma unroll
            for (int kt = 0; kt < 8; kt++) {
                bf16x8 a = *(const bf16x8*)&hrd[c * 264 + kt * 32 + q8];
                ar = __builtin_amdgcn_mfma_f32_16x16x32_bf16(a, Bf[0 + hh][kt], ar, 0, 0, 0);
                az = __builtin_amdgcn_mfma_f32_16x16x32_bf16(a, Bf[2 + hh][kt], az, 0, 0, 0);
                an = __builtin_amdgcn_mfma_f32_16x16x32_bf16(a, Bf[4 + hh][kt], an, 0, 0, 0);
            }
#pragma unroll
            for (int rg = 0; rg < 4; rg++) {
                float gr = gp[rg * 772 +       hh * 16];
                float gz = gp[rg * 772 + 256 + hh * 16];
                float gn = gp[rg * 772 + 512 + hh * 16];
                float r  = __builtin_amdgcn_rcpf(1.f + __expf(-(gr + ar[rg])));
                float zg = __builtin_amdgcn_rcpf(1.f + __expf(-(gz + az[rg])));
                float nn = 1.f - 2.f * __builtin_amdgcn_rcpf(1.f + __expf(2.f * (gn + r * an[rg])));
                float hv = (1.f - zg) * nn + zg * hreg[hh][rg];
                hreg[hh][rg] = hv;
                hwr[rg * 264 + hh * 16] = f2b(hv);
                optr[rg][hh * 16] = hv;
            }
            asm volatile("" ::: "memory");
        }

#pragma unroll
        for (int rg = 0; rg < 4; rg++) optr[rg] += ostride;

        asm volatile("s_waitcnt vmcnt(8) lgkmcnt(0)" ::: "memory");
        __builtin_amdgcn_sched_barrier(0);
        __builtin_amdgcn_s_barrier();
        __builtin_amdgcn_sched_barrier(0);
    }

    if (!kgru) {
#pragma unroll
        for (int hh = 0; hh < 2; hh++)
#pragma unroll
            for (int rg = 0; rg < 4; rg++)
                h_state[(long)(n0 + q * 4 + rg) * 256 + wcol + hh * 16 + c] = hreg[hh][rg];
    }
}

// ---- gemm role: 512-thread 128x128 tile, B stored (K,N), swizzled LDS.
// Each wave computes its 32x32 quadrant at rows wr and wr+64. ----
__device__ __forceinline__ void gemm_role_impl(
    unsigned short (*As)[32], unsigned short (*Bs)[32], const GemmRole& R, int rb)
{
    const int tid = threadIdx.x;
    const int lane = tid & 63, w = tid >> 6;
    const int mt = rb / R.ntn, nt = rb % R.ntn;
    const long m0 = (long)mt * 128, n0 = (long)nt * 128;
    const int wr = (w >> 2) * 32, wc = (w & 3) * 32;

    f32x4 acc[2][2][2];   // [mhalf][i][j]
#pragma unroll
    for (int h = 0; h < 2; h++)
#pragma unroll
        for (int i = 0; i < 2; i++)
#pragma unroll
            for (int j = 0; j < 2; j++) acc[h][i][j] = (f32x4){0.f, 0.f, 0.f, 0.f};

    for (int k0 = 0; k0 < R.K; k0 += 32) {
        {   // A: 128 x 32, 512 thr x 8 floats
            const int r = tid >> 2, ck = (tid & 3) << 3;
            const float* s = R.A + (m0 + r) * R.lda + k0 + ck;
            float4 v0 = *(const float4*)s, v1 = *(const float4*)(s + 4);
            unsigned short* d = &As[r][swzi(r, ck >> 3)];
            d[0] = f2b(v0.x); d[1] = f2b(v0.y); d[2] = f2b(v0.z); d[3] = f2b(v0.w);
            d[4] = f2b(v1.x); d[5] = f2b(v1.y); d[6] = f2b(v1.z); d[7] = f2b(v1.w);
        }
        {   // B: 32 x 128 scatter-transpose
            const int kk = tid >> 4, cn = (tid & 15) << 3;
            const float* s = R.B + (long)(k0 + kk) * R.ldb + n0 + cn;
            float4 v0 = *(const float4*)s, v1 = *(const float4*)(s + 4);
            const int sc = swzi(cn, kk >> 3) + (kk & 7);
            Bs[cn + 0][sc] = f2b(v0.x); Bs[cn + 1][sc] = f2b(v0.y);
            Bs[cn + 2][sc] = f2b(v0.z); Bs[cn + 3][sc] = f2b(v0.w);
            Bs[cn + 4][sc] = f2b(v1.x); Bs[cn + 5][sc] = f2b(v1.y);
            Bs[cn + 6][sc] = f2b(v1.z); Bs[cn + 7][sc] = f2b(v1.w);
        }
        __syncthreads();
        const int l15 = lane & 15, q = lane >> 4;
        bf16x8 b0 = *(const bf16x8*)&Bs[wc +      l15][swzi(wc +      l15, q)];
        bf16x8 b1 = *(const bf16x8*)&Bs[wc + 16 + l15][swzi(wc + 16 + l15, q)];
#pragma unroll
        for (int h = 0; h < 2; h++) {
            const int rb0 = wr + h * 64;
            bf16x8 a0 = *(const bf16x8*)&As[rb0 +      l15][swzi(rb0 +      l15, q)];
            bf16x8 a1 = *(const bf16x8*)&As[rb0 + 16 + l15][swzi(rb0 + 16 + l15, q)];
            acc[h][0][0] = __builtin_amdgcn_mfma_f32_16x16x32_bf16(a0, b0, acc[h][0][0], 0, 0, 0);
            acc[h][0][1] = __builtin_amdgcn_mfma_f32_16x16x32_bf16(a0, b1, acc[h][0][1], 0, 0, 0);
            acc[h][1][0] = __builtin_amdgcn_mfma_f32_16x16x32_bf16(a1, b0, acc[h][1][0], 0, 0, 0);
            acc[h][1][1] = __builtin_amdgcn_mfma_f32_16x16x32_bf16(a1, b1, acc[h][1][1], 0, 0, 0);
        }
        __syncthreads();
    }
    const int cq = lane >> 4, cc = lane & 15;
#pragma unroll
    for (int h = 0; h < 2; h++)
#pragma unroll
        for (int i = 0; i < 2; i++)
#pragma unroll
            for (int j = 0; j < 2; j++) {
#pragma unroll
                for (int rg = 0; rg < 4; rg++) {
                    long row = m0 + wr + h * 64 + i * 16 + cq * 4 + rg;
                    long col = n0 + wc + j * 16 + cc;
                    float v = acc[h][i][j][rg];
                    if (R.bias) v += R.bias[col];
                    if (R.act == 1) v = v > 0.f ? v : 0.f;
                    R.C[row * R.ldc + col] = v;
                }
            }
}

// ---- logits role: dual-z 64x64x512 GEMM (both halves barrier-identical) ----
__device__ __forceinline__ void logits_role_impl(
    unsigned short (*As)[64][32], unsigned short (*Bs)[64][32], int rb,
    const float* Qs, const float* Kb, float* Lout)
{
    const int tid = threadIdx.x;
    const int half = tid >> 8, htid = tid & 255;
    const int z = rb * 2 + half;
    const float* A = Qs + (long)z * 512;
    const float* B = Kb + (long)z * 32768;
    float* C = Lout + (long)z * 64;
    const int lane = htid & 63, w4 = htid >> 6;
    const int wr = (w4 >> 1) * 32, wc = (w4 & 1) * 32;

    f32x4 acc[2][2];
#pragma unroll
    for (int i = 0; i < 2; i++)
#pragma unroll
        for (int j = 0; j < 2; j++) acc[i][j] = (f32x4){0.f, 0.f, 0.f, 0.f};

    for (int k0 = 0; k0 < 512; k0 += 32) {
        const int r = htid >> 2, ck = (htid & 3) << 3;
        {
            const float* s = A + (long)r * 131072 + k0 + ck;
            float4 v0 = *(const float4*)s, v1 = *(const float4*)(s + 4);
            unsigned short* d = &As[half][r][swzi(r, ck >> 3)];
            d[0] = f2b(v0.x); d[1] = f2b(v0.y); d[2] = f2b(v0.z); d[3] = f2b(v0.w);
            d[4] = f2b(v1.x); d[5] = f2b(v1.y); d[6] = f2b(v1.z); d[7] = f2b(v1.w);
        }
        {
            const float* s = B + (long)r * 512 + k0 + ck;
            float4 v0 = *(const float4*)s, v1 = *(const float4*)(s + 4);
            unsigned short* d = &Bs[half][r][swzi(r, ck >> 3)];
            d[0] = f2b(v0.x); d[1] = f2b(v0.y); d[2] = f2b(v0.z); d[3] = f2b(v0.w);
            d[4] = f2b(v1.x); d[5] = f2b(v1.y); d[6] = f2b(v1.z); d[7] = f2b(v1.w);
        }
        __syncthreads();
        const int l15 = lane & 15, q = lane >> 4;
        bf16x8 a0 = *(const bf16x8*)&As[half][wr +      l15][swzi(wr +      l15, q)];
        bf16x8 a1 = *(const bf16x8*)&As[half][wr + 16 + l15][swzi(wr + 16 + l15, q)];
        bf16x8 b0 = *(const bf16x8*)&Bs[half][wc +      l15][swzi(wc +      l15, q)];
        bf16x8 b1 = *(const bf16x8*)&Bs[half][wc + 16 + l15][swzi(wc + 16 + l15, q)];
        acc[0][0] = __builtin_amdgcn_mfma_f32_16x16x32_bf16(a0, b0, acc[0][0], 0, 0, 0);
        acc[0][1] = __builtin_amdgcn_mfma_f32_16x16x32_bf16(a0, b1, acc[0][1], 0, 0, 0);
        acc[1][0] = __builtin_amdgcn_mfma_f32_16x16x32_bf16(a1, b0, acc[1][0], 0, 0, 0);
        acc[1][1] = __builtin_amdgcn_mfma_f32_16x16x32_bf16(a1, b1, acc[1][1], 0, 0, 0);
        __syncthreads();
    }
    const int cq = lane >> 4, cc = lane & 15;
#pragma unroll
    for (int i = 0; i < 2; i++)
#pragma unroll
        for (int j = 0; j < 2; j++) {
#pragma unroll
            for (int rg = 0; rg < 4; rg++)
                C[(long)(wr + i * 16 + cq * 4 + rg) * 16384 + wc + j * 16 + cc] = acc[i][j][rg];
        }
}

// ---- epilogue role: per warp, one (t,n); no barriers ----
__device__ __forceinline__ void epi_role(int rb,
    const float* Hall, const float* Lc, const int* actions,
    const float* critic_W, const float* critic_b, float* out, int t0)
{
    const int w = threadIdx.x >> 6, j = threadIdx.x & 63;
    const int m = rb * 8 + w;
    const int tl = m >> 8, n = m & 255;
    const int t = t0 + tl;
    long o = ((long)t * 256 + n) * 322;
    const float* h = Hall + (long)m * 256;
    float part = 0.f;
#pragma unroll
    for (int i = 0; i < 4; i++) {
        float hv = h[j + 64 * i];
        out[o + 2 + j + 64 * i] = hv;
        part += hv * critic_W[j + 64 * i];
    }
    for (int off = 32; off > 0; off >>= 1) part += __shfl_down(part, off);
    if (j == 0) {
        out[o]     = (float)actions[(long)t * 256 + n];
        out[o + 1] = part + critic_b[0];
    }
    float x = Lc[(long)m * 64 + j];
    float mx = x;
    for (int off = 32; off > 0; off >>= 1) mx = fmaxf(mx, __shfl_down(mx, off));
    mx = __shfl(mx, 0);
    float e = __expf(x - mx);
    float ssum = e;
    for (int off = 32; off > 0; off >>= 1) ssum += __shfl_down(ssum, off);
    ssum = __shfl(ssum, 0);
    out[o + 258 + j] = e / ssum;
}

// ---- build_x role ----
__device__ __forceinline__ void bx_role(int rb,
    const float* values, const float* Mbuf, const int* actions, const int* a0,
    float* Xd, int t0)
{
    const int tid = threadIdx.x;
    if (tid >= 320) return;
    for (int rr = 0; rr < 128; rr++) {
        int m = rb * 128 + rr;
        int tl = m >> 8, n = m & 255;
        int t = t0 + tl;
        float v;
        if (tid < 64) {
            v = values[((long)t * 256 + n) * 64 + tid];
        } else {
            int ap = (t == 0) ? a0[n] : actions[(long)(t - 1) * 256 + n];
            v = Mbuf[((long)n * 64 + ap) * 256 + (tid - 64)];
        }
        Xd[(long)m * 320 + tid] = v;
    }
}

__global__ __launch_bounds__(512, 2) void fused_k(
    const float* sc_gi, const unsigned short* sc_PK, const float* sc_hinit,
    float* sc_out, float* sc_hstate,
    int kgru_nblk, const float* kg_gi0, const float* kg_gi1,
    const unsigned short* kg_PK0, const unsigned short* kg_PK1, float* kg_out,
    GemmRole g0, GemmRole g1, GemmRole g2, GemmRole g3,
    int lg_nblk, const float* lg_Q, const float* lg_K, float* lg_L,
    int ep_nblk, const float* ep_Hall, const float* ep_L, int ep_t0,
    int bx_nblk, const float* values, const float* Mbuf,
    const int* actions, const int* a0, float* bx_dst, int bx_t0,
    const float* critic_W, const float* critic_b, float* out)
{
    __shared__ __align__(16) FusedLds L;
    int b = blockIdx.x;
    if (b < 16) {
        scan_role(&L, sc_gi, sc_PK, sc_hinit, sc_out, sc_hstate, b * 16, TCHUNK, 0, 0);
        return;
    }
    b -= 16;
    if (b < kgru_nblk) {
        int d = b >> 4, n0 = (b & 15) * 16;
        scan_role(&L, d ? kg_gi1 : kg_gi0, d ? kg_PK1 : kg_PK0, nullptr,
                  kg_out, nullptr, n0, 64, 1, d);
        return;
    }
    b -= kgru_nblk;
    if (b < g0.nblocks) { gemm_role_impl(L.g.As, L.g.Bs, g0, b); return; }
    b -= g0.nblocks;
    if (b < g1.nblocks) { gemm_role_impl(L.g.As, L.g.Bs, g1, b); return; }
    b -= g1.nblocks;
    if (b < g2.nblocks) { gemm_role_impl(L.g.As, L.g.Bs, g2, b); return; }
    b -= g2.nblocks;
    if (b < g3.nblocks) { gemm_role_impl(L.g.As, L.g.Bs, g3, b); return; }
    b -= g3.nblocks;
    if (b < lg_nblk) { logits_role_impl(L.l.As2, L.l.Bs2, b, lg_Q, lg_K, lg_L); return; }
    b -= lg_nblk;
    if (b < ep_nblk) { epi_role(b, ep_Hall, ep_L, actions, critic_W, critic_b, out, ep_t0); return; }
    b -= ep_nblk;
    if (b < bx_nblk) bx_role(b, values, Mbuf, actions, a0, bx_dst, bx_t0);
}

// ---- Tail kernel: roles only, SMALL LDS union (~16.4KB). ----
__global__ __launch_bounds__(512, 2) void tail_k(
    GemmRole g3,
    int lg_nblk, const float* lg_Q, const float* lg_K, float* lg_L,
    int ep_nblk, const float* ep_Hall, const float* ep_L, int ep_t0,
    const int* actions, const float* critic_W, const float* critic_b, float* out)
{
    __shared__ __align__(16) TailLds L;
    int b = blockIdx.x;
    if (b < g3.nblocks) { gemm_role_impl(L.g.As, L.g.Bs, g3, b); return; }
    b -= g3.nblocks;
    if (b < lg_nblk) { logits_role_impl(L.l.As2, L.l.Bs2, b, lg_Q, lg_K, lg_L); return; }
    b -= lg_nblk;
    if (b < ep_nblk) epi_role(b, ep_Hall, ep_L, actions, critic_W, critic_b, out, ep_t0);
}

// ---------------------------------------------------------------------------
// Epilogue kernel (final tail use)
// ---------------------------------------------------------------------------
__global__ __launch_bounds__(64) void epilogue_k(
    const float* __restrict__ Hallc, const float* __restrict__ Lc,
    const int* __restrict__ actions,
    const float* __restrict__ critic_W, const float* __restrict__ critic_b,
    float* __restrict__ out, int t0)
{
    int m = blockIdx.x;
    int tl = m >> 8, n = m & 255;
    int t = t0 + tl;
    int j = threadIdx.x;
    long o = ((long)t * 256 + n) * 322;
    const float* h = Hallc + (long)m * 256;
    float part = 0.f;
#pragma unroll
    for (int i = 0; i < 4; i++) {
        float hv = h[j + 64 * i];
        out[o + 2 + j + 64 * i] = hv;
        part += hv * critic_W[j + 64 * i];
    }
    for (int off = 32; off > 0; off >>= 1) part += __shfl_down(part, off);
    if (j == 0) {
        out[o]     = (float)actions[(long)t * 256 + n];
        out[o + 1] = part + critic_b[0];
    }
    float x = Lc[(long)m * 64 + j];
    float mx = x;
    for (int off = 32; off > 0; off >>= 1) mx = fmaxf(mx, __shfl_down(mx, off));
    mx = __shfl(mx, 0);
    float e = __expf(x - mx);
    float ssum = e;
    for (int off = 32; off > 0; off >>= 1) ssum += __shfl_down(ssum, off);
    ssum = __shfl(ssum, 0);
    out[o + 258 + j] = e / ssum;
}

// ---------------------------------------------------------------------------
extern "C" void kernel_launch(void* const* d_in, const int* in_sizes, int n_in,
                              void* d_out, int out_size, void* d_ws, size_t ws_size,
                              hipStream_t stream)
{
    const float* values   = (const float*)d_in[0];
    const float* mdp      = (const float*)d_in[1];
    const int*   actions  = (const int*)  d_in[2];
    const int*   a0       = (const int*)  d_in[3];
    const float* h0       = (const float*)d_in[4];
    const float* emb_W    = (const float*)d_in[5];
    const float* emb_b    = (const float*)d_in[6];
    const float* gfw_Wih  = (const float*)d_in[7];
    const float* gfw_Whh  = (const float*)d_in[8];
    const float* gfw_bih  = (const float*)d_in[9];
    const float* gfw_bhh  = (const float*)d_in[10];
    const float* gbw_Wih  = (const float*)d_in[11];
    const float* gbw_Whh  = (const float*)d_in[12];
    const float* gbw_bih  = (const float*)d_in[13];
    const float* gbw_bhh  = (const float*)d_in[14];
    const float* f0_W     = (const float*)d_in[15];
    const float* f0_b     = (const float*)d_in[16];
    const float* f1_W     = (const float*)d_in[17];
    const float* f1_b     = (const float*)d_in[18];
    const float* cell_Wih = (const float*)d_in[19];
    const float* cell_Whh = (const float*)d_in[20];
    const float* cell_bih = (const float*)d_in[21];
    const float* cell_bhh = (const float*)d_in[22];
    const float* critic_W = (const float*)d_in[23];
    const float* critic_b = (const float*)d_in[24];
    const float* qg_W     = (const float*)d_in[25];
    const float* qg_b     = (const float*)d_in[26];
    float* out = (float*)d_out;

    char* base = (char*)d_ws;
    size_t off = 0;
    auto alloc = [&](size_t nf) -> float* {
        float* p = (float*)(base + off);
        off += nf * sizeof(float);
        off = (off + 255) & ~(size_t)255;
        return p;
    };
    float* Mbuf   = alloc(16384ull * 256);
    float* Mseq   = alloc(16384ull * 256);   // aliased as Hallr[2] (dead after prologue)
    float* gfA    = alloc(16384ull * 768);
    float* gbA    = alloc(16384ull * 768);   // aliased as Qr[1] from fused(2) on
    float* Kbuf   = alloc(256ull * 64 * 512);
    float* PKf    = alloc(98304);
    float* PKb    = alloc(98304);
    float* PKc    = alloc(98304);
    float* hstate = alloc(256ull * 256);
    float* Xr[2]    = { alloc(16384ull * 320), alloc(16384ull * 320) };
    float* X0r[2]   = { alloc(16384ull * 256), alloc(16384ull * 256) };
    float* X1r[2]   = { alloc(16384ull * 256), alloc(16384ull * 256) };
    float* GIr[2]   = { alloc(16384ull * 768), alloc(16384ull * 768) };
    float* Hallr[4] = { alloc(16384ull * 256), alloc(16384ull * 256),
                        Mseq, alloc(16384ull * 256) };
    float* Qr[2]  = { alloc(16384ull * 512), gbA };  // gbA dead after fused(0) kgru
    float* Lr[2]  = { alloc(16384ull * 64), alloc(16384ull * 64) };
    float* bias_f = alloc(768);
    float* bias_b = alloc(768);
    float* bias_c = alloc(768);
    (void)ws_size; (void)in_sizes; (void)n_in; (void)out_size;

    dim3 blk(256);

    // ---- Phase 1: embeddings, gate-input GEMMs (serial, v7 schedule), packing ----
    gemm_f32<false, 0><<<dim3(4, 256, 1), blk, 0, stream>>>(
        mdp, 128, 0, emb_W, 256, 0, emb_b, Mbuf, 256, 0, 16384, 256, 128);
    seq_major<<<dim3(16384), blk, 0, stream>>>(Mbuf, Mseq);
    pack_w<<<dim3(96, 3, 1), blk, 0, stream>>>(
        gfw_Whh, gbw_Whh, cell_Whh,
        (unsigned short*)PKf, (unsigned short*)PKb, (unsigned short*)PKc);
    combine_bias<<<dim3(3), blk, 0, stream>>>(gfw_bih, gfw_bhh, gbw_bih, gbw_bhh,
                                              cell_bih, cell_bhh, bias_f, bias_b, bias_c);
    gemm_f32<false, 0><<<dim3(12, 256, 1), blk, 0, stream>>>(
        Mseq, 256, 0, gfw_Wih, 768, 0, bias_f, gfA, 768, 0, 16384, 768, 256);
    gemm_f32<false, 0><<<dim3(12, 256, 1), blk, 0, stream>>>(
        Mseq, 256, 0, gbw_Wih, 768, 0, bias_b, gbA, 768, 0, 16384, 768, 256);

    // ---- Pipeline priming (x-path for chunks 0..3 partial) ----
    build_x<<<dim3(16384), dim3(320), 0, stream>>>(values, Mbuf, actions, a0, Xr[0], 0);
    gemm_f32<false, 1><<<dim3(4, 256, 1), blk, 0, stream>>>(
        Xr[0], 320, 0, f0_W, 256, 0, f0_b, X0r[0], 256, 0, 16384, 256, 320);
    build_x<<<dim3(16384), dim3(320), 0, stream>>>(values, Mbuf, actions, a0, Xr[1], 64);
    gemm_f32<false, 1><<<dim3(4, 256, 1), blk, 0, stream>>>(
        Xr[1], 320, 0, f0_W, 256, 0, f0_b, X0r[1], 256, 0, 16384, 256, 320);
    gemm_f32<false, 1><<<dim3(4, 256, 1), blk, 0, stream>>>(
        X0r[0], 256, 0, f1_W, 256, 0, f1_b, X1r[0], 256, 0, 16384, 256, 256);
    build_x<<<dim3(16384), dim3(320), 0, stream>>>(values, Mbuf, actions, a0, Xr[0], 128);
    gemm_f32<false, 1><<<dim3(4, 256, 1), blk, 0, stream>>>(
        Xr[0], 320, 0, f0_W, 256, 0, f0_b, X0r[0], 256, 0, 16384, 256, 320);
    gemm_f32<false, 1><<<dim3(4, 256, 1), blk, 0, stream>>>(
        X0r[1], 256, 0, f1_W, 256, 0, f1_b, X1r[1], 256, 0, 16384, 256, 256);
    build_x<<<dim3(16384), dim3(320), 0, stream>>>(values, Mbuf, actions, a0, Xr[1], 192);
    gemm_f32<false, 0><<<dim3(12, 256, 1), blk, 0, stream>>>(
        X1r[0], 256, 0, cell_Wih, 768, 0, bias_c, GIr[0], 768, 0, 16384, 768, 256);

    // ---- Fused pipeline (v7 schedule, 128x128 role tiles):
    //   fused(c) = scan(c) | kgru(c==0) | f0(c+3) | f1(c+2) | GI(c+1)
    //            | qg(c-1) | logits(c-2) | epi(c-3) | bx(c+4)
    for (int c = 0; c < NCHUNK; c++) {
        GemmRole g0{}, g1{}, g2{}, g3{};
        if (c <= 4) g0 = GemmRole{ Xr[(c + 1) & 1], f0_W, f0_b, X0r[(c + 1) & 1],
                                   320, 320, 256, 256, 1, 256, 2 };
        if (c <= 5) g1 = GemmRole{ X0r[c & 1], f1_W, f1_b, X1r[c & 1],
                                   256, 256, 256, 256, 1, 256, 2 };
        if (c <= 6) g2 = GemmRole{ X1r[(c + 1) & 1], cell_Wih, bias_c, GIr[(c + 1) & 1],
                                   256, 256, 768, 768, 0, 768, 6 };
        if (c >= 1) g3 = GemmRole{ Hallr[(c - 1) & 3], qg_W, qg_b, Qr[(c - 1) & 1],
                                   256, 256, 512, 512, 0, 512, 4 };
        int kgn = (c == 0) ? 32 : 0;
        int lgn = (c >= 2) ? 128 : 0;
        int epn = (c >= 3) ? 2048 : 0;
        int bxn = (c <= 3) ? 128 : 0;
        int total = 16 + kgn + g0.nblocks + g1.nblocks + g2.nblocks + g3.nblocks
                    + lgn + epn + bxn;

        fused_k<<<dim3(total), dim3(512), 0, stream>>>(
            GIr[c & 1], (const unsigned short*)PKc, (c == 0) ? h0 : (const float*)hstate,
            Hallr[c & 3], hstate,
            kgn, gfA, gbA, (const unsigned short*)PKf, (const unsigned short*)PKb, Kbuf,
            g0, g1, g2, g3,
            lgn, Qr[(c - 2) & 1], Kbuf, Lr[(c - 2) & 1],
            epn, Hallr[(c - 3) & 3], Lr[(c - 3) & 1], (c - 3) * 64,
            bxn, values, Mbuf, actions, a0, Xr[c & 1], (c + 4) * 64,
            critic_W, critic_b, out);
    }

    // ---- Tail drain (small-LDS tail_k): T1 = qg(7) | logits(6) | epi(5) ----
    {
        GemmRole g3t = GemmRole{ Hallr[3], qg_W, qg_b, Qr[1],
                                 256, 256, 512, 512, 0, 512, 4 };
        tail_k<<<dim3(512 + 128 + 2048), dim3(512), 0, stream>>>(
            g3t, 128, Qr[0], Kbuf, Lr[0],
            2048, Hallr[1], Lr[1], 5 * 64,
            actions, critic_W, critic_b, out);
    }
    // ---- T2 = logits(7) | epi(6) ----
    {
        GemmRole gz{};
        tail_k<<<dim3(128 + 2048), dim3(512), 0, stream>>>(
            gz, 128, Qr[1], Kbuf, Lr[1],
            2048, Hallr[2], Lr[0], 6 * 64,
            actions, critic_W, critic_b, out);
    }
    // ---- T3 = epi(7) ----
    epilogue_k<<<dim3(16384), dim3(64), 0, stream>>>(
        Hallr[3], Lr[1], actions, critic_W, critic_b, out, 7 * 64);
}

// Round 18
// 1900.317 us; speedup vs baseline: 3.1316x; 1.0084x over previous
//
#include <hip/hip_runtime.h>

// Problem constants (reference: T=512, N=256, H=256, HR=64, WC=128, V=64)
#define TSTEPS 512
#define NBATCH 256
#define HID    256
#define TCHUNK 64
#define NCHUNK 8

typedef __attribute__((ext_vector_type(8))) short bf16x8;
typedef __attribute__((ext_vector_type(4))) float f32x4;

__device__ __forceinline__ unsigned short f2b(float x) {
    union { float f; unsigned int u; } c; c.f = x;
    unsigned int u = c.u;
    return (unsigned short)((u + 0x7fffu + ((u >> 16) & 1u)) >> 16);
}

__device__ __forceinline__ void gload_lds16(const float* g, float* l) {
    __builtin_amdgcn_global_load_lds(
        (const __attribute__((address_space(1))) unsigned int*)g,
        (__attribute__((address_space(3))) unsigned int*)l,
        16, 0, 0);
}

// LDS bank-conflict mitigation for [row][32]-short GEMM tiles (v7, kept).
__device__ __forceinline__ int swzi(int row, int g) {
    return ((g ^ ((row >> 3) & 3)) << 3);
}

// ---------------------------------------------------------------------------
// Generic GEMM (256 thr): C = act(A@B + bias). Prologue use. Swizzled LDS.
// ---------------------------------------------------------------------------
template<bool TRANS_B, int ACT>
__global__ __launch_bounds__(256) void gemm_f32(
    const float* __restrict__ A, long lda, long sA,
    const float* __restrict__ B, long ldb, long sB,
    const float* __restrict__ bias,
    float* __restrict__ C, long ldc, long sC,
    int M, int N, int K)
{
    __shared__ __align__(16) unsigned short As[64][32];
    __shared__ __align__(16) unsigned short Bs[64][32];
    const int z = blockIdx.z;
    A += (long)z * sA; B += (long)z * sB; C += (long)z * sC;
    const int n0 = blockIdx.x * 64, m0 = blockIdx.y * 64;
    const int tid  = threadIdx.x;
    const int lane = tid & 63, w = tid >> 6;
    const int wr = (w >> 1) * 32, wc = (w & 1) * 32;

    f32x4 acc[2][2];
#pragma unroll
    for (int i = 0; i < 2; i++)
#pragma unroll
        for (int j = 0; j < 2; j++) acc[i][j] = (f32x4){0.f, 0.f, 0.f, 0.f};

    for (int k0 = 0; k0 < K; k0 += 32) {
        {
            const int r = tid >> 2, ck = (tid & 3) << 3;
            const float* s = A + (long)(m0 + r) * lda + k0 + ck;
            float4 v0 = *(const float4*)s, v1 = *(const float4*)(s + 4);
            unsigned short* d = &As[r][swzi(r, ck >> 3)];
            d[0] = f2b(v0.x); d[1] = f2b(v0.y); d[2] = f2b(v0.z); d[3] = f2b(v0.w);
            d[4] = f2b(v1.x); d[5] = f2b(v1.y); d[6] = f2b(v1.z); d[7] = f2b(v1.w);
        }
        if (TRANS_B) {
            const int r = tid >> 2, ck = (tid & 3) << 3;
            const float* s = B + (long)(n0 + r) * ldb + k0 + ck;
            float4 v0 = *(const float4*)s, v1 = *(const float4*)(s + 4);
            unsigned short* d = &Bs[r][swzi(r, ck >> 3)];
            d[0] = f2b(v0.x); d[1] = f2b(v0.y); d[2] = f2b(v0.z); d[3] = f2b(v0.w);
            d[4] = f2b(v1.x); d[5] = f2b(v1.y); d[6] = f2b(v1.z); d[7] = f2b(v1.w);
        } else {
            const int kk = tid >> 3, cn = (tid & 7) << 3;
            const float* s = B + (long)(k0 + kk) * ldb + n0 + cn;
            float4 v0 = *(const float4*)s, v1 = *(const float4*)(s + 4);
            const int sc = swzi(cn, kk >> 3) + (kk & 7);
            Bs[cn + 0][sc] = f2b(v0.x); Bs[cn + 1][sc] = f2b(v0.y);
            Bs[cn + 2][sc] = f2b(v0.z); Bs[cn + 3][sc] = f2b(v0.w);
            Bs[cn + 4][sc] = f2b(v1.x); Bs[cn + 5][sc] = f2b(v1.y);
            Bs[cn + 6][sc] = f2b(v1.z); Bs[cn + 7][sc] = f2b(v1.w);
        }
        __syncthreads();
        const int l15 = lane & 15, q = lane >> 4;
        bf16x8 a0 = *(const bf16x8*)&As[wr +      l15][swzi(wr +      l15, q)];
        bf16x8 a1 = *(const bf16x8*)&As[wr + 16 + l15][swzi(wr + 16 + l15, q)];
        bf16x8 b0 = *(const bf16x8*)&Bs[wc +      l15][swzi(wc +      l15, q)];
        bf16x8 b1 = *(const bf16x8*)&Bs[wc + 16 + l15][swzi(wc + 16 + l15, q)];
        acc[0][0] = __builtin_amdgcn_mfma_f32_16x16x32_bf16(a0, b0, acc[0][0], 0, 0, 0);
        acc[0][1] = __builtin_amdgcn_mfma_f32_16x16x32_bf16(a0, b1, acc[0][1], 0, 0, 0);
        acc[1][0] = __builtin_amdgcn_mfma_f32_16x16x32_bf16(a1, b0, acc[1][0], 0, 0, 0);
        acc[1][1] = __builtin_amdgcn_mfma_f32_16x16x32_bf16(a1, b1, acc[1][1], 0, 0, 0);
        __syncthreads();
    }
    const int cq = lane >> 4, cc = lane & 15;
#pragma unroll
    for (int i = 0; i < 2; i++)
#pragma unroll
        for (int j = 0; j < 2; j++) {
#pragma unroll
            for (int rg = 0; rg < 4; rg++) {
                int row = m0 + wr + i * 16 + cq * 4 + rg;
                int col = n0 + wc + j * 16 + cc;
                float v = acc[i][j][rg];
                if (bias) v += bias[col];
                if (ACT == 1) v = v > 0.f ? v : 0.f;
                C[(long)row * ldc + col] = v;
            }
        }
}

// ---------------------------------------------------------------------------
// Helpers
// ---------------------------------------------------------------------------
__global__ void combine_bias(const float* a0, const float* b0,
                             const float* a1, const float* b1,
                             const float* a2, const float* b2,
                             float* o0, float* o1, float* o2)
{
    int i = blockIdx.x * 256 + threadIdx.x;
    o0[i] = a0[i] + b0[i];
    o1[i] = a1[i] + b1[i];
    o2[i] = a2[i] + b2[i];
}

__global__ void seq_major(const float* __restrict__ M, float* __restrict__ Mseq)
{
    int b = blockIdx.x;
    int s = b >> 8, n = b & 255;
    int t = threadIdx.x;
    Mseq[(long)b * 256 + t] = M[((long)n * 64 + s) * 256 + t];
}

// ---------------------------------------------------------------------------
// pack_w: 8-wave scan fragment layout (v3/v7, proven).
// ---------------------------------------------------------------------------
__global__ __launch_bounds__(256) void pack_w(
    const float* __restrict__ Wf, const float* __restrict__ Wb, const float* __restrict__ Wc,
    unsigned short* __restrict__ Pf, unsigned short* __restrict__ Pb, unsigned short* __restrict__ Pc)
{
    int chunk = blockIdx.x * 256 + threadIdx.x;      // 0..24575
    const float* W = (blockIdx.y == 0) ? Wf : ((blockIdx.y == 1) ? Wb : Wc);
    unsigned short* P = (blockIdx.y == 0) ? Pf : ((blockIdx.y == 1) ? Pb : Pc);
    int lane = chunk & 63;
    int kt   = (chunk >> 6) & 7;
    int f    = (chunk >> 9) % 6;
    int w    = chunk / 3072;
    int g = f >> 1, hh = f & 1;
    int c = lane & 15, q = lane >> 4;
    int col = g * 256 + w * 32 + hh * 16 + c;
    int k0  = kt * 32 + q * 8;
    unsigned int v[8];
#pragma unroll
    for (int j = 0; j < 8; j++) v[j] = f2b(W[(long)(k0 + j) * 768 + col]);
    uint4 o;
    o.x = v[0] | (v[1] << 16); o.y = v[2] | (v[3] << 16);
    o.z = v[4] | (v[5] << 16); o.w = v[6] | (v[7] << 16);
    *(uint4*)&P[(long)chunk * 8] = o;
}

__global__ void build_x(const float* __restrict__ values, const float* __restrict__ Mbuf,
                        const int* __restrict__ actions, const int* __restrict__ a0,
                        float* __restrict__ Xc, int t0)
{
    int m = blockIdx.x;
    int tl = m >> 8, n = m & 255;
    int t = t0 + tl;
    int c = threadIdx.x;
    float v;
    if (c < 64) {
        v = values[((long)t * 256 + n) * 64 + c];
    } else {
        int ap = (t == 0) ? a0[n] : actions[(long)(t - 1) * 256 + n];
        v = Mbuf[((long)n * 64 + ap) * 256 + (c - 64)];
    }
    Xc[(long)m * 320 + c] = v;
}

// ---------------------------------------------------------------------------
// Fused kernel v16 = v15 + gate GEMMs as fused(0) roles (kgru -> fused(1)).
// ---------------------------------------------------------------------------
struct GemmRole {
    const float* A; const float* B; const float* bias; float* C;
    int K; long lda; long ldb; long ldc; int act; int nblocks; int ntn;
};

union FusedLds {
    struct { unsigned short hbuf[2][16][264]; float gibuf[2][16 * 772]; } s;
    struct { unsigned short As[128][32]; unsigned short Bs[128][32]; } g;
    struct { unsigned short As2[2][64][32]; unsigned short Bs2[2][64][32]; } l;
};
// Tail union: roles only (~16.4KB).
union TailLds {
    struct { unsigned short As[128][32]; unsigned short Bs[128][32]; } g;
    struct { unsigned short As2[2][64][32]; unsigned short Bs2[2][64][32]; } l;
};

// ---- scan role: EXACT v3/v7 structure (8 waves, split-hh, fences, vmcnt(8)) ----
__device__ __forceinline__ void scan_role(FusedLds* L,
    const float* gi, const unsigned short* PK, const float* h_init,
    float* outp, float* h_state, int n0, int steps, int kgru, int d)
{
    auto& hbuf  = L->s.hbuf;
    auto& gibuf = L->s.gibuf;
    const int tid = threadIdx.x;
    const int w = tid >> 6, lane = tid & 63;
    const int q = lane >> 4, c = lane & 15, q8 = q << 3;
    const int wcol = w * 32;

    bf16x8 Bf[6][8];
#pragma unroll
    for (int f = 0; f < 6; f++)
#pragma unroll
        for (int kt = 0; kt < 8; kt++)
            Bf[f][kt] = *(const bf16x8*)&PK[(((long)(w * 6 + f) * 8 + kt) * 64 + lane) * 8];

    f32x4 hreg[2];
#pragma unroll
    for (int hh = 0; hh < 2; hh++)
#pragma unroll
        for (int rg = 0; rg < 4; rg++) {
            float v = 0.f;
            if (!kgru) v = h_init[(long)(n0 + q * 4 + rg) * 256 + wcol + hh * 16 + c];
            hreg[hh][rg] = v;
            hbuf[1][q * 4 + rg][wcol + hh * 16 + c] = f2b(v);
        }

    const int row0 = kgru ? (d ? 63 : 0) : 0;
    const long gstride = (kgru && d) ? -196608L : 196608L;
    const float* gsrc = gi + ((long)row0 * 256 + n0) * 768;
    float* optr[4];
    long ostride;
    if (kgru) {
        ostride = d ? -512L : 512L;
#pragma unroll
        for (int rg = 0; rg < 4; rg++)
            optr[rg] = outp + ((long)(n0 + q * 4 + rg) * 64 + row0) * 512 + d * 256 + wcol + c;
    } else {
        ostride = 65536L;
#pragma unroll
        for (int rg = 0; rg < 4; rg++)
            optr[rg] = outp + (long)(n0 + q * 4 + rg) * 256 + wcol + c;
    }

#pragma unroll
    for (int i = 0; i < 6; i++) {
        int idx = w * 6 + i;
        int r = idx / 3, ch = idx % 3;
        gload_lds16(gsrc + (long)r * 768 + ch * 256 + lane * 4,
                    &gibuf[0][r * 772 + ch * 256]);
    }
    __syncthreads();

    for (int s = 0; s < steps; s++) {
        const int cur = s & 1;
        if (s + 1 < steps) {
            const float* src = gsrc + gstride;
#pragma unroll
            for (int i = 0; i < 6; i++) {
                int idx = w * 6 + i;
                int r = idx / 3, ch = idx % 3;
                gload_lds16(src + (long)r * 768 + ch * 256 + lane * 4,
                            &gibuf[cur ^ 1][r * 772 + ch * 256]);
            }
        }
        gsrc += gstride;
        asm volatile("" ::: "memory");

        const unsigned short* hrd = &hbuf[cur ^ 1][0][0];
        const float* gp = &gibuf[cur][(q * 4) * 772 + wcol + c];
        unsigned short* hwr = &hbuf[cur][q * 4][wcol + c];

#pragma unroll
        for (int hh = 0; hh < 2; hh++) {
            f32x4 ar = (f32x4){0.f, 0.f, 0.f, 0.f};
            f32x4 az = (f32x4){0.f, 0.f, 0.f, 0.f};
            f32x4 an = (f32x4){0.f, 0.f, 0.f, 0.f};
#pragma unroll
            for (int kt = 0; kt < 8; kt++) {
                bf16x8 a = *(const bf16x8*)&hrd[c * 264 + kt * 32 + q8];
                ar = __builtin_amdgcn_mfma_f32_16x16x32_bf16(a, Bf[0 + hh][kt], ar, 0, 0, 0);
                az = __builtin_amdgcn_mfma_f32_16x16x32_bf16(a, Bf[2 + hh][kt], az, 0, 0, 0);
                an = __builtin_amdgcn_mfma_f32_16x16x32_bf16(a, Bf[4 + hh][kt], an, 0, 0, 0);
            }
#pragma unroll
            for (int rg = 0; rg < 4; rg++) {
                float gr = gp[rg * 772 +       hh * 16];
                float gz = gp[rg * 772 + 256 + hh * 16];
                float gn = gp[rg * 772 + 512 + hh * 16];
                float r  = __builtin_amdgcn_rcpf(1.f + __expf(-(gr + ar[rg])));
                float zg = __builtin_amdgcn_rcpf(1.f + __expf(-(gz + az[rg])));
                float nn = 1.f - 2.f * __builtin_amdgcn_rcpf(1.f + __expf(2.f * (gn + r * an[rg])));
                float hv = (1.f - zg) * nn + zg * hreg[hh][rg];
                hreg[hh][rg] = hv;
                hwr[rg * 264 + hh * 16] = f2b(hv);
                optr[rg][hh * 16] = hv;
            }
            asm volatile("" ::: "memory");
        }

#pragma unroll
        for (int rg = 0; rg < 4; rg++) optr[rg] += ostride;

        asm volatile("s_waitcnt vmcnt(8) lgkmcnt(0)" ::: "memory");
        __builtin_amdgcn_sched_barrier(0);
        __builtin_amdgcn_s_barrier();
        __builtin_amdgcn_sched_barrier(0);
    }

    if (!kgru) {
#pragma unroll
        for (int hh = 0; hh < 2; hh++)
#pragma unroll
            for (int rg = 0; rg < 4; rg++)
                h_state[(long)(n0 + q * 4 + rg) * 256 + wcol + hh * 16 + c] = hreg[hh][rg];
    }
}

// ---- gemm role: 512-thread 128x128 tile, B stored (K,N), swizzled LDS.
// Each wave computes its 32x32 quadrant at rows wr and wr+64. ----
__device__ __forceinline__ void gemm_role_impl(
    unsigned short (*As)[32], unsigned short (*Bs)[32], const GemmRole& R, int rb)
{
    const int tid = threadIdx.x;
    const int lane = tid & 63, w = tid >> 6;
    const int mt = rb / R.ntn, nt = rb % R.ntn;
    const long m0 = (long)mt * 128, n0 = (long)nt * 128;
    const int wr = (w >> 2) * 32, wc = (w & 3) * 32;

    f32x4 acc[2][2][2];   // [mhalf][i][j]
#pragma unroll
    for (int h = 0; h < 2; h++)
#pragma unroll
        for (int i = 0; i < 2; i++)
#pragma unroll
            for (int j = 0; j < 2; j++) acc[h][i][j] = (f32x4){0.f, 0.f, 0.f, 0.f};

    for (int k0 = 0; k0 < R.K; k0 += 32) {
        {   // A: 128 x 32, 512 thr x 8 floats
            const int r = tid >> 2, ck = (tid & 3) << 3;
            const float* s = R.A + (m0 + r) * R.lda + k0 + ck;
            float4 v0 = *(const float4*)s, v1 = *(const float4*)(s + 4);
            unsigned short* d = &As[r][swzi(r, ck >> 3)];
            d[0] = f2b(v0.x); d[1] = f2b(v0.y); d[2] = f2b(v0.z); d[3] = f2b(v0.w);
            d[4] = f2b(v1.x); d[5] = f2b(v1.y); d[6] = f2b(v1.z); d[7] = f2b(v1.w);
        }
        {   // B: 32 x 128 scatter-transpose
            const int kk = tid >> 4, cn = (tid & 15) << 3;
            const float* s = R.B + (long)(k0 + kk) * R.ldb + n0 + cn;
            float4 v0 = *(const float4*)s, v1 = *(const float4*)(s + 4);
            const int sc = swzi(cn, kk >> 3) + (kk & 7);
            Bs[cn + 0][sc] = f2b(v0.x); Bs[cn + 1][sc] = f2b(v0.y);
            Bs[cn + 2][sc] = f2b(v0.z); Bs[cn + 3][sc] = f2b(v0.w);
            Bs[cn + 4][sc] = f2b(v1.x); Bs[cn + 5][sc] = f2b(v1.y);
            Bs[cn + 6][sc] = f2b(v1.z); Bs[cn + 7][sc] = f2b(v1.w);
        }
        __syncthreads();
        const int l15 = lane & 15, q = lane >> 4;
        bf16x8 b0 = *(const bf16x8*)&Bs[wc +      l15][swzi(wc +      l15, q)];
        bf16x8 b1 = *(const bf16x8*)&Bs[wc + 16 + l15][swzi(wc + 16 + l15, q)];
#pragma unroll
        for (int h = 0; h < 2; h++) {
            const int rb0 = wr + h * 64;
            bf16x8 a0 = *(const bf16x8*)&As[rb0 +      l15][swzi(rb0 +      l15, q)];
            bf16x8 a1 = *(const bf16x8*)&As[rb0 + 16 + l15][swzi(rb0 + 16 + l15, q)];
            acc[h][0][0] = __builtin_amdgcn_mfma_f32_16x16x32_bf16(a0, b0, acc[h][0][0], 0, 0, 0);
            acc[h][0][1] = __builtin_amdgcn_mfma_f32_16x16x32_bf16(a0, b1, acc[h][0][1], 0, 0, 0);
            acc[h][1][0] = __builtin_amdgcn_mfma_f32_16x16x32_bf16(a1, b0, acc[h][1][0], 0, 0, 0);
            acc[h][1][1] = __builtin_amdgcn_mfma_f32_16x16x32_bf16(a1, b1, acc[h][1][1], 0, 0, 0);
        }
        __syncthreads();
    }
    const int cq = lane >> 4, cc = lane & 15;
#pragma unroll
    for (int h = 0; h < 2; h++)
#pragma unroll
        for (int i = 0; i < 2; i++)
#pragma unroll
            for (int j = 0; j < 2; j++) {
#pragma unroll
                for (int rg = 0; rg < 4; rg++) {
                    long row = m0 + wr + h * 64 + i * 16 + cq * 4 + rg;
                    long col = n0 + wc + j * 16 + cc;
                    float v = acc[h][i][j][rg];
                    if (R.bias) v += R.bias[col];
                    if (R.act == 1) v = v > 0.f ? v : 0.f;
                    R.C[row * R.ldc + col] = v;
                }
            }
}

// ---- logits role: dual-z 64x64x512 GEMM (both halves barrier-identical) ----
__device__ __forceinline__ void logits_role_impl(
    unsigned short (*As)[64][32], unsigned short (*Bs)[64][32], int rb,
    const float* Qs, const float* Kb, float* Lout)
{
    const int tid = threadIdx.x;
    const int half = tid >> 8, htid = tid & 255;
    const int z = rb * 2 + half;
    const float* A = Qs + (long)z * 512;
    const float* B = Kb + (long)z * 32768;
    float* C = Lout + (long)z * 64;
    const int lane = htid & 63, w4 = htid >> 6;
    const int wr = (w4 >> 1) * 32, wc = (w4 & 1) * 32;

    f32x4 acc[2][2];
#pragma unroll
    for (int i = 0; i < 2; i++)
#pragma unroll
        for (int j = 0; j < 2; j++) acc[i][j] = (f32x4){0.f, 0.f, 0.f, 0.f};

    for (int k0 = 0; k0 < 512; k0 += 32) {
        const int r = htid >> 2, ck = (htid & 3) << 3;
        {
            const float* s = A + (long)r * 131072 + k0 + ck;
            float4 v0 = *(const float4*)s, v1 = *(const float4*)(s + 4);
            unsigned short* d = &As[half][r][swzi(r, ck >> 3)];
            d[0] = f2b(v0.x); d[1] = f2b(v0.y); d[2] = f2b(v0.z); d[3] = f2b(v0.w);
            d[4] = f2b(v1.x); d[5] = f2b(v1.y); d[6] = f2b(v1.z); d[7] = f2b(v1.w);
        }
        {
            const float* s = B + (long)r * 512 + k0 + ck;
            float4 v0 = *(const float4*)s, v1 = *(const float4*)(s + 4);
            unsigned short* d = &Bs[half][r][swzi(r, ck >> 3)];
            d[0] = f2b(v0.x); d[1] = f2b(v0.y); d[2] = f2b(v0.z); d[3] = f2b(v0.w);
            d[4] = f2b(v1.x); d[5] = f2b(v1.y); d[6] = f2b(v1.z); d[7] = f2b(v1.w);
        }
        __syncthreads();
        const int l15 = lane & 15, q = lane >> 4;
        bf16x8 a0 = *(const bf16x8*)&As[half][wr +      l15][swzi(wr +      l15, q)];
        bf16x8 a1 = *(const bf16x8*)&As[half][wr + 16 + l15][swzi(wr + 16 + l15, q)];
        bf16x8 b0 = *(const bf16x8*)&Bs[half][wc +      l15][swzi(wc +      l15, q)];
        bf16x8 b1 = *(const bf16x8*)&Bs[half][wc + 16 + l15][swzi(wc + 16 + l15, q)];
        acc[0][0] = __builtin_amdgcn_mfma_f32_16x16x32_bf16(a0, b0, acc[0][0], 0, 0, 0);
        acc[0][1] = __builtin_amdgcn_mfma_f32_16x16x32_bf16(a0, b1, acc[0][1], 0, 0, 0);
        acc[1][0] = __builtin_amdgcn_mfma_f32_16x16x32_bf16(a1, b0, acc[1][0], 0, 0, 0);
        acc[1][1] = __builtin_amdgcn_mfma_f32_16x16x32_bf16(a1, b1, acc[1][1], 0, 0, 0);
        __syncthreads();
    }
    const int cq = lane >> 4, cc = lane & 15;
#pragma unroll
    for (int i = 0; i < 2; i++)
#pragma unroll
        for (int j = 0; j < 2; j++) {
#pragma unroll
            for (int rg = 0; rg < 4; rg++)
                C[(long)(wr + i * 16 + cq * 4 + rg) * 16384 + wc + j * 16 + cc] = acc[i][j][rg];
        }
}

// ---- epilogue role: per warp, one (t,n); no barriers ----
__device__ __forceinline__ void epi_role(int rb,
    const float* Hall, const float* Lc, const int* actions,
    const float* critic_W, const float* critic_b, float* out, int t0)
{
    const int w = threadIdx.x >> 6, j = threadIdx.x & 63;
    const int m = rb * 8 + w;
    const int tl = m >> 8, n = m & 255;
    const int t = t0 + tl;
    long o = ((long)t * 256 + n) * 322;
    const float* h = Hall + (long)m * 256;
    float part = 0.f;
#pragma unroll
    for (int i = 0; i < 4; i++) {
        float hv = h[j + 64 * i];
        out[o + 2 + j + 64 * i] = hv;
        part += hv * critic_W[j + 64 * i];
    }
    for (int off = 32; off > 0; off >>= 1) part += __shfl_down(part, off);
    if (j == 0) {
        out[o]     = (float)actions[(long)t * 256 + n];
        out[o + 1] = part + critic_b[0];
    }
    float x = Lc[(long)m * 64 + j];
    float mx = x;
    for (int off = 32; off > 0; off >>= 1) mx = fmaxf(mx, __shfl_down(mx, off));
    mx = __shfl(mx, 0);
    float e = __expf(x - mx);
    float ssum = e;
    for (int off = 32; off > 0; off >>= 1) ssum += __shfl_down(ssum, off);
    ssum = __shfl(ssum, 0);
    out[o + 258 + j] = e / ssum;
}

// ---- build_x role ----
__device__ __forceinline__ void bx_role(int rb,
    const float* values, const float* Mbuf, const int* actions, const int* a0,
    float* Xd, int t0)
{
    const int tid = threadIdx.x;
    if (tid >= 320) return;
    for (int rr = 0; rr < 128; rr++) {
        int m = rb * 128 + rr;
        int tl = m >> 8, n = m & 255;
        int t = t0 + tl;
        float v;
        if (tid < 64) {
            v = values[((long)t * 256 + n) * 64 + tid];
        } else {
            int ap = (t == 0) ? a0[n] : actions[(long)(t - 1) * 256 + n];
            v = Mbuf[((long)n * 64 + ap) * 256 + (tid - 64)];
        }
        Xd[(long)m * 320 + tid] = v;
    }
}

__global__ __launch_bounds__(512, 2) void fused_k(
    const float* sc_gi, const unsigned short* sc_PK, const float* sc_hinit,
    float* sc_out, float* sc_hstate,
    int kgru_nblk, const float* kg_gi0, const float* kg_gi1,
    const unsigned short* kg_PK0, const unsigned short* kg_PK1, float* kg_out,
    GemmRole g0, GemmRole g1, GemmRole g2, GemmRole g3, GemmRole g4, GemmRole g5,
    int lg_nblk, const float* lg_Q, const float* lg_K, float* lg_L,
    int ep_nblk, const float* ep_Hall, const float* ep_L, int ep_t0,
    int bx_nblk, const float* values, const float* Mbuf,
    const int* actions, const int* a0, float* bx_dst, int bx_t0,
    const float* critic_W, const float* critic_b, float* out)
{
    __shared__ __align__(16) FusedLds L;
    int b = blockIdx.x;
    if (b < 16) {
        scan_role(&L, sc_gi, sc_PK, sc_hinit, sc_out, sc_hstate, b * 16, TCHUNK, 0, 0);
        return;
    }
    b -= 16;
    if (b < kgru_nblk) {
        int d = b >> 4, n0 = (b & 15) * 16;
        scan_role(&L, d ? kg_gi1 : kg_gi0, d ? kg_PK1 : kg_PK0, nullptr,
                  kg_out, nullptr, n0, 64, 1, d);
        return;
    }
    b -= kgru_nblk;
    if (b < g0.nblocks) { gemm_role_impl(L.g.As, L.g.Bs, g0, b); return; }
    b -= g0.nblocks;
    if (b < g1.nblocks) { gemm_role_impl(L.g.As, L.g.Bs, g1, b); return; }
    b -= g1.nblocks;
    if (b < g2.nblocks) { gemm_role_impl(L.g.As, L.g.Bs, g2, b); return; }
    b -= g2.nblocks;
    if (b < g3.nblocks) { gemm_role_impl(L.g.As, L.g.Bs, g3, b); return; }
    b -= g3.nblocks;
    if (b < g4.nblocks) { gemm_role_impl(L.g.As, L.g.Bs, g4, b); return; }
    b -= g4.nblocks;
    if (b < g5.nblocks) { gemm_role_impl(L.g.As, L.g.Bs, g5, b); return; }
    b -= g5.nblocks;
    if (b < lg_nblk) { logits_role_impl(L.l.As2, L.l.Bs2, b, lg_Q, lg_K, lg_L); return; }
    b -= lg_nblk;
    if (b < ep_nblk) { epi_role(b, ep_Hall, ep_L, actions, critic_W, critic_b, out, ep_t0); return; }
    b -= ep_nblk;
    if (b < bx_nblk) bx_role(b, values, Mbuf, actions, a0, bx_dst, bx_t0);
}

// ---- Tail kernel: roles only, SMALL LDS union (~16.4KB). ----
__global__ __launch_bounds__(512, 2) void tail_k(
    GemmRole g3,
    int lg_nblk, const float* lg_Q, const float* lg_K, float* lg_L,
    int ep_nblk, const float* ep_Hall, const float* ep_L, int ep_t0,
    const int* actions, const float* critic_W, const float* critic_b, float* out)
{
    __shared__ __align__(16) TailLds L;
    int b = blockIdx.x;
    if (b < g3.nblocks) { gemm_role_impl(L.g.As, L.g.Bs, g3, b); return; }
    b -= g3.nblocks;
    if (b < lg_nblk) { logits_role_impl(L.l.As2, L.l.Bs2, b, lg_Q, lg_K, lg_L); return; }
    b -= lg_nblk;
    if (b < ep_nblk) epi_role(b, ep_Hall, ep_L, actions, critic_W, critic_b, out, ep_t0);
}

// ---------------------------------------------------------------------------
// Epilogue kernel (final tail use)
// ---------------------------------------------------------------------------
__global__ __launch_bounds__(64) void epilogue_k(
    const float* __restrict__ Hallc, const float* __restrict__ Lc,
    const int* __restrict__ actions,
    const float* __restrict__ critic_W, const float* __restrict__ critic_b,
    float* __restrict__ out, int t0)
{
    int m = blockIdx.x;
    int tl = m >> 8, n = m & 255;
    int t = t0 + tl;
    int j = threadIdx.x;
    long o = ((long)t * 256 + n) * 322;
    const float* h = Hallc + (long)m * 256;
    float part = 0.f;
#pragma unroll
    for (int i = 0; i < 4; i++) {
        float hv = h[j + 64 * i];
        out[o + 2 + j + 64 * i] = hv;
        part += hv * critic_W[j + 64 * i];
    }
    for (int off = 32; off > 0; off >>= 1) part += __shfl_down(part, off);
    if (j == 0) {
        out[o]     = (float)actions[(long)t * 256 + n];
        out[o + 1] = part + critic_b[0];
    }
    float x = Lc[(long)m * 64 + j];
    float mx = x;
    for (int off = 32; off > 0; off >>= 1) mx = fmaxf(mx, __shfl_down(mx, off));
    mx = __shfl(mx, 0);
    float e = __expf(x - mx);
    float ssum = e;
    for (int off = 32; off > 0; off >>= 1) ssum += __shfl_down(ssum, off);
    ssum = __shfl(ssum, 0);
    out[o + 258 + j] = e / ssum;
}

// ---------------------------------------------------------------------------
extern "C" void kernel_launch(void* const* d_in, const int* in_sizes, int n_in,
                              void* d_out, int out_size, void* d_ws, size_t ws_size,
                              hipStream_t stream)
{
    const float* values   = (const float*)d_in[0];
    const float* mdp      = (const float*)d_in[1];
    const int*   actions  = (const int*)  d_in[2];
    const int*   a0       = (const int*)  d_in[3];
    const float* h0       = (const float*)d_in[4];
    const float* emb_W    = (const float*)d_in[5];
    const float* emb_b    = (const float*)d_in[6];
    const float* gfw_Wih  = (const float*)d_in[7];
    const float* gfw_Whh  = (const float*)d_in[8];
    const float* gfw_bih  = (const float*)d_in[9];
    const float* gfw_bhh  = (const float*)d_in[10];
    const float* gbw_Wih  = (const float*)d_in[11];
    const float* gbw_Whh  = (const float*)d_in[12];
    const float* gbw_bih  = (const float*)d_in[13];
    const float* gbw_bhh  = (const float*)d_in[14];
    const float* f0_W     = (const float*)d_in[15];
    const float* f0_b     = (const float*)d_in[16];
    const float* f1_W     = (const float*)d_in[17];
    const float* f1_b     = (const float*)d_in[18];
    const float* cell_Wih = (const float*)d_in[19];
    const float* cell_Whh = (const float*)d_in[20];
    const float* cell_bih = (const float*)d_in[21];
    const float* cell_bhh = (const float*)d_in[22];
    const float* critic_W = (const float*)d_in[23];
    const float* critic_b = (const float*)d_in[24];
    const float* qg_W     = (const float*)d_in[25];
    const float* qg_b     = (const float*)d_in[26];
    float* out = (float*)d_out;

    char* base = (char*)d_ws;
    size_t off = 0;
    auto alloc = [&](size_t nf) -> float* {
        float* p = (float*)(base + off);
        off += nf * sizeof(float);
        off = (off + 255) & ~(size_t)255;
        return p;
    };
    float* Mbuf   = alloc(16384ull * 256);
    float* Mseq   = alloc(16384ull * 256);   // aliased as Hallr[2] (dead after fused(0))
    float* gfA    = alloc(16384ull * 768);   // written by fused(0) roles, read by kgru fused(1)
    float* gbA    = alloc(16384ull * 768);   // idem; aliased as Qr[1] from fused(2) on
    float* Kbuf   = alloc(256ull * 64 * 512);
    float* PKf    = alloc(98304);
    float* PKb    = alloc(98304);
    float* PKc    = alloc(98304);
    float* hstate = alloc(256ull * 256);
    float* Xr[2]    = { alloc(16384ull * 320), alloc(16384ull * 320) };
    float* X0r[2]   = { alloc(16384ull * 256), alloc(16384ull * 256) };
    float* X1r[2]   = { alloc(16384ull * 256), alloc(16384ull * 256) };
    float* GIr[2]   = { alloc(16384ull * 768), alloc(16384ull * 768) };
    float* Hallr[4] = { alloc(16384ull * 256), alloc(16384ull * 256),
                        Mseq, alloc(16384ull * 256) };
    float* Qr[2]  = { alloc(16384ull * 512), gbA };  // gbA dead after fused(1) kgru
    float* Lr[2]  = { alloc(16384ull * 64), alloc(16384ull * 64) };
    float* bias_f = alloc(768);
    float* bias_b = alloc(768);
    float* bias_c = alloc(768);
    (void)ws_size; (void)in_sizes; (void)n_in; (void)out_size;

    dim3 blk(256);

    // ---- Phase 1: embeddings + weight prep (gate GEMMs run in fused(0)) ----
    gemm_f32<false, 0><<<dim3(4, 256, 1), blk, 0, stream>>>(
        mdp, 128, 0, emb_W, 256, 0, emb_b, Mbuf, 256, 0, 16384, 256, 128);
    seq_major<<<dim3(16384), blk, 0, stream>>>(Mbuf, Mseq);
    pack_w<<<dim3(96, 3, 1), blk, 0, stream>>>(
        gfw_Whh, gbw_Whh, cell_Whh,
        (unsigned short*)PKf, (unsigned short*)PKb, (unsigned short*)PKc);
    combine_bias<<<dim3(3), blk, 0, stream>>>(gfw_bih, gfw_bhh, gbw_bih, gbw_bhh,
                                              cell_bih, cell_bhh, bias_f, bias_b, bias_c);

    // ---- Pipeline priming (x-path for chunks 0..3 partial) ----
    build_x<<<dim3(16384), dim3(320), 0, stream>>>(values, Mbuf, actions, a0, Xr[0], 0);
    gemm_f32<false, 1><<<dim3(4, 256, 1), blk, 0, stream>>>(
        Xr[0], 320, 0, f0_W, 256, 0, f0_b, X0r[0], 256, 0, 16384, 256, 320);
    build_x<<<dim3(16384), dim3(320), 0, stream>>>(values, Mbuf, actions, a0, Xr[1], 64);
    gemm_f32<false, 1><<<dim3(4, 256, 1), blk, 0, stream>>>(
        Xr[1], 320, 0, f0_W, 256, 0, f0_b, X0r[1], 256, 0, 16384, 256, 320);
    gemm_f32<false, 1><<<dim3(4, 256, 1), blk, 0, stream>>>(
        X0r[0], 256, 0, f1_W, 256, 0, f1_b, X1r[0], 256, 0, 16384, 256, 256);
    build_x<<<dim3(16384), dim3(320), 0, stream>>>(values, Mbuf, actions, a0, Xr[0], 128);
    gemm_f32<false, 1><<<dim3(4, 256, 1), blk, 0, stream>>>(
        Xr[0], 320, 0, f0_W, 256, 0, f0_b, X0r[0], 256, 0, 16384, 256, 320);
    gemm_f32<false, 1><<<dim3(4, 256, 1), blk, 0, stream>>>(
        X0r[1], 256, 0, f1_W, 256, 0, f1_b, X1r[1], 256, 0, 16384, 256, 256);
    build_x<<<dim3(16384), dim3(320), 0, stream>>>(values, Mbuf, actions, a0, Xr[1], 192);
    gemm_f32<false, 0><<<dim3(12, 256, 1), blk, 0, stream>>>(
        X1r[0], 256, 0, cell_Wih, 768, 0, bias_c, GIr[0], 768, 0, 16384, 768, 256);

    // ---- Fused pipeline (v15 schedule + gate GEMMs in fused(0)):
    //   fused(c) = scan(c) | gateGEMMs(c==0) | kgru(c==1) | f0(c+3) | f1(c+2)
    //            | GI(c+1) | qg(c-1) | logits(c-2) | epi(c-3) | bx(c+4)
    for (int c = 0; c < NCHUNK; c++) {
        GemmRole g0{}, g1{}, g2{}, g3{}, g4{}, g5{};
        if (c <= 4) g0 = GemmRole{ Xr[(c + 1) & 1], f0_W, f0_b, X0r[(c + 1) & 1],
                                   320, 320, 256, 256, 1, 256, 2 };
        if (c <= 5) g1 = GemmRole{ X0r[c & 1], f1_W, f1_b, X1r[c & 1],
                                   256, 256, 256, 256, 1, 256, 2 };
        if (c <= 6) g2 = GemmRole{ X1r[(c + 1) & 1], cell_Wih, bias_c, GIr[(c + 1) & 1],
                                   256, 256, 768, 768, 0, 768, 6 };
        if (c >= 1) g3 = GemmRole{ Hallr[(c - 1) & 3], qg_W, qg_b, Qr[(c - 1) & 1],
                                   256, 256, 512, 512, 0, 512, 4 };
        if (c == 0) {
            g4 = GemmRole{ Mseq, gfw_Wih, bias_f, gfA, 256, 256, 768, 768, 0, 768, 6 };
            g5 = GemmRole{ Mseq, gbw_Wih, bias_b, gbA, 256, 256, 768, 768, 0, 768, 6 };
        }
        int kgn = (c == 1) ? 32 : 0;
        int lgn = (c >= 2) ? 128 : 0;
        int epn = (c >= 3) ? 2048 : 0;
        int bxn = (c <= 3) ? 128 : 0;
        int total = 16 + kgn + g0.nblocks + g1.nblocks + g2.nblocks + g3.nblocks
                    + g4.nblocks + g5.nblocks + lgn + epn + bxn;

        fused_k<<<dim3(total), dim3(512), 0, stream>>>(
            GIr[c & 1], (const unsigned short*)PKc, (c == 0) ? h0 : (const float*)hstate,
            Hallr[c & 3], hstate,
            kgn, gfA, gbA, (const unsigned short*)PKf, (const unsigned short*)PKb, Kbuf,
            g0, g1, g2, g3, g4, g5,
            lgn, Qr[(c - 2) & 1], Kbuf, Lr[(c - 2) & 1],
            epn, Hallr[(c - 3) & 3], Lr[(c - 3) & 1], (c - 3) * 64,
            bxn, values, Mbuf, actions, a0, Xr[c & 1], (c + 4) * 64,
            critic_W, critic_b, out);
    }

    // ---- Tail drain (small-LDS tail_k): T1 = qg(7) | logits(6) | epi(5) ----
    {
        GemmRole g3t = GemmRole{ Hallr[3], qg_W, qg_b, Qr[1],
                                 256, 256, 512, 512, 0, 512, 4 };
        tail_k<<<dim3(512 + 128 + 2048), dim3(512), 0, stream>>>(
            g3t, 128, Qr[0], Kbuf, Lr[0],
            2048, Hallr[1], Lr[1], 5 * 64,
            actions, critic_W, critic_b, out);
    }
    // ---- T2 = logits(7) | epi(6) ----
    {
        GemmRole gz{};
        tail_k<<<dim3(128 + 2048), dim3(512), 0, stream>>>(
            gz, 128, Qr[1], Kbuf, Lr[1],
            2048, Hallr[2], Lr[0], 6 * 64,
            actions, critic_W, critic_b, out);
    }
    // ---- T3 = epi(7) ----
    epilogue_k<<<dim3(16384), dim3(64), 0, stream>>>(
        Hallr[3], Lr[1], actions, critic_W, critic_b, out, 7 * 64);
}